// Round 10
// baseline (1426.582 us; speedup 1.0000x reference)
//
#include <hip/hip_runtime.h>
#include <hip/hip_bf16.h>
#include <math.h>

#define BATCH 8
#define NPTS  2048
#define KNN   20
#define NEG_INF (-3.402823466e38f)

static __device__ __forceinline__ float bn_scale(float g){ return g * rsqrtf(1.0f + 1e-5f); }

// bf16 round-to-nearest-even
static __device__ __forceinline__ unsigned short bf16r(float f){
  unsigned int u = __float_as_uint(f);
  unsigned int r = (u + 0x7fffu + ((u >> 16) & 1u)) >> 16;
  return (unsigned short)r;
}
static __device__ __forceinline__ float bf2f(unsigned short h){
  return __uint_as_float((unsigned int)h << 16);
}
// ordered-int encode/decode for float max via atomicMax(uint)
static __device__ __forceinline__ unsigned int fenc(float f){
  unsigned int u = __float_as_uint(f);
  return (u & 0x80000000u) ? ~u : (u | 0x80000000u);
}
static __device__ __forceinline__ float fdec(unsigned int e){
  return __uint_as_float((e & 0x80000000u) ? (e & 0x7fffffffu) : ~e);
}

using bfrag = __attribute__((ext_vector_type(8))) short;  // 8 bf16 (4 VGPRs)
using f32x4 = __attribute__((ext_vector_type(4))) float;  // 4 fp32 acc

// ---------------- squared norms, channel-major input (layer 1 only, C=3) ----------------
__global__ void sqnorm_kernel(const float* __restrict__ X, float* __restrict__ sq, int C){
  int i = blockIdx.x*blockDim.x + threadIdx.x;
  if (i >= BATCH*NPTS) return;
  int b = i / NPTS, n = i - b*NPTS;
  const float* xb = X + (size_t)b*C*NPTS + n;
  float s = 0.f;
  for (int c=0;c<C;++c){ float v = xb[(size_t)c*NPTS]; s += v*v; }
  sq[i] = s;
}

// ---------------- squared norms, point-major input (layers 2-4) ----------------
__global__ void sqnorm_pm_kernel(const float* __restrict__ xT, float* __restrict__ sq, int C){
  int i = blockIdx.x*blockDim.x + threadIdx.x;
  if (i >= BATCH*NPTS) return;
  const float* r = xT + (size_t)i*C;
  float s = 0.f;
  for (int c4=0; c4<C; c4+=4){
    float4 v = *(const float4*)&r[c4];
    s += v.x*v.x; s += v.y*v.y; s += v.z*v.z; s += v.w*v.w;   // ascending-c order preserved
  }
  sq[i] = s;
}

// ---------------- kNN layer 1 (C=3): round-7 v3 (VALU dist + LDS selection), bit-exact --
__global__ __launch_bounds__(256, 2) void knn3_kernel(const float* __restrict__ X,
                                                      const float* __restrict__ sq,
                                                      int* __restrict__ idxout){
  const int b = blockIdx.y;
  const int n0 = blockIdx.x * 8;
  const int t = threadIdx.x;
  __shared__ __align__(16) float dist[4][NPTS];
  __shared__ float ctrs[3][8];
  __shared__ float sqn[8];
  const float* xb = X + (size_t)b*3*NPTS;
  if (t < 24) ctrs[t>>3][t&7] = xb[(size_t)(t>>3)*NPTS + n0 + (t&7)];
  if (t < 8) sqn[t] = sq[b*NPTS + n0 + t];
  __syncthreads();

  const int m0 = t * 8;
  float acc[8][8];
  #pragma unroll
  for (int i=0;i<8;++i)
    #pragma unroll
    for (int j=0;j<8;++j) acc[i][j] = 0.f;
  #pragma unroll
  for (int c=0;c<3;++c){
    const float4 xa = *(const float4*)&xb[(size_t)c*NPTS + m0];
    const float4 xc = *(const float4*)&xb[(size_t)c*NPTS + m0 + 4];
    const float xm[8] = {xa.x,xa.y,xa.z,xa.w,xc.x,xc.y,xc.z,xc.w};
    #pragma unroll
    for (int i=0;i<8;++i){
      const float cv = ctrs[c][i];
      #pragma unroll
      for (int j=0;j<8;++j) acc[i][j] += cv*xm[j];
    }
  }
  {
    const float4 sa = *(const float4*)&sq[b*NPTS + m0];
    const float4 sb = *(const float4*)&sq[b*NPTS + m0 + 4];
    const float sm[8] = {sa.x,sa.y,sa.z,sa.w,sb.x,sb.y,sb.z,sb.w};
    #pragma unroll
    for (int i=0;i<8;++i){
      const float si = sqn[i];
      #pragma unroll
      for (int j=0;j<8;++j) acc[i][j] = 2.f*acc[i][j] - si - sm[j];
    }
  }

  const int wv = t >> 6, lane = t & 63;
  #pragma unroll
  for (int rep=0; rep<2; ++rep){
    #pragma unroll
    for (int i=0;i<4;++i){
      *(float4*)&dist[i][m0]   = make_float4(acc[rep*4+i][0],acc[rep*4+i][1],acc[rep*4+i][2],acc[rep*4+i][3]);
      *(float4*)&dist[i][m0+4] = make_float4(acc[rep*4+i][4],acc[rep*4+i][5],acc[rep*4+i][6],acc[rep*4+i][7]);
    }
    __syncthreads();
    float lmax = NEG_INF; int lidx = 0x7fffffff;
    #pragma unroll
    for (int j=0;j<32;++j){
      float vv = dist[wv][lane + 64*j];
      if (vv > lmax){ lmax = vv; lidx = lane + 64*j; }
    }
    int* row = idxout + ((size_t)b*NPTS + n0 + rep*4 + wv)*KNN;
    for (int sel=0; sel<KNN; ++sel){
      float bv = lmax; int bi = lidx;
      #pragma unroll
      for (int off=32; off>0; off>>=1){
        float ov = __shfl_down(bv, off, 64);
        int   oi = __shfl_down(bi, off, 64);
        if (ov > bv || (ov == bv && oi < bi)){ bv = ov; bi = oi; }
      }
      const int widx = __shfl(bi, 0, 64);
      if (lane == 0) row[sel] = widx;
      if ((widx & 63) == lane){
        dist[wv][widx] = NEG_INF;
        lmax = NEG_INF; lidx = 0x7fffffff;
        #pragma unroll
        for (int j=0;j<32;++j){
          float vv = dist[wv][lane + 64*j];
          if (vv > lmax){ lmax = vv; lidx = lane + 64*j; }
        }
      }
    }
    __syncthreads();
  }
}

// ---------------- kNN MFMA (layers 2-4): split-bf16 distance GEMM + v3 selection --------
// Block: 512 threads (8 waves), 8 points. dist[8][2048] fp32 in LDS (64KB, 2 blocks/CU).
// A = 8 centers (+8 dup rows), B = candidate rows; both read from the split-bf16 point-major
// feature array (row stride 512 shorts, column base pre-offset into the pointers).
// D = Ah.Bh + Ah.Bl + Al.Bh (fp32 acc ~ fp32-accurate); epilogue 2*acc - sqn - sqm.
// Then each wave runs the v3 extraction for one point (single pass, no rep serialization).
template<int C>
__global__ __launch_bounds__(512, 4) void knn_mfma(const unsigned short* __restrict__ xhi,
    const unsigned short* __restrict__ xlo, const float* __restrict__ sqg,
    int* __restrict__ idxout){
  constexpr int KS = C / 32;
  const int b = blockIdx.y, n0 = blockIdx.x*8, t = threadIdx.x;
  __shared__ __align__(16) float dist[8][NPTS];
  __shared__ float sqn[8];
  const int wv = t >> 6, lane = t & 63, lane15 = lane & 15, quad = lane >> 4;
  const size_t rowbase = (size_t)b*NPTS;
  if (t < 8) sqn[t] = sqg[rowbase + n0 + t];
  // A fragments: row = lane15&7 (rows 8-15 duplicate rows 0-7; their D rows are ignored)
  bfrag Ah[KS], Al[KS];
  {
    const size_t aoff = (rowbase + n0 + (lane15 & 7))*512;
    #pragma unroll
    for (int s=0;s<KS;++s){
      Ah[s] = *(const bfrag*)&xhi[aoff + s*32 + quad*8];
      Al[s] = *(const bfrag*)&xlo[aoff + s*32 + quad*8];
    }
  }
  __syncthreads();   // sqn visible

  #pragma unroll 2
  for (int i=0;i<16;++i){
    const int cand0 = (wv*16 + i)*16;
    const size_t boff = (rowbase + cand0 + lane15)*512;
    bfrag Bh[KS], Bl[KS];
    #pragma unroll
    for (int s=0;s<KS;++s){
      Bh[s] = *(const bfrag*)&xhi[boff + s*32 + quad*8];
      Bl[s] = *(const bfrag*)&xlo[boff + s*32 + quad*8];
    }
    f32x4 acc = {0.f,0.f,0.f,0.f};
    #pragma unroll
    for (int s=0;s<KS;++s){
      acc = __builtin_amdgcn_mfma_f32_16x16x32_bf16(Ah[s], Bh[s], acc, 0, 0, 0);
      acc = __builtin_amdgcn_mfma_f32_16x16x32_bf16(Ah[s], Bl[s], acc, 0, 0, 0);
      acc = __builtin_amdgcn_mfma_f32_16x16x32_bf16(Al[s], Bh[s], acc, 0, 0, 0);
    }
    const float sqm = sqg[rowbase + cand0 + lane15];
    if (quad < 2){
      #pragma unroll
      for (int r=0;r<4;++r){
        const int row = quad*4 + r;                 // D mapping: col=lane&15, row=quad*4+r
        dist[row][cand0 + lane15] = 2.f*acc[r] - sqn[row] - sqm;
      }
    }
  }
  __syncthreads();

  // selection: wave wv extracts top-20 for point n0+wv (v3 semantics, bit-exact ties)
  float lmax = NEG_INF; int lidx = 0x7fffffff;
  #pragma unroll
  for (int j=0;j<32;++j){
    float vv = dist[wv][lane + 64*j];
    if (vv > lmax){ lmax = vv; lidx = lane + 64*j; }
  }
  int* row = idxout + (rowbase + n0 + wv)*KNN;
  for (int sel=0; sel<KNN; ++sel){
    float bv = lmax; int bi = lidx;
    #pragma unroll
    for (int off=32; off>0; off>>=1){
      float ov = __shfl_down(bv, off, 64);
      int   oi = __shfl_down(bi, off, 64);
      if (ov > bv || (ov == bv && oi < bi)){ bv = ov; bi = oi; }
    }
    const int widx = __shfl(bi, 0, 64);
    if (lane == 0) row[sel] = widx;
    if ((widx & 63) == lane){
      dist[wv][widx] = NEG_INF;
      lmax = NEG_INF; lidx = 0x7fffffff;
      #pragma unroll
      for (int j=0;j<32;++j){
        float vv = dist[wv][lane + 64*j];
        if (vv > lmax){ lmax = vv; lidx = lane + 64*j; }
      }
    }
  }
}

// ---------------- fp32 weight prep (layer 1 only): wnT[c][o], wdT[c][o] ----------------
__global__ void wprep_kernel(const float* __restrict__ w, float* __restrict__ wnT,
                             float* __restrict__ wdT, int O, int C){
  int i = blockIdx.x*blockDim.x + threadIdx.x;
  if (i >= O*C) return;
  int c = i / O, o = i - c*O;
  float a = w[(size_t)o*2*C + c];
  wnT[(size_t)c*O + o] = a;
  wdT[(size_t)c*O + o] = w[(size_t)o*2*C + C + c] - a;
}

// ---------------- bf16 weight prep (layers 2-4): wn[o][c], wd[o][c] (k contiguous) -----
__global__ void wprep_bf_kernel(const float* __restrict__ w, unsigned short* __restrict__ wn,
                                unsigned short* __restrict__ wd, int O, int C){
  int i = blockIdx.x*blockDim.x + threadIdx.x;
  if (i >= O*C) return;
  int o = i / C, c = i - o*C;
  float a = w[(size_t)o*2*C + c];
  float d = w[(size_t)o*2*C + C + c] - a;
  wn[(size_t)o*C + c] = bf16r(a);
  wd[(size_t)o*C + c] = bf16r(d);
}

// ---------------- split-bf16 weight convert (conv5): hi = bf16(w), lo = bf16(w-hi) ------
__global__ void bfsplit_kernel(const float* __restrict__ in, unsigned short* __restrict__ hi,
                               unsigned short* __restrict__ lo, int nq){
  int i = blockIdx.x*blockDim.x + threadIdx.x;
  if (i >= nq) return;
  float4 v = *(const float4*)&in[(size_t)i*4];
  unsigned short h0=bf16r(v.x), h1=bf16r(v.y), h2=bf16r(v.z), h3=bf16r(v.w);
  unsigned short l0=bf16r(v.x-bf2f(h0)), l1=bf16r(v.y-bf2f(h1)),
                 l2=bf16r(v.z-bf2f(h2)), l3=bf16r(v.w-bf2f(h3));
  *(uint2*)&hi[(size_t)i*4] = make_uint2((unsigned)h0|((unsigned)h1<<16), (unsigned)h2|((unsigned)h3<<16));
  *(uint2*)&lo[(size_t)i*4] = make_uint2((unsigned)l0|((unsigned)l1<<16), (unsigned)l2|((unsigned)l3<<16));
}

// ---------------- xsplit: fp32 [b][n][Csrc] -> split-bf16 xcat slice (stride 512) -------
// dst pointers are pre-offset by the base column.
__global__ __launch_bounds__(256) void xsplit_kernel(const float* __restrict__ src,
    unsigned short* __restrict__ hi, unsigned short* __restrict__ lo, int Cq){ // Cq = Csrc/4
  int i = blockIdx.x*blockDim.x + threadIdx.x;
  if (i >= BATCH*NPTS*Cq) return;
  int bn_ = i / Cq, q = i - bn_*Cq;
  float4 v = *(const float4*)&src[(size_t)i*4];
  unsigned short h0=bf16r(v.x), h1=bf16r(v.y), h2=bf16r(v.z), h3=bf16r(v.w);
  unsigned short l0=bf16r(v.x-bf2f(h0)), l1=bf16r(v.y-bf2f(h1)),
                 l2=bf16r(v.z-bf2f(h2)), l3=bf16r(v.w-bf2f(h3));
  const size_t d = (size_t)bn_*512 + q*4;
  *(uint2*)&hi[d] = make_uint2((unsigned)h0|((unsigned)h1<<16), (unsigned)h2|((unsigned)h3<<16));
  *(uint2*)&lo[d] = make_uint2((unsigned)l0|((unsigned)l1<<16), (unsigned)l2|((unsigned)l3<<16));
}

// ---------------- x -> xT0 [N][3] ----------------
__global__ void xt0_kernel(const float* __restrict__ x, float* __restrict__ xT0){
  int i = blockIdx.x*blockDim.x + threadIdx.x;
  if (i >= BATCH*NPTS) return;
  int b = i / NPTS, n = i - b*NPTS;
  const float* xb = x + (size_t)b*3*NPTS;
  float v0 = xb[n], v1 = xb[NPTS + n], v2 = xb[2*NPTS + n];
  float* o = xT0 + ((size_t)b*NPTS + n)*3;
  o[0]=v0; o[1]=v1; o[2]=v2;
}

// ---------------- edge conv layer 1 (C=3, fp32): 4 points per block ----------------
__global__ __launch_bounds__(256) void edgeconv1_kernel(const float* __restrict__ xT0,
    const int* __restrict__ idx, const float* __restrict__ wnT, const float* __restrict__ wdT,
    const float* __restrict__ g, const float* __restrict__ bb, float* __restrict__ outT){
  const int b = blockIdx.y, n0 = blockIdx.x*4, t = threadIdx.x;
  __shared__ float nbr[4][KNN][3];
  __shared__ float ctr[4][3];
  __shared__ int   idxs[4][KNN];
  const float* xb = xT0 + (size_t)b*NPTS*3;
  if (t < 4*KNN) idxs[t/KNN][t%KNN] = idx[((size_t)b*NPTS + n0 + t/KNN)*KNN + (t%KNN)];
  if (t >= 128 && t < 140){ int i = t-128; ctr[i/3][i%3] = xb[(size_t)(n0 + i/3)*3 + i%3]; }
  __syncthreads();
  for (int i=t; i<4*KNN*3; i+=256){
    int p = i/(KNN*3), r = i - p*(KNN*3), k = r/3, c = r - k*3;
    nbr[p][k][c] = xb[(size_t)idxs[p][k]*3 + c];
  }
  __syncthreads();
  const int p = t >> 6, o = t & 63;
  const float wn0 = wnT[o], wn1 = wnT[64+o], wn2 = wnT[128+o];
  const float cst = ctr[p][0]*wdT[o] + ctr[p][1]*wdT[64+o] + ctr[p][2]*wdT[128+o];
  float best = NEG_INF;
  #pragma unroll
  for (int k=0;k<KNN;++k){
    float a = nbr[p][k][0]*wn0 + nbr[p][k][1]*wn1 + nbr[p][k][2]*wn2;
    best = fmaxf(best, a);
  }
  float vv = (best + cst) * bn_scale(g[o]) + bb[o];
  outT[((size_t)b*NPTS + n0 + p)*64 + o] = fmaxf(vv, 0.f);
}

// ---------------- edge conv MFMA (bf16): block = 4 points ----------------
template<int C, int O>
__global__ __launch_bounds__(256) void edgeconv_mfma(const float* __restrict__ xT,
    const int* __restrict__ idx,
    const unsigned short* __restrict__ wn_bf, const unsigned short* __restrict__ wd_bf,
    const float* __restrict__ g, const float* __restrict__ bb, float* __restrict__ outT){
  constexpr int ROWS = 112;        // 7 m-tiles of 16
  constexpr int CP   = C + 8;      // padded row (bf16): 16B-aligned stride, conflict-free b128
  constexpr int KS   = C / 32;     // k-steps per tile
  constexpr int NTW  = O / 64;     // n-tiles per wave (O/16 tiles over 4 waves)
  __shared__ __align__(16) unsigned short A[ROWS][CP];
  __shared__ unsigned int res[4][O];
  __shared__ float cst_s[4][O];
  __shared__ int idxs[4][KNN];
  const int b = blockIdx.y, n0 = blockIdx.x*4, t = threadIdx.x;
  const float* xTb = xT + (size_t)b*NPTS*C;
  if (t < 4*KNN) idxs[t/KNN][t%KNN] = idx[((size_t)b*NPTS + n0 + t/KNN)*KNN + (t%KNN)];
  for (int i=t; i<4*O; i+=256) res[i/O][i & (O-1)] = 0u;   // 0 < fenc(any finite)
  __syncthreads();
  for (int i=t; i<ROWS*(C/4); i+=256){
    int r = i/(C/4), c4 = i - r*(C/4);
    float4 v = make_float4(0.f,0.f,0.f,0.f);
    if (r < 96){
      int p = r/24, kk = r - p*24;
      int src = idxs[p][kk < KNN ? kk : 0];        // pad rows duplicate nbr 0 (max-neutral)
      v = *(const float4*)&xTb[(size_t)src*C + c4*4];
    } else if (r < 100){
      v = *(const float4*)&xTb[(size_t)(n0 + (r-96))*C + c4*4];
    }
    unsigned int lo = (unsigned int)bf16r(v.x) | ((unsigned int)bf16r(v.y) << 16);
    unsigned int hi = (unsigned int)bf16r(v.z) | ((unsigned int)bf16r(v.w) << 16);
    *(uint2*)&A[r][c4*4] = make_uint2(lo, hi);
  }
  __syncthreads();

  const int wv = t >> 6, l = t & 63;
  const int lane15 = l & 15, quad = l >> 4;
  bfrag Bn[NTW][KS];
  #pragma unroll
  for (int nt=0; nt<NTW; ++nt){
    const int col = (wv*NTW + nt)*16 + lane15;
    #pragma unroll
    for (int s=0; s<KS; ++s)
      Bn[nt][s] = *(const bfrag*)&wn_bf[(size_t)col*C + s*32 + quad*8];
  }
  #pragma unroll
  for (int mt=0; mt<7; ++mt){
    bfrag Af[KS];
    #pragma unroll
    for (int s=0; s<KS; ++s)
      Af[s] = *(const bfrag*)&A[mt*16 + lane15][s*32 + quad*8];
    if (mt < 6){
      const int rbase = mt*16 + quad*4;
      const int p = rbase / 24;
      #pragma unroll
      for (int nt=0; nt<NTW; ++nt){
        f32x4 acc = {0.f,0.f,0.f,0.f};
        #pragma unroll
        for (int s=0; s<KS; ++s)
          acc = __builtin_amdgcn_mfma_f32_16x16x32_bf16(Af[s], Bn[nt][s], acc, 0, 0, 0);
        float m = fmaxf(fmaxf(acc[0], acc[1]), fmaxf(acc[2], acc[3]));
        const int col = (wv*NTW + nt)*16 + lane15;
        atomicMax(&res[p][col], fenc(m));
      }
    } else {
      #pragma unroll
      for (int nt=0; nt<NTW; ++nt){
        const int col = (wv*NTW + nt)*16 + lane15;
        f32x4 acc = {0.f,0.f,0.f,0.f};
        #pragma unroll
        for (int s=0; s<KS; ++s){
          bfrag Bd = *(const bfrag*)&wd_bf[(size_t)col*C + s*32 + quad*8];
          acc = __builtin_amdgcn_mfma_f32_16x16x32_bf16(Af[s], Bd, acc, 0, 0, 0);
        }
        if (quad == 0){
          #pragma unroll
          for (int r=0;r<4;++r) cst_s[r][col] = acc[r];
        }
      }
    }
  }
  __syncthreads();
  for (int i=t; i<4*O; i+=256){
    int p = i/O, o = i - p*O;
    float mx = fdec(res[p][o]);
    float vv = (mx + cst_s[p][o]) * bn_scale(g[o]) + bb[o];
    outT[((size_t)b*NPTS + n0 + p)*O + o] = fmaxf(vv, 0.f);
  }
}

// ---------------- conv5 v3: LDS-staged split-bf16 MFMA GEMM + max over n ----------------
__global__ __launch_bounds__(256) void conv5_v3(const unsigned short* __restrict__ xhi,
    const unsigned short* __restrict__ xlo, const unsigned short* __restrict__ whi,
    const unsigned short* __restrict__ wlo, const float* __restrict__ g,
    const float* __restrict__ bb, float* __restrict__ out5){
  __shared__ __align__(16) unsigned short Ah_s[128*32];
  __shared__ __align__(16) unsigned short Al_s[128*32];
  __shared__ __align__(16) unsigned short Bh_s[64*32];
  __shared__ __align__(16) unsigned short Bl_s[64*32];
  const int t = threadIdx.x;
  const int row0 = blockIdx.x*128, o0 = blockIdx.y*64;
  const int b = row0 / NPTS;   // 128 | NPTS, so a block never straddles batches
  const int wv = t >> 6, l = t & 63, lane15 = l & 15, quad = l >> 4;
  const int ar = t >> 2, ac = (t & 3)*8;
  const unsigned short* gAh0 = xhi + (size_t)(row0 + ar)*512 + ac;
  const unsigned short* gAh1 = xhi + (size_t)(row0 + 64 + ar)*512 + ac;
  const unsigned short* gAl0 = xlo + (size_t)(row0 + ar)*512 + ac;
  const unsigned short* gAl1 = xlo + (size_t)(row0 + 64 + ar)*512 + ac;
  const unsigned short* gBh  = whi + (size_t)(o0 + ar)*512 + ac;
  const unsigned short* gBl  = wlo + (size_t)(o0 + ar)*512 + ac;

  uint4 pf0 = *(const uint4*)gAh0;
  uint4 pf1 = *(const uint4*)gAh1;
  uint4 pf2 = *(const uint4*)gAl0;
  uint4 pf3 = *(const uint4*)gAl1;
  uint4 pf4 = *(const uint4*)gBh;
  uint4 pf5 = *(const uint4*)gBl;

  f32x4 acc[2][4];
  #pragma unroll
  for (int mt=0;mt<2;++mt)
    #pragma unroll
    for (int nt=0;nt<4;++nt) acc[mt][nt] = (f32x4){0.f,0.f,0.f,0.f};

  for (int ks=0; ks<16; ++ks){
    *(uint4*)&Ah_s[t*8]        = pf0;
    *(uint4*)&Ah_s[2048 + t*8] = pf1;
    *(uint4*)&Al_s[t*8]        = pf2;
    *(uint4*)&Al_s[2048 + t*8] = pf3;
    *(uint4*)&Bh_s[t*8]        = pf4;
    *(uint4*)&Bl_s[t*8]        = pf5;
    __syncthreads();
    if (ks < 15){
      const int koff = (ks+1)*32;
      pf0 = *(const uint4*)(gAh0 + koff);
      pf1 = *(const uint4*)(gAh1 + koff);
      pf2 = *(const uint4*)(gAl0 + koff);
      pf3 = *(const uint4*)(gAl1 + koff);
      pf4 = *(const uint4*)(gBh  + koff);
      pf5 = *(const uint4*)(gBl  + koff);
    }
    bfrag Afh[2], Afl[2], Bfh[4], Bfl[4];
    #pragma unroll
    for (int mt=0;mt<2;++mt){
      const int m = wv*32 + mt*16 + lane15;
      Afh[mt] = *(const bfrag*)&Ah_s[m*32 + quad*8];
      Afl[mt] = *(const bfrag*)&Al_s[m*32 + quad*8];
    }
    #pragma unroll
    for (int nt=0;nt<4;++nt){
      const int oc = nt*16 + lane15;
      Bfh[nt] = *(const bfrag*)&Bh_s[oc*32 + quad*8];
      Bfl[nt] = *(const bfrag*)&Bl_s[oc*32 + quad*8];
    }
    #pragma unroll
    for (int mt=0;mt<2;++mt)
      #pragma unroll
      for (int nt=0;nt<4;++nt){
        acc[mt][nt] = __builtin_amdgcn_mfma_f32_16x16x32_bf16(Afh[mt], Bfh[nt], acc[mt][nt], 0, 0, 0);
        acc[mt][nt] = __builtin_amdgcn_mfma_f32_16x16x32_bf16(Afl[mt], Bfh[nt], acc[mt][nt], 0, 0, 0);
        acc[mt][nt] = __builtin_amdgcn_mfma_f32_16x16x32_bf16(Afh[mt], Bfl[nt], acc[mt][nt], 0, 0, 0);
      }
    __syncthreads();
  }
  #pragma unroll
  for (int nt=0;nt<4;++nt){
    float m = NEG_INF;
    #pragma unroll
    for (int mt=0;mt<2;++mt)
      #pragma unroll
      for (int r=0;r<4;++r) m = fmaxf(m, acc[mt][nt][r]);
    m = fmaxf(m, __shfl_xor(m, 16, 64));
    m = fmaxf(m, __shfl_xor(m, 32, 64));
    if (quad == 0){
      const int o = o0 + nt*16 + lane15;
      float vv = fmaxf(m * bn_scale(g[o]) + bb[o], 0.f);
      atomicMax((int*)&out5[(size_t)b*1024 + o], __float_as_int(vv));
    }
  }
}

__global__ void zero_kernel(float* __restrict__ p, int nfloats){
  int i = blockIdx.x*blockDim.x + threadIdx.x;
  if (i < nfloats) p[i] = 0.f;
}

// ---------------- FC layers ----------------
__global__ void fc_kernel(const float* __restrict__ in, const float* __restrict__ w,
                          const float* __restrict__ g, const float* __restrict__ bb,
                          float* __restrict__ out, int IN, int O){
  int i = blockIdx.x*blockDim.x + threadIdx.x;
  if (i >= BATCH*O) return;
  int b = i / O, o = i - b*O;
  const float* inb = in + (size_t)b*IN;
  const float* wo  = w + (size_t)o*IN;
  float s = 0.f;
  for (int c=0;c<IN;++c) s += inb[c]*wo[c];
  if (g){ s = s*bn_scale(g[o]) + bb[o]; s = fmaxf(s, 0.f); }
  out[i] = s;
}

extern "C" void kernel_launch(void* const* d_in, const int* in_sizes, int n_in,
                              void* d_out, int out_size, void* d_ws, size_t ws_size,
                              hipStream_t stream){
  const float* x   = (const float*)d_in[0];
  const float* w1  = (const float*)d_in[1];
  const float* w2  = (const float*)d_in[2];
  const float* w3  = (const float*)d_in[3];
  const float* w4  = (const float*)d_in[4];
  const float* w5  = (const float*)d_in[5];
  const float* fw1 = (const float*)d_in[6];
  const float* fw2 = (const float*)d_in[7];
  const float* fw3 = (const float*)d_in[8];
  const float* g1 = (const float*)d_in[9];  const float* b1 = (const float*)d_in[10];
  const float* g2 = (const float*)d_in[11]; const float* b2 = (const float*)d_in[12];
  const float* g3 = (const float*)d_in[13]; const float* b3 = (const float*)d_in[14];
  const float* g4 = (const float*)d_in[15]; const float* b4 = (const float*)d_in[16];
  const float* g5 = (const float*)d_in[17]; const float* b5 = (const float*)d_in[18];
  const float* g6 = (const float*)d_in[19]; const float* b6 = (const float*)d_in[20];
  const float* g7 = (const float*)d_in[21]; const float* b7 = (const float*)d_in[22];

  float* ws = (float*)d_ws;
  size_t off = 0;
  unsigned short* xcat_hi = (unsigned short*)(ws + off); off += (size_t)BATCH*256*NPTS; // B*N*512 bf16
  unsigned short* xcat_lo = (unsigned short*)(ws + off); off += (size_t)BATCH*256*NPTS;
  float* x1T = ws + off; off += (size_t)BATCH*64*NPTS;
  float* x2T = ws + off; off += (size_t)BATCH*64*NPTS;
  float* x3T = ws + off; off += (size_t)BATCH*128*NPTS;
  float* x4T = ws + off; off += (size_t)BATCH*256*NPTS;
  float* xT0 = ws + off; off += (size_t)BATCH*3*NPTS;
  float* sq  = ws + off; off += (size_t)BATCH*NPTS;
  int*  idx  = (int*)(ws + off); off += (size_t)BATCH*NPTS*KNN;
  float* out5 = ws + off; off += BATCH*1024;
  float* h6 = ws + off;   off += BATCH*512;
  float* h7 = ws + off;   off += BATCH*256;
  float* wnT1 = ws + off; off += 3*64;
  float* wdT1 = ws + off; off += 3*64;
  unsigned short* wn2 = (unsigned short*)(ws + off); off += 64*64/2;
  unsigned short* wd2 = (unsigned short*)(ws + off); off += 64*64/2;
  unsigned short* wn3 = (unsigned short*)(ws + off); off += 128*64/2;
  unsigned short* wd3 = (unsigned short*)(ws + off); off += 128*64/2;
  unsigned short* wn4 = (unsigned short*)(ws + off); off += 256*128/2;
  unsigned short* wd4 = (unsigned short*)(ws + off); off += 256*128/2;
  unsigned short* w5hi = (unsigned short*)(ws + off); off += 1024*512/2;
  unsigned short* w5lo = (unsigned short*)(ws + off); off += 1024*512/2;

  dim3 gridKNN8(NPTS/8, BATCH);
  dim3 gridEC(NPTS/4, BATCH);

  // layer 1 (C=3 -> 64, fp32, bit-exact knn)
  xt0_kernel<<<64, 256, 0, stream>>>(x, xT0);
  sqnorm_kernel<<<64, 256, 0, stream>>>(x, sq, 3);
  knn3_kernel<<<gridKNN8, 256, 0, stream>>>(x, sq, idx);
  wprep_kernel<<<1, 256, 0, stream>>>(w1, wnT1, wdT1, 64, 3);
  edgeconv1_kernel<<<gridEC, 256, 0, stream>>>(xT0, idx, wnT1, wdT1, g1, b1, x1T);
  // layer 2 (C=64 -> 64): split x1T into xcat cols 0..63, MFMA knn + edgeconv
  xsplit_kernel<<<(BATCH*NPTS*16)/256, 256, 0, stream>>>(x1T, xcat_hi, xcat_lo, 16);
  sqnorm_pm_kernel<<<64, 256, 0, stream>>>(x1T, sq, 64);
  knn_mfma<64><<<gridKNN8, 512, 0, stream>>>(xcat_hi, xcat_lo, sq, idx);
  wprep_bf_kernel<<<16, 256, 0, stream>>>(w2, wn2, wd2, 64, 64);
  edgeconv_mfma<64,64><<<gridEC, 256, 0, stream>>>(x1T, idx, wn2, wd2, g2, b2, x2T);
  // layer 3 (C=64 -> 128): cols 64..127
  xsplit_kernel<<<(BATCH*NPTS*16)/256, 256, 0, stream>>>(x2T, xcat_hi + 64, xcat_lo + 64, 16);
  sqnorm_pm_kernel<<<64, 256, 0, stream>>>(x2T, sq, 64);
  knn_mfma<64><<<gridKNN8, 512, 0, stream>>>(xcat_hi + 64, xcat_lo + 64, sq, idx);
  wprep_bf_kernel<<<32, 256, 0, stream>>>(w3, wn3, wd3, 128, 64);
  edgeconv_mfma<64,128><<<gridEC, 256, 0, stream>>>(x2T, idx, wn3, wd3, g3, b3, x3T);
  // layer 4 (C=128 -> 256): cols 128..255
  xsplit_kernel<<<(BATCH*NPTS*32)/256, 256, 0, stream>>>(x3T, xcat_hi + 128, xcat_lo + 128, 32);
  sqnorm_pm_kernel<<<64, 256, 0, stream>>>(x3T, sq, 128);
  knn_mfma<128><<<gridKNN8, 512, 0, stream>>>(xcat_hi + 128, xcat_lo + 128, sq, idx);
  wprep_bf_kernel<<<128, 256, 0, stream>>>(w4, wn4, wd4, 256, 128);
  edgeconv_mfma<128,256><<<gridEC, 256, 0, stream>>>(x3T, idx, wn4, wd4, g4, b4, x4T);
  // conv5 (split-bf16 MFMA): cols 256..511 then GEMM + global max over n
  xsplit_kernel<<<(BATCH*NPTS*64)/256, 256, 0, stream>>>(x4T, xcat_hi + 256, xcat_lo + 256, 64);
  bfsplit_kernel<<<512, 256, 0, stream>>>(w5, w5hi, w5lo, 1024*512/4);
  zero_kernel<<<32, 256, 0, stream>>>(out5, BATCH*1024);
  conv5_v3<<<dim3(BATCH*NPTS/128, 16), 256, 0, stream>>>(xcat_hi, xcat_lo, w5hi, w5lo, g5, b5, out5);
  // FC head
  fc_kernel<<<16, 256, 0, stream>>>(out5, fw1, g6, b6, h6, 1024, 512);
  fc_kernel<<<8, 256, 0, stream>>>(h6, fw2, g7, b7, h7, 512, 256);
  fc_kernel<<<2, 256, 0, stream>>>(h7, fw3, nullptr, nullptr, (float*)d_out, 256, 40);
}

// Round 11
// 1399.222 us; speedup vs baseline: 1.0196x; 1.0196x over previous
//
#include <hip/hip_runtime.h>
#include <hip/hip_bf16.h>
#include <math.h>

#define BATCH 8
#define NPTS  2048
#define KNN   20
#define NEG_INF (-3.402823466e38f)

static __device__ __forceinline__ float bn_scale(float g){ return g * rsqrtf(1.0f + 1e-5f); }

// bf16 round-to-nearest-even
static __device__ __forceinline__ unsigned short bf16r(float f){
  unsigned int u = __float_as_uint(f);
  unsigned int r = (u + 0x7fffu + ((u >> 16) & 1u)) >> 16;
  return (unsigned short)r;
}
static __device__ __forceinline__ float bf2f(unsigned short h){
  return __uint_as_float((unsigned int)h << 16);
}
// ordered-int encode/decode for float max via atomicMax(uint)
static __device__ __forceinline__ unsigned int fenc(float f){
  unsigned int u = __float_as_uint(f);
  return (u & 0x80000000u) ? ~u : (u | 0x80000000u);
}
static __device__ __forceinline__ float fdec(unsigned int e){
  return __uint_as_float((e & 0x80000000u) ? (e & 0x7fffffffu) : ~e);
}

using bfrag = __attribute__((ext_vector_type(8))) short;  // 8 bf16 (4 VGPRs)
using f32x4 = __attribute__((ext_vector_type(4))) float;  // 4 fp32 acc

// ---------------- squared norms per point (reads channel-major [C][N]) ----------------
__global__ void sqnorm_kernel(const float* __restrict__ X, float* __restrict__ sq, int C){
  int i = blockIdx.x*blockDim.x + threadIdx.x;
  if (i >= BATCH*NPTS) return;
  int b = i / NPTS, n = i - b*NPTS;
  const float* xb = X + (size_t)b*C*NPTS + n;
  float s = 0.f;
  for (int c=0;c<C;++c){ float v = xb[(size_t)c*NPTS]; s += v*v; }
  sq[i] = s;
}

// ---------------- kNN v6: round-7 v3 + register-cached selection ----------------
// v3 distance phase (bit-identical), selection caches the lane's 32 values in registers:
// winner-lane rescan = 32 register compares instead of 32 ds_read_b32. launch_bounds(256,2)
// gives a 256-VGPR budget so v[32] does NOT spill (round-4's spill was the (,4) 128-cap).
template<int C>
__global__ __launch_bounds__(256, 2) void knn_kernel(const float* __restrict__ X,
                                                     const float* __restrict__ sq,
                                                     int* __restrict__ idxout){
  const int b = blockIdx.y;
  const int n0 = blockIdx.x * 8;
  const int t = threadIdx.x;
  __shared__ __align__(16) float dist[4][NPTS];
  __shared__ float ctrs[C][8];
  __shared__ float sqn[8];
  const float* xb = X + (size_t)b*C*NPTS;
  for (int i=t; i<C*8; i+=256){
    int c = i >> 3, p = i & 7;
    ctrs[c][p] = xb[(size_t)c*NPTS + n0 + p];
  }
  if (t < 8) sqn[t] = sq[b*NPTS + n0 + t];
  __syncthreads();

  const int m0 = t * 8;
  float acc[8][8];
  #pragma unroll
  for (int i=0;i<8;++i)
    #pragma unroll
    for (int j=0;j<8;++j) acc[i][j] = 0.f;
  for (int c=0;c<C;++c){
    const float4 xa = *(const float4*)&xb[(size_t)c*NPTS + m0];
    const float4 xc = *(const float4*)&xb[(size_t)c*NPTS + m0 + 4];
    const float xm[8] = {xa.x,xa.y,xa.z,xa.w,xc.x,xc.y,xc.z,xc.w};
    #pragma unroll
    for (int i=0;i<8;++i){
      const float cv = ctrs[c][i];
      #pragma unroll
      for (int j=0;j<8;++j) acc[i][j] += cv*xm[j];
    }
  }
  {
    const float4 sa = *(const float4*)&sq[b*NPTS + m0];
    const float4 sb = *(const float4*)&sq[b*NPTS + m0 + 4];
    const float sm[8] = {sa.x,sa.y,sa.z,sa.w,sb.x,sb.y,sb.z,sb.w};
    #pragma unroll
    for (int i=0;i<8;++i){
      const float si = sqn[i];
      #pragma unroll
      for (int j=0;j<8;++j) acc[i][j] = 2.f*acc[i][j] - si - sm[j];
    }
  }

  const int wv = t >> 6, lane = t & 63;
  #pragma unroll
  for (int rep=0; rep<2; ++rep){
    #pragma unroll
    for (int i=0;i<4;++i){
      *(float4*)&dist[i][m0]   = make_float4(acc[rep*4+i][0],acc[rep*4+i][1],acc[rep*4+i][2],acc[rep*4+i][3]);
      *(float4*)&dist[i][m0+4] = make_float4(acc[rep*4+i][4],acc[rep*4+i][5],acc[rep*4+i][6],acc[rep*4+i][7]);
    }
    __syncthreads();
    // wave wv selects for point (rep*4 + wv); lane owns m = lane + 64*j, cached in regs
    float v[32];
    float lmax = NEG_INF; int lidx = 0x7fffffff;
    #pragma unroll
    for (int j=0;j<32;++j){
      v[j] = dist[wv][lane + 64*j];
      if (v[j] > lmax){ lmax = v[j]; lidx = lane + 64*j; }   // ascending m => first max kept
    }
    int* row = idxout + ((size_t)b*NPTS + n0 + rep*4 + wv)*KNN;
    for (int sel=0; sel<KNN; ++sel){
      float bv = lmax; int bi = lidx;
      #pragma unroll
      for (int off=32; off>0; off>>=1){
        float ov = __shfl_down(bv, off, 64);
        int   oi = __shfl_down(bi, off, 64);
        if (ov > bv || (ov == bv && oi < bi)){ bv = ov; bi = oi; }
      }
      const int widx = __shfl(bi, 0, 64);
      if (lane == 0) row[sel] = widx;
      if ((widx & 63) == lane){
        const int jj = widx >> 6;
        #pragma unroll
        for (int j=0;j<32;++j) if (j == jj) v[j] = NEG_INF;
        lmax = NEG_INF; lidx = 0x7fffffff;
        #pragma unroll
        for (int j=0;j<32;++j) if (v[j] > lmax){ lmax = v[j]; lidx = lane + 64*j; }
      }
    }
    __syncthreads();   // all waves done before the slab is overwritten (rep 1)
  }
}

// ---------------- fp32 weight prep (layer 1 only): wnT[c][o], wdT[c][o] ----------------
__global__ void wprep_kernel(const float* __restrict__ w, float* __restrict__ wnT,
                             float* __restrict__ wdT, int O, int C){
  int i = blockIdx.x*blockDim.x + threadIdx.x;
  if (i >= O*C) return;
  int c = i / O, o = i - c*O;
  float a = w[(size_t)o*2*C + c];
  wnT[(size_t)c*O + o] = a;
  wdT[(size_t)c*O + o] = w[(size_t)o*2*C + C + c] - a;
}

// ---------------- bf16 weight prep (layers 2-4): wn[o][c], wd[o][c] (k contiguous) -----
__global__ void wprep_bf_kernel(const float* __restrict__ w, unsigned short* __restrict__ wn,
                                unsigned short* __restrict__ wd, int O, int C){
  int i = blockIdx.x*blockDim.x + threadIdx.x;
  if (i >= O*C) return;
  int o = i / C, c = i - o*C;
  float a = w[(size_t)o*2*C + c];
  float d = w[(size_t)o*2*C + C + c] - a;
  wn[(size_t)o*C + c] = bf16r(a);
  wd[(size_t)o*C + c] = bf16r(d);
}

// ---------------- split-bf16 weight convert (conv5): hi = bf16(w), lo = bf16(w-hi) ------
__global__ void bfsplit_kernel(const float* __restrict__ in, unsigned short* __restrict__ hi,
                               unsigned short* __restrict__ lo, int nq){
  int i = blockIdx.x*blockDim.x + threadIdx.x;
  if (i >= nq) return;
  float4 v = *(const float4*)&in[(size_t)i*4];
  unsigned short h0=bf16r(v.x), h1=bf16r(v.y), h2=bf16r(v.z), h3=bf16r(v.w);
  unsigned short l0=bf16r(v.x-bf2f(h0)), l1=bf16r(v.y-bf2f(h1)),
                 l2=bf16r(v.z-bf2f(h2)), l3=bf16r(v.w-bf2f(h3));
  *(uint2*)&hi[(size_t)i*4] = make_uint2((unsigned)h0|((unsigned)h1<<16), (unsigned)h2|((unsigned)h3<<16));
  *(uint2*)&lo[(size_t)i*4] = make_uint2((unsigned)l0|((unsigned)l1<<16), (unsigned)l2|((unsigned)l3<<16));
}

// ---------------- xcat: concat x1T..x4T -> split-bf16 [b][n][512] ----------------
__global__ __launch_bounds__(256) void xcat_kernel(const float* __restrict__ x1T,
    const float* __restrict__ x2T, const float* __restrict__ x3T, const float* __restrict__ x4T,
    unsigned short* __restrict__ xhi, unsigned short* __restrict__ xlo){
  int i = blockIdx.x*blockDim.x + threadIdx.x;   // quad index over B*N*128
  if (i >= BATCH*NPTS*128) return;
  int q = i & 127, bn_ = i >> 7;
  int k = q*4;
  const float* src; int kk;
  if (k < 64)      { src = x1T + (size_t)bn_*64;  kk = k; }
  else if (k <128) { src = x2T + (size_t)bn_*64;  kk = k-64; }
  else if (k <256) { src = x3T + (size_t)bn_*128; kk = k-128; }
  else             { src = x4T + (size_t)bn_*256; kk = k-256; }
  float4 v = *(const float4*)&src[kk];
  unsigned short h0=bf16r(v.x), h1=bf16r(v.y), h2=bf16r(v.z), h3=bf16r(v.w);
  unsigned short l0=bf16r(v.x-bf2f(h0)), l1=bf16r(v.y-bf2f(h1)),
                 l2=bf16r(v.z-bf2f(h2)), l3=bf16r(v.w-bf2f(h3));
  *(uint2*)&xhi[(size_t)i*4] = make_uint2((unsigned)h0|((unsigned)h1<<16), (unsigned)h2|((unsigned)h3<<16));
  *(uint2*)&xlo[(size_t)i*4] = make_uint2((unsigned)l0|((unsigned)l1<<16), (unsigned)l2|((unsigned)l3<<16));
}

// ---------------- generic tiled transpose: in[R][Cc] -> out[Cc][R], per z-slice ----------------
__global__ __launch_bounds__(256) void transpose2d_kernel(const float* __restrict__ in,
    float* __restrict__ out, int R, int Cc){
  __shared__ float tile[32][33];
  const size_t boff = (size_t)blockIdx.z * (size_t)R * Cc;
  const int c0 = blockIdx.x*32, r0 = blockIdx.y*32;
  const int tx = threadIdx.x & 31, ty = threadIdx.x >> 5;
  #pragma unroll
  for (int j=0;j<4;++j){
    int r = ty*4 + j;
    tile[r][tx] = in[boff + (size_t)(r0+r)*Cc + c0 + tx];
  }
  __syncthreads();
  #pragma unroll
  for (int j=0;j<4;++j){
    int r = ty*4 + j;
    out[boff + (size_t)(c0+r)*R + r0 + tx] = tile[tx][r];
  }
}

// ---------------- x -> xT0 [N][3] ----------------
__global__ void xt0_kernel(const float* __restrict__ x, float* __restrict__ xT0){
  int i = blockIdx.x*blockDim.x + threadIdx.x;
  if (i >= BATCH*NPTS) return;
  int b = i / NPTS, n = i - b*NPTS;
  const float* xb = x + (size_t)b*3*NPTS;
  float v0 = xb[n], v1 = xb[NPTS + n], v2 = xb[2*NPTS + n];
  float* o = xT0 + ((size_t)b*NPTS + n)*3;
  o[0]=v0; o[1]=v1; o[2]=v2;
}

// ---------------- edge conv layer 1 (C=3, fp32): 4 points per block ----------------
__global__ __launch_bounds__(256) void edgeconv1_kernel(const float* __restrict__ xT0,
    const int* __restrict__ idx, const float* __restrict__ wnT, const float* __restrict__ wdT,
    const float* __restrict__ g, const float* __restrict__ bb, float* __restrict__ outT){
  const int b = blockIdx.y, n0 = blockIdx.x*4, t = threadIdx.x;
  __shared__ float nbr[4][KNN][3];
  __shared__ float ctr[4][3];
  __shared__ int   idxs[4][KNN];
  const float* xb = xT0 + (size_t)b*NPTS*3;
  if (t < 4*KNN) idxs[t/KNN][t%KNN] = idx[((size_t)b*NPTS + n0 + t/KNN)*KNN + (t%KNN)];
  if (t >= 128 && t < 140){ int i = t-128; ctr[i/3][i%3] = xb[(size_t)(n0 + i/3)*3 + i%3]; }
  __syncthreads();
  for (int i=t; i<4*KNN*3; i+=256){
    int p = i/(KNN*3), r = i - p*(KNN*3), k = r/3, c = r - k*3;
    nbr[p][k][c] = xb[(size_t)idxs[p][k]*3 + c];
  }
  __syncthreads();
  const int p = t >> 6, o = t & 63;
  const float wn0 = wnT[o], wn1 = wnT[64+o], wn2 = wnT[128+o];
  const float cst = ctr[p][0]*wdT[o] + ctr[p][1]*wdT[64+o] + ctr[p][2]*wdT[128+o];
  float best = NEG_INF;
  #pragma unroll
  for (int k=0;k<KNN;++k){
    float a = nbr[p][k][0]*wn0 + nbr[p][k][1]*wn1 + nbr[p][k][2]*wn2;
    best = fmaxf(best, a);
  }
  float vv = (best + cst) * bn_scale(g[o]) + bb[o];
  outT[((size_t)b*NPTS + n0 + p)*64 + o] = fmaxf(vv, 0.f);
}

// ---------------- edge conv MFMA (bf16): block = 4 points ----------------
template<int C, int O>
__global__ __launch_bounds__(256) void edgeconv_mfma(const float* __restrict__ xT,
    const int* __restrict__ idx,
    const unsigned short* __restrict__ wn_bf, const unsigned short* __restrict__ wd_bf,
    const float* __restrict__ g, const float* __restrict__ bb, float* __restrict__ outT){
  constexpr int ROWS = 112;        // 7 m-tiles of 16
  constexpr int CP   = C + 8;      // padded row (bf16): 16B-aligned stride, conflict-free b128
  constexpr int KS   = C / 32;     // k-steps per tile
  constexpr int NTW  = O / 64;     // n-tiles per wave (O/16 tiles over 4 waves)
  __shared__ __align__(16) unsigned short A[ROWS][CP];
  __shared__ unsigned int res[4][O];
  __shared__ float cst_s[4][O];
  __shared__ int idxs[4][KNN];
  const int b = blockIdx.y, n0 = blockIdx.x*4, t = threadIdx.x;
  const float* xTb = xT + (size_t)b*NPTS*C;
  if (t < 4*KNN) idxs[t/KNN][t%KNN] = idx[((size_t)b*NPTS + n0 + t/KNN)*KNN + (t%KNN)];
  for (int i=t; i<4*O; i+=256) res[i/O][i & (O-1)] = 0u;   // 0 < fenc(any finite)
  __syncthreads();
  for (int i=t; i<ROWS*(C/4); i+=256){
    int r = i/(C/4), c4 = i - r*(C/4);
    float4 v = make_float4(0.f,0.f,0.f,0.f);
    if (r < 96){
      int p = r/24, kk = r - p*24;
      int src = idxs[p][kk < KNN ? kk : 0];        // pad rows duplicate nbr 0 (max-neutral)
      v = *(const float4*)&xTb[(size_t)src*C + c4*4];
    } else if (r < 100){
      v = *(const float4*)&xTb[(size_t)(n0 + (r-96))*C + c4*4];
    }
    unsigned int lo = (unsigned int)bf16r(v.x) | ((unsigned int)bf16r(v.y) << 16);
    unsigned int hi = (unsigned int)bf16r(v.z) | ((unsigned int)bf16r(v.w) << 16);
    *(uint2*)&A[r][c4*4] = make_uint2(lo, hi);
  }
  __syncthreads();

  const int wv = t >> 6, l = t & 63;
  const int lane15 = l & 15, quad = l >> 4;
  bfrag Bn[NTW][KS];
  #pragma unroll
  for (int nt=0; nt<NTW; ++nt){
    const int col = (wv*NTW + nt)*16 + lane15;
    #pragma unroll
    for (int s=0; s<KS; ++s)
      Bn[nt][s] = *(const bfrag*)&wn_bf[(size_t)col*C + s*32 + quad*8];
  }
  #pragma unroll
  for (int mt=0; mt<7; ++mt){
    bfrag Af[KS];
    #pragma unroll
    for (int s=0; s<KS; ++s)
      Af[s] = *(const bfrag*)&A[mt*16 + lane15][s*32 + quad*8];
    if (mt < 6){
      const int rbase = mt*16 + quad*4;
      const int p = rbase / 24;
      #pragma unroll
      for (int nt=0; nt<NTW; ++nt){
        f32x4 acc = {0.f,0.f,0.f,0.f};
        #pragma unroll
        for (int s=0; s<KS; ++s)
          acc = __builtin_amdgcn_mfma_f32_16x16x32_bf16(Af[s], Bn[nt][s], acc, 0, 0, 0);
        float m = fmaxf(fmaxf(acc[0], acc[1]), fmaxf(acc[2], acc[3]));
        const int col = (wv*NTW + nt)*16 + lane15;
        atomicMax(&res[p][col], fenc(m));
      }
    } else {
      #pragma unroll
      for (int nt=0; nt<NTW; ++nt){
        const int col = (wv*NTW + nt)*16 + lane15;
        f32x4 acc = {0.f,0.f,0.f,0.f};
        #pragma unroll
        for (int s=0; s<KS; ++s){
          bfrag Bd = *(const bfrag*)&wd_bf[(size_t)col*C + s*32 + quad*8];
          acc = __builtin_amdgcn_mfma_f32_16x16x32_bf16(Af[s], Bd, acc, 0, 0, 0);
        }
        if (quad == 0){
          #pragma unroll
          for (int r=0;r<4;++r) cst_s[r][col] = acc[r];
        }
      }
    }
  }
  __syncthreads();
  for (int i=t; i<4*O; i+=256){
    int p = i/O, o = i - p*O;
    float mx = fdec(res[p][o]);
    float vv = (mx + cst_s[p][o]) * bn_scale(g[o]) + bb[o];
    outT[((size_t)b*NPTS + n0 + p)*O + o] = fmaxf(vv, 0.f);
  }
}

// ---------------- conv5 v3: LDS-staged split-bf16 MFMA GEMM + max over n ----------------
__global__ __launch_bounds__(256) void conv5_v3(const unsigned short* __restrict__ xhi,
    const unsigned short* __restrict__ xlo, const unsigned short* __restrict__ whi,
    const unsigned short* __restrict__ wlo, const float* __restrict__ g,
    const float* __restrict__ bb, float* __restrict__ out5){
  __shared__ __align__(16) unsigned short Ah_s[128*32];
  __shared__ __align__(16) unsigned short Al_s[128*32];
  __shared__ __align__(16) unsigned short Bh_s[64*32];
  __shared__ __align__(16) unsigned short Bl_s[64*32];
  const int t = threadIdx.x;
  const int row0 = blockIdx.x*128, o0 = blockIdx.y*64;
  const int b = row0 / NPTS;   // 128 | NPTS, so a block never straddles batches
  const int wv = t >> 6, l = t & 63, lane15 = l & 15, quad = l >> 4;
  const int ar = t >> 2, ac = (t & 3)*8;
  const unsigned short* gAh0 = xhi + (size_t)(row0 + ar)*512 + ac;
  const unsigned short* gAh1 = xhi + (size_t)(row0 + 64 + ar)*512 + ac;
  const unsigned short* gAl0 = xlo + (size_t)(row0 + ar)*512 + ac;
  const unsigned short* gAl1 = xlo + (size_t)(row0 + 64 + ar)*512 + ac;
  const unsigned short* gBh  = whi + (size_t)(o0 + ar)*512 + ac;
  const unsigned short* gBl  = wlo + (size_t)(o0 + ar)*512 + ac;

  uint4 pf0 = *(const uint4*)gAh0;
  uint4 pf1 = *(const uint4*)gAh1;
  uint4 pf2 = *(const uint4*)gAl0;
  uint4 pf3 = *(const uint4*)gAl1;
  uint4 pf4 = *(const uint4*)gBh;
  uint4 pf5 = *(const uint4*)gBl;

  f32x4 acc[2][4];
  #pragma unroll
  for (int mt=0;mt<2;++mt)
    #pragma unroll
    for (int nt=0;nt<4;++nt) acc[mt][nt] = (f32x4){0.f,0.f,0.f,0.f};

  for (int ks=0; ks<16; ++ks){
    *(uint4*)&Ah_s[t*8]        = pf0;
    *(uint4*)&Ah_s[2048 + t*8] = pf1;
    *(uint4*)&Al_s[t*8]        = pf2;
    *(uint4*)&Al_s[2048 + t*8] = pf3;
    *(uint4*)&Bh_s[t*8]        = pf4;
    *(uint4*)&Bl_s[t*8]        = pf5;
    __syncthreads();
    if (ks < 15){
      const int koff = (ks+1)*32;
      pf0 = *(const uint4*)(gAh0 + koff);
      pf1 = *(const uint4*)(gAh1 + koff);
      pf2 = *(const uint4*)(gAl0 + koff);
      pf3 = *(const uint4*)(gAl1 + koff);
      pf4 = *(const uint4*)(gBh  + koff);
      pf5 = *(const uint4*)(gBl  + koff);
    }
    bfrag Afh[2], Afl[2], Bfh[4], Bfl[4];
    #pragma unroll
    for (int mt=0;mt<2;++mt){
      const int m = wv*32 + mt*16 + lane15;
      Afh[mt] = *(const bfrag*)&Ah_s[m*32 + quad*8];
      Afl[mt] = *(const bfrag*)&Al_s[m*32 + quad*8];
    }
    #pragma unroll
    for (int nt=0;nt<4;++nt){
      const int oc = nt*16 + lane15;
      Bfh[nt] = *(const bfrag*)&Bh_s[oc*32 + quad*8];
      Bfl[nt] = *(const bfrag*)&Bl_s[oc*32 + quad*8];
    }
    #pragma unroll
    for (int mt=0;mt<2;++mt)
      #pragma unroll
      for (int nt=0;nt<4;++nt){
        acc[mt][nt] = __builtin_amdgcn_mfma_f32_16x16x32_bf16(Afh[mt], Bfh[nt], acc[mt][nt], 0, 0, 0);
        acc[mt][nt] = __builtin_amdgcn_mfma_f32_16x16x32_bf16(Afl[mt], Bfh[nt], acc[mt][nt], 0, 0, 0);
        acc[mt][nt] = __builtin_amdgcn_mfma_f32_16x16x32_bf16(Afh[mt], Bfl[nt], acc[mt][nt], 0, 0, 0);
      }
    __syncthreads();
  }
  #pragma unroll
  for (int nt=0;nt<4;++nt){
    float m = NEG_INF;
    #pragma unroll
    for (int mt=0;mt<2;++mt)
      #pragma unroll
      for (int r=0;r<4;++r) m = fmaxf(m, acc[mt][nt][r]);
    m = fmaxf(m, __shfl_xor(m, 16, 64));
    m = fmaxf(m, __shfl_xor(m, 32, 64));
    if (quad == 0){
      const int o = o0 + nt*16 + lane15;
      float vv = fmaxf(m * bn_scale(g[o]) + bb[o], 0.f);
      atomicMax((int*)&out5[(size_t)b*1024 + o], __float_as_int(vv));
    }
  }
}

__global__ void zero_kernel(float* __restrict__ p, int nfloats){
  int i = blockIdx.x*blockDim.x + threadIdx.x;
  if (i < nfloats) p[i] = 0.f;
}

// ---------------- FC layers ----------------
__global__ void fc_kernel(const float* __restrict__ in, const float* __restrict__ w,
                          const float* __restrict__ g, const float* __restrict__ bb,
                          float* __restrict__ out, int IN, int O){
  int i = blockIdx.x*blockDim.x + threadIdx.x;
  if (i >= BATCH*O) return;
  int b = i / O, o = i - b*O;
  const float* inb = in + (size_t)b*IN;
  const float* wo  = w + (size_t)o*IN;
  float s = 0.f;
  for (int c=0;c<IN;++c) s += inb[c]*wo[c];
  if (g){ s = s*bn_scale(g[o]) + bb[o]; s = fmaxf(s, 0.f); }
  out[i] = s;
}

extern "C" void kernel_launch(void* const* d_in, const int* in_sizes, int n_in,
                              void* d_out, int out_size, void* d_ws, size_t ws_size,
                              hipStream_t stream){
  const float* x   = (const float*)d_in[0];
  const float* w1  = (const float*)d_in[1];
  const float* w2  = (const float*)d_in[2];
  const float* w3  = (const float*)d_in[3];
  const float* w4  = (const float*)d_in[4];
  const float* w5  = (const float*)d_in[5];
  const float* fw1 = (const float*)d_in[6];
  const float* fw2 = (const float*)d_in[7];
  const float* fw3 = (const float*)d_in[8];
  const float* g1 = (const float*)d_in[9];  const float* b1 = (const float*)d_in[10];
  const float* g2 = (const float*)d_in[11]; const float* b2 = (const float*)d_in[12];
  const float* g3 = (const float*)d_in[13]; const float* b3 = (const float*)d_in[14];
  const float* g4 = (const float*)d_in[15]; const float* b4 = (const float*)d_in[16];
  const float* g5 = (const float*)d_in[17]; const float* b5 = (const float*)d_in[18];
  const float* g6 = (const float*)d_in[19]; const float* b6 = (const float*)d_in[20];
  const float* g7 = (const float*)d_in[21]; const float* b7 = (const float*)d_in[22];

  float* ws = (float*)d_ws;
  size_t off = 0;
  // x1..x3 channel-major; this 4.19M-float region is later reused as xcat_lo
  float* x1  = ws + off; off += (size_t)BATCH*64*NPTS;
  float* x2  = ws + off; off += (size_t)BATCH*64*NPTS;
  float* x3  = ws + off; off += (size_t)BATCH*128*NPTS;
  unsigned short* xcat_lo = (unsigned short*)x1;           // alias: x1..x3 dead before xcat runs
  unsigned short* xcat_hi = (unsigned short*)(ws + off); off += (size_t)BATCH*256*NPTS; // = B*N*512 bf16
  float* x1T = ws + off; off += (size_t)BATCH*64*NPTS;
  float* x2T = ws + off; off += (size_t)BATCH*64*NPTS;
  float* x3T = ws + off; off += (size_t)BATCH*128*NPTS;
  float* x4T = ws + off; off += (size_t)BATCH*256*NPTS;
  float* xT0 = ws + off; off += (size_t)BATCH*3*NPTS;
  float* sq  = ws + off; off += (size_t)BATCH*NPTS;
  int*  idx  = (int*)(ws + off); off += (size_t)BATCH*NPTS*KNN;
  float* out5 = ws + off; off += BATCH*1024;
  float* h6 = ws + off;   off += BATCH*512;
  float* h7 = ws + off;   off += BATCH*256;
  float* wnT1 = ws + off; off += 3*64;
  float* wdT1 = ws + off; off += 3*64;
  unsigned short* wn2 = (unsigned short*)(ws + off); off += 64*64/2;
  unsigned short* wd2 = (unsigned short*)(ws + off); off += 64*64/2;
  unsigned short* wn3 = (unsigned short*)(ws + off); off += 128*64/2;
  unsigned short* wd3 = (unsigned short*)(ws + off); off += 128*64/2;
  unsigned short* wn4 = (unsigned short*)(ws + off); off += 256*128/2;
  unsigned short* wd4 = (unsigned short*)(ws + off); off += 256*128/2;
  unsigned short* w5hi = (unsigned short*)(ws + off); off += 1024*512/2;
  unsigned short* w5lo = (unsigned short*)(ws + off); off += 1024*512/2;

  dim3 gridKNN(NPTS/8, BATCH);
  dim3 gridEC(NPTS/4, BATCH);

  // layer 1 (C=3 -> 64, fp32)
  xt0_kernel<<<64, 256, 0, stream>>>(x, xT0);
  sqnorm_kernel<<<64, 256, 0, stream>>>(x, sq, 3);
  knn_kernel<3><<<gridKNN, 256, 0, stream>>>(x, sq, idx);
  wprep_kernel<<<1, 256, 0, stream>>>(w1, wnT1, wdT1, 64, 3);
  edgeconv1_kernel<<<gridEC, 256, 0, stream>>>(xT0, idx, wnT1, wdT1, g1, b1, x1T);
  transpose2d_kernel<<<dim3(2,64,BATCH), 256, 0, stream>>>(x1T, x1, NPTS, 64);
  // layer 2 (C=64 -> 64, bf16 MFMA)
  sqnorm_kernel<<<64, 256, 0, stream>>>(x1, sq, 64);
  knn_kernel<64><<<gridKNN, 256, 0, stream>>>(x1, sq, idx);
  wprep_bf_kernel<<<16, 256, 0, stream>>>(w2, wn2, wd2, 64, 64);
  edgeconv_mfma<64,64><<<gridEC, 256, 0, stream>>>(x1T, idx, wn2, wd2, g2, b2, x2T);
  transpose2d_kernel<<<dim3(2,64,BATCH), 256, 0, stream>>>(x2T, x2, NPTS, 64);
  // layer 3 (C=64 -> 128, bf16 MFMA)
  sqnorm_kernel<<<64, 256, 0, stream>>>(x2, sq, 64);
  knn_kernel<64><<<gridKNN, 256, 0, stream>>>(x2, sq, idx);
  wprep_bf_kernel<<<32, 256, 0, stream>>>(w3, wn3, wd3, 128, 64);
  edgeconv_mfma<64,128><<<gridEC, 256, 0, stream>>>(x2T, idx, wn3, wd3, g3, b3, x3T);
  transpose2d_kernel<<<dim3(4,64,BATCH), 256, 0, stream>>>(x3T, x3, NPTS, 128);
  // layer 4 (C=128 -> 256, bf16 MFMA)
  sqnorm_kernel<<<64, 256, 0, stream>>>(x3, sq, 128);
  knn_kernel<128><<<gridKNN, 256, 0, stream>>>(x3, sq, idx);
  wprep_bf_kernel<<<128, 256, 0, stream>>>(w4, wn4, wd4, 256, 128);
  edgeconv_mfma<128,256><<<gridEC, 256, 0, stream>>>(x3T, idx, wn4, wd4, g4, b4, x4T);
  // conv5 (split-bf16 MFMA, LDS-staged) + global max over n
  xcat_kernel<<<(BATCH*NPTS*128)/256, 256, 0, stream>>>(x1T, x2T, x3T, x4T, xcat_hi, xcat_lo);
  bfsplit_kernel<<<512, 256, 0, stream>>>(w5, w5hi, w5lo, 1024*512/4);
  zero_kernel<<<32, 256, 0, stream>>>(out5, BATCH*1024);
  conv5_v3<<<dim3(BATCH*NPTS/128, 16), 256, 0, stream>>>(xcat_hi, xcat_lo, w5hi, w5lo, g5, b5, out5);
  // FC head
  fc_kernel<<<16, 256, 0, stream>>>(out5, fw1, g6, b6, h6, 1024, 512);
  fc_kernel<<<8, 256, 0, stream>>>(h6, fw2, g7, b7, h7, 512, 256);
  fc_kernel<<<2, 256, 0, stream>>>(h7, fw3, nullptr, nullptr, (float*)d_out, 256, 40);
}

// Round 12
// 1226.258 us; speedup vs baseline: 1.1634x; 1.1411x over previous
//
#include <hip/hip_runtime.h>
#include <hip/hip_bf16.h>
#include <math.h>

#define BATCH 8
#define NPTS  2048
#define KNN   20
#define NEG_INF (-3.402823466e38f)

static __device__ __forceinline__ float bn_scale(float g){ return g * rsqrtf(1.0f + 1e-5f); }

// bf16 round-to-nearest-even
static __device__ __forceinline__ unsigned short bf16r(float f){
  unsigned int u = __float_as_uint(f);
  unsigned int r = (u + 0x7fffu + ((u >> 16) & 1u)) >> 16;
  return (unsigned short)r;
}
static __device__ __forceinline__ float bf2f(unsigned short h){
  return __uint_as_float((unsigned int)h << 16);
}
// ordered-int encode/decode for float max via atomicMax(uint)
static __device__ __forceinline__ unsigned int fenc(float f){
  unsigned int u = __float_as_uint(f);
  return (u & 0x80000000u) ? ~u : (u | 0x80000000u);
}
static __device__ __forceinline__ float fdec(unsigned int e){
  return __uint_as_float((e & 0x80000000u) ? (e & 0x7fffffffu) : ~e);
}

using bfrag = __attribute__((ext_vector_type(8))) short;  // 8 bf16 (4 VGPRs)
using f32x4 = __attribute__((ext_vector_type(4))) float;  // 4 fp32 acc

// ---------------- squared norms per point (reads channel-major [C][N]) ----------------
__global__ void sqnorm_kernel(const float* __restrict__ X, float* __restrict__ sq, int C){
  int i = blockIdx.x*blockDim.x + threadIdx.x;
  if (i >= BATCH*NPTS) return;
  int b = i / NPTS, n = i - b*NPTS;
  const float* xb = X + (size_t)b*C*NPTS + n;
  float s = 0.f;
  for (int c=0;c<C;++c){ float v = xb[(size_t)c*NPTS]; s += v*v; }
  sq[i] = s;
}

// ---------------- kNN v3 (round-7 best): no spills, LDS-based selection ----------
// Established local optimum: r8 (LDS stash) lost to occupancy, r9 (reg stash) to VGPR,
// r10 (MFMA dist) to dependent-load latency, r11 (reg cache) to VGPR/latency.
template<int C>
__global__ __launch_bounds__(256, 2) void knn_kernel(const float* __restrict__ X,
                                                     const float* __restrict__ sq,
                                                     int* __restrict__ idxout){
  const int b = blockIdx.y;
  const int n0 = blockIdx.x * 8;
  const int t = threadIdx.x;
  __shared__ __align__(16) float dist[4][NPTS];
  __shared__ float ctrs[C][8];
  __shared__ float sqn[8];
  const float* xb = X + (size_t)b*C*NPTS;
  for (int i=t; i<C*8; i+=256){
    int c = i >> 3, p = i & 7;
    ctrs[c][p] = xb[(size_t)c*NPTS + n0 + p];
  }
  if (t < 8) sqn[t] = sq[b*NPTS + n0 + t];
  __syncthreads();

  const int m0 = t * 8;
  float acc[8][8];
  #pragma unroll
  for (int i=0;i<8;++i)
    #pragma unroll
    for (int j=0;j<8;++j) acc[i][j] = 0.f;
  for (int c=0;c<C;++c){
    const float4 xa = *(const float4*)&xb[(size_t)c*NPTS + m0];
    const float4 xc = *(const float4*)&xb[(size_t)c*NPTS + m0 + 4];
    const float xm[8] = {xa.x,xa.y,xa.z,xa.w,xc.x,xc.y,xc.z,xc.w};
    #pragma unroll
    for (int i=0;i<8;++i){
      const float cv = ctrs[c][i];
      #pragma unroll
      for (int j=0;j<8;++j) acc[i][j] += cv*xm[j];
    }
  }
  {
    const float4 sa = *(const float4*)&sq[b*NPTS + m0];
    const float4 sb = *(const float4*)&sq[b*NPTS + m0 + 4];
    const float sm[8] = {sa.x,sa.y,sa.z,sa.w,sb.x,sb.y,sb.z,sb.w};
    #pragma unroll
    for (int i=0;i<8;++i){
      const float si = sqn[i];
      #pragma unroll
      for (int j=0;j<8;++j) acc[i][j] = 2.f*acc[i][j] - si - sm[j];
    }
  }

  const int wv = t >> 6, lane = t & 63;
  #pragma unroll
  for (int rep=0; rep<2; ++rep){
    #pragma unroll
    for (int i=0;i<4;++i){
      *(float4*)&dist[i][m0]   = make_float4(acc[rep*4+i][0],acc[rep*4+i][1],acc[rep*4+i][2],acc[rep*4+i][3]);
      *(float4*)&dist[i][m0+4] = make_float4(acc[rep*4+i][4],acc[rep*4+i][5],acc[rep*4+i][6],acc[rep*4+i][7]);
    }
    __syncthreads();
    float lmax = NEG_INF; int lidx = 0x7fffffff;
    #pragma unroll
    for (int j=0;j<32;++j){
      float vv = dist[wv][lane + 64*j];
      if (vv > lmax){ lmax = vv; lidx = lane + 64*j; }
    }
    int* row = idxout + ((size_t)b*NPTS + n0 + rep*4 + wv)*KNN;
    for (int sel=0; sel<KNN; ++sel){
      float bv = lmax; int bi = lidx;
      #pragma unroll
      for (int off=32; off>0; off>>=1){
        float ov = __shfl_down(bv, off, 64);
        int   oi = __shfl_down(bi, off, 64);
        if (ov > bv || (ov == bv && oi < bi)){ bv = ov; bi = oi; }
      }
      const int widx = __shfl(bi, 0, 64);
      if (lane == 0) row[sel] = widx;
      if ((widx & 63) == lane){
        dist[wv][widx] = NEG_INF;
        lmax = NEG_INF; lidx = 0x7fffffff;
        #pragma unroll
        for (int j=0;j<32;++j){
          float vv = dist[wv][lane + 64*j];
          if (vv > lmax){ lmax = vv; lidx = lane + 64*j; }
        }
      }
    }
    __syncthreads();
  }
}

// ---------------- fp32 weight prep (layer 1 only): wnT[c][o], wdT[c][o] ----------------
__global__ void wprep_kernel(const float* __restrict__ w, float* __restrict__ wnT,
                             float* __restrict__ wdT, int O, int C){
  int i = blockIdx.x*blockDim.x + threadIdx.x;
  if (i >= O*C) return;
  int c = i / O, o = i - c*O;
  float a = w[(size_t)o*2*C + c];
  wnT[(size_t)c*O + o] = a;
  wdT[(size_t)c*O + o] = w[(size_t)o*2*C + C + c] - a;
}

// ---------------- bf16 weight prep (layers 2-4): wn[o][c], wd[o][c] (k contiguous) -----
__global__ void wprep_bf_kernel(const float* __restrict__ w, unsigned short* __restrict__ wn,
                                unsigned short* __restrict__ wd, int O, int C){
  int i = blockIdx.x*blockDim.x + threadIdx.x;
  if (i >= O*C) return;
  int o = i / C, c = i - o*C;
  float a = w[(size_t)o*2*C + c];
  float d = w[(size_t)o*2*C + C + c] - a;
  wn[(size_t)o*C + c] = bf16r(a);
  wd[(size_t)o*C + c] = bf16r(d);
}

// ---------------- split-bf16 weight convert (conv5): hi = bf16(w), lo = bf16(w-hi) ------
__global__ void bfsplit_kernel(const float* __restrict__ in, unsigned short* __restrict__ hi,
                               unsigned short* __restrict__ lo, int nq){
  int i = blockIdx.x*blockDim.x + threadIdx.x;
  if (i >= nq) return;
  float4 v = *(const float4*)&in[(size_t)i*4];
  unsigned short h0=bf16r(v.x), h1=bf16r(v.y), h2=bf16r(v.z), h3=bf16r(v.w);
  unsigned short l0=bf16r(v.x-bf2f(h0)), l1=bf16r(v.y-bf2f(h1)),
                 l2=bf16r(v.z-bf2f(h2)), l3=bf16r(v.w-bf2f(h3));
  *(uint2*)&hi[(size_t)i*4] = make_uint2((unsigned)h0|((unsigned)h1<<16), (unsigned)h2|((unsigned)h3<<16));
  *(uint2*)&lo[(size_t)i*4] = make_uint2((unsigned)l0|((unsigned)l1<<16), (unsigned)l2|((unsigned)l3<<16));
}

// ---------------- xcat: concat x1T..x4T -> split-bf16 [b][n][512] ----------------
__global__ __launch_bounds__(256) void xcat_kernel(const float* __restrict__ x1T,
    const float* __restrict__ x2T, const float* __restrict__ x3T, const float* __restrict__ x4T,
    unsigned short* __restrict__ xhi, unsigned short* __restrict__ xlo){
  int i = blockIdx.x*blockDim.x + threadIdx.x;   // quad index over B*N*128
  if (i >= BATCH*NPTS*128) return;
  int q = i & 127, bn_ = i >> 7;
  int k = q*4;
  const float* src; int kk;
  if (k < 64)      { src = x1T + (size_t)bn_*64;  kk = k; }
  else if (k <128) { src = x2T + (size_t)bn_*64;  kk = k-64; }
  else if (k <256) { src = x3T + (size_t)bn_*128; kk = k-128; }
  else             { src = x4T + (size_t)bn_*256; kk = k-256; }
  float4 v = *(const float4*)&src[kk];
  unsigned short h0=bf16r(v.x), h1=bf16r(v.y), h2=bf16r(v.z), h3=bf16r(v.w);
  unsigned short l0=bf16r(v.x-bf2f(h0)), l1=bf16r(v.y-bf2f(h1)),
                 l2=bf16r(v.z-bf2f(h2)), l3=bf16r(v.w-bf2f(h3));
  *(uint2*)&xhi[(size_t)i*4] = make_uint2((unsigned)h0|((unsigned)h1<<16), (unsigned)h2|((unsigned)h3<<16));
  *(uint2*)&xlo[(size_t)i*4] = make_uint2((unsigned)l0|((unsigned)l1<<16), (unsigned)l2|((unsigned)l3<<16));
}

// ---------------- generic tiled transpose: in[R][Cc] -> out[Cc][R], per z-slice ----------------
__global__ __launch_bounds__(256) void transpose2d_kernel(const float* __restrict__ in,
    float* __restrict__ out, int R, int Cc){
  __shared__ float tile[32][33];
  const size_t boff = (size_t)blockIdx.z * (size_t)R * Cc;
  const int c0 = blockIdx.x*32, r0 = blockIdx.y*32;
  const int tx = threadIdx.x & 31, ty = threadIdx.x >> 5;
  #pragma unroll
  for (int j=0;j<4;++j){
    int r = ty*4 + j;
    tile[r][tx] = in[boff + (size_t)(r0+r)*Cc + c0 + tx];
  }
  __syncthreads();
  #pragma unroll
  for (int j=0;j<4;++j){
    int r = ty*4 + j;
    out[boff + (size_t)(c0+r)*R + r0 + tx] = tile[tx][r];
  }
}

// ---------------- x -> xT0 [N][3] ----------------
__global__ void xt0_kernel(const float* __restrict__ x, float* __restrict__ xT0){
  int i = blockIdx.x*blockDim.x + threadIdx.x;
  if (i >= BATCH*NPTS) return;
  int b = i / NPTS, n = i - b*NPTS;
  const float* xb = x + (size_t)b*3*NPTS;
  float v0 = xb[n], v1 = xb[NPTS + n], v2 = xb[2*NPTS + n];
  float* o = xT0 + ((size_t)b*NPTS + n)*3;
  o[0]=v0; o[1]=v1; o[2]=v2;
}

// ---------------- edge conv layer 1 (C=3, fp32): 4 points per block ----------------
__global__ __launch_bounds__(256) void edgeconv1_kernel(const float* __restrict__ xT0,
    const int* __restrict__ idx, const float* __restrict__ wnT, const float* __restrict__ wdT,
    const float* __restrict__ g, const float* __restrict__ bb, float* __restrict__ outT){
  const int b = blockIdx.y, n0 = blockIdx.x*4, t = threadIdx.x;
  __shared__ float nbr[4][KNN][3];
  __shared__ float ctr[4][3];
  __shared__ int   idxs[4][KNN];
  const float* xb = xT0 + (size_t)b*NPTS*3;
  if (t < 4*KNN) idxs[t/KNN][t%KNN] = idx[((size_t)b*NPTS + n0 + t/KNN)*KNN + (t%KNN)];
  if (t >= 128 && t < 140){ int i = t-128; ctr[i/3][i%3] = xb[(size_t)(n0 + i/3)*3 + i%3]; }
  __syncthreads();
  for (int i=t; i<4*KNN*3; i+=256){
    int p = i/(KNN*3), r = i - p*(KNN*3), k = r/3, c = r - k*3;
    nbr[p][k][c] = xb[(size_t)idxs[p][k]*3 + c];
  }
  __syncthreads();
  const int p = t >> 6, o = t & 63;
  const float wn0 = wnT[o], wn1 = wnT[64+o], wn2 = wnT[128+o];
  const float cst = ctr[p][0]*wdT[o] + ctr[p][1]*wdT[64+o] + ctr[p][2]*wdT[128+o];
  float best = NEG_INF;
  #pragma unroll
  for (int k=0;k<KNN;++k){
    float a = nbr[p][k][0]*wn0 + nbr[p][k][1]*wn1 + nbr[p][k][2]*wn2;
    best = fmaxf(best, a);
  }
  float vv = (best + cst) * bn_scale(g[o]) + bb[o];
  outT[((size_t)b*NPTS + n0 + p)*64 + o] = fmaxf(vv, 0.f);
}

// ---------------- edge conv MFMA (bf16): block = 4 points ----------------
template<int C, int O>
__global__ __launch_bounds__(256) void edgeconv_mfma(const float* __restrict__ xT,
    const int* __restrict__ idx,
    const unsigned short* __restrict__ wn_bf, const unsigned short* __restrict__ wd_bf,
    const float* __restrict__ g, const float* __restrict__ bb, float* __restrict__ outT){
  constexpr int ROWS = 112;        // 7 m-tiles of 16
  constexpr int CP   = C + 8;      // padded row (bf16): 16B-aligned stride, conflict-free b128
  constexpr int KS   = C / 32;     // k-steps per tile
  constexpr int NTW  = O / 64;     // n-tiles per wave (O/16 tiles over 4 waves)
  __shared__ __align__(16) unsigned short A[ROWS][CP];
  __shared__ unsigned int res[4][O];
  __shared__ float cst_s[4][O];
  __shared__ int idxs[4][KNN];
  const int b = blockIdx.y, n0 = blockIdx.x*4, t = threadIdx.x;
  const float* xTb = xT + (size_t)b*NPTS*C;
  if (t < 4*KNN) idxs[t/KNN][t%KNN] = idx[((size_t)b*NPTS + n0 + t/KNN)*KNN + (t%KNN)];
  for (int i=t; i<4*O; i+=256) res[i/O][i & (O-1)] = 0u;   // 0 < fenc(any finite)
  __syncthreads();
  for (int i=t; i<ROWS*(C/4); i+=256){
    int r = i/(C/4), c4 = i - r*(C/4);
    float4 v = make_float4(0.f,0.f,0.f,0.f);
    if (r < 96){
      int p = r/24, kk = r - p*24;
      int src = idxs[p][kk < KNN ? kk : 0];        // pad rows duplicate nbr 0 (max-neutral)
      v = *(const float4*)&xTb[(size_t)src*C + c4*4];
    } else if (r < 100){
      v = *(const float4*)&xTb[(size_t)(n0 + (r-96))*C + c4*4];
    }
    unsigned int lo = (unsigned int)bf16r(v.x) | ((unsigned int)bf16r(v.y) << 16);
    unsigned int hi = (unsigned int)bf16r(v.z) | ((unsigned int)bf16r(v.w) << 16);
    *(uint2*)&A[r][c4*4] = make_uint2(lo, hi);
  }
  __syncthreads();

  const int wv = t >> 6, l = t & 63;
  const int lane15 = l & 15, quad = l >> 4;
  bfrag Bn[NTW][KS];
  #pragma unroll
  for (int nt=0; nt<NTW; ++nt){
    const int col = (wv*NTW + nt)*16 + lane15;
    #pragma unroll
    for (int s=0; s<KS; ++s)
      Bn[nt][s] = *(const bfrag*)&wn_bf[(size_t)col*C + s*32 + quad*8];
  }
  #pragma unroll
  for (int mt=0; mt<7; ++mt){
    bfrag Af[KS];
    #pragma unroll
    for (int s=0; s<KS; ++s)
      Af[s] = *(const bfrag*)&A[mt*16 + lane15][s*32 + quad*8];
    if (mt < 6){
      const int rbase = mt*16 + quad*4;
      const int p = rbase / 24;
      #pragma unroll
      for (int nt=0; nt<NTW; ++nt){
        f32x4 acc = {0.f,0.f,0.f,0.f};
        #pragma unroll
        for (int s=0; s<KS; ++s)
          acc = __builtin_amdgcn_mfma_f32_16x16x32_bf16(Af[s], Bn[nt][s], acc, 0, 0, 0);
        float m = fmaxf(fmaxf(acc[0], acc[1]), fmaxf(acc[2], acc[3]));
        const int col = (wv*NTW + nt)*16 + lane15;
        atomicMax(&res[p][col], fenc(m));
      }
    } else {
      #pragma unroll
      for (int nt=0; nt<NTW; ++nt){
        const int col = (wv*NTW + nt)*16 + lane15;
        f32x4 acc = {0.f,0.f,0.f,0.f};
        #pragma unroll
        for (int s=0; s<KS; ++s){
          bfrag Bd = *(const bfrag*)&wd_bf[(size_t)col*C + s*32 + quad*8];
          acc = __builtin_amdgcn_mfma_f32_16x16x32_bf16(Af[s], Bd, acc, 0, 0, 0);
        }
        if (quad == 0){
          #pragma unroll
          for (int r=0;r<4;++r) cst_s[r][col] = acc[r];
        }
      }
    }
  }
  __syncthreads();
  for (int i=t; i<4*O; i+=256){
    int p = i/O, o = i - p*O;
    float mx = fdec(res[p][o]);
    float vv = (mx + cst_s[p][o]) * bn_scale(g[o]) + bb[o];
    outT[((size_t)b*NPTS + n0 + p)*O + o] = fmaxf(vv, 0.f);
  }
}

// ---------------- conv5 v3: LDS-staged split-bf16 MFMA GEMM + max over n ----------------
__global__ __launch_bounds__(256) void conv5_v3(const unsigned short* __restrict__ xhi,
    const unsigned short* __restrict__ xlo, const unsigned short* __restrict__ whi,
    const unsigned short* __restrict__ wlo, const float* __restrict__ g,
    const float* __restrict__ bb, float* __restrict__ out5){
  __shared__ __align__(16) unsigned short Ah_s[128*32];
  __shared__ __align__(16) unsigned short Al_s[128*32];
  __shared__ __align__(16) unsigned short Bh_s[64*32];
  __shared__ __align__(16) unsigned short Bl_s[64*32];
  const int t = threadIdx.x;
  const int row0 = blockIdx.x*128, o0 = blockIdx.y*64;
  const int b = row0 / NPTS;   // 128 | NPTS, so a block never straddles batches
  const int wv = t >> 6, l = t & 63, lane15 = l & 15, quad = l >> 4;
  const int ar = t >> 2, ac = (t & 3)*8;
  const unsigned short* gAh0 = xhi + (size_t)(row0 + ar)*512 + ac;
  const unsigned short* gAh1 = xhi + (size_t)(row0 + 64 + ar)*512 + ac;
  const unsigned short* gAl0 = xlo + (size_t)(row0 + ar)*512 + ac;
  const unsigned short* gAl1 = xlo + (size_t)(row0 + 64 + ar)*512 + ac;
  const unsigned short* gBh  = whi + (size_t)(o0 + ar)*512 + ac;
  const unsigned short* gBl  = wlo + (size_t)(o0 + ar)*512 + ac;

  uint4 pf0 = *(const uint4*)gAh0;
  uint4 pf1 = *(const uint4*)gAh1;
  uint4 pf2 = *(const uint4*)gAl0;
  uint4 pf3 = *(const uint4*)gAl1;
  uint4 pf4 = *(const uint4*)gBh;
  uint4 pf5 = *(const uint4*)gBl;

  f32x4 acc[2][4];
  #pragma unroll
  for (int mt=0;mt<2;++mt)
    #pragma unroll
    for (int nt=0;nt<4;++nt) acc[mt][nt] = (f32x4){0.f,0.f,0.f,0.f};

  for (int ks=0; ks<16; ++ks){
    *(uint4*)&Ah_s[t*8]        = pf0;
    *(uint4*)&Ah_s[2048 + t*8] = pf1;
    *(uint4*)&Al_s[t*8]        = pf2;
    *(uint4*)&Al_s[2048 + t*8] = pf3;
    *(uint4*)&Bh_s[t*8]        = pf4;
    *(uint4*)&Bl_s[t*8]        = pf5;
    __syncthreads();
    if (ks < 15){
      const int koff = (ks+1)*32;
      pf0 = *(const uint4*)(gAh0 + koff);
      pf1 = *(const uint4*)(gAh1 + koff);
      pf2 = *(const uint4*)(gAl0 + koff);
      pf3 = *(const uint4*)(gAl1 + koff);
      pf4 = *(const uint4*)(gBh  + koff);
      pf5 = *(const uint4*)(gBl  + koff);
    }
    bfrag Afh[2], Afl[2], Bfh[4], Bfl[4];
    #pragma unroll
    for (int mt=0;mt<2;++mt){
      const int m = wv*32 + mt*16 + lane15;
      Afh[mt] = *(const bfrag*)&Ah_s[m*32 + quad*8];
      Afl[mt] = *(const bfrag*)&Al_s[m*32 + quad*8];
    }
    #pragma unroll
    for (int nt=0;nt<4;++nt){
      const int oc = nt*16 + lane15;
      Bfh[nt] = *(const bfrag*)&Bh_s[oc*32 + quad*8];
      Bfl[nt] = *(const bfrag*)&Bl_s[oc*32 + quad*8];
    }
    #pragma unroll
    for (int mt=0;mt<2;++mt)
      #pragma unroll
      for (int nt=0;nt<4;++nt){
        acc[mt][nt] = __builtin_amdgcn_mfma_f32_16x16x32_bf16(Afh[mt], Bfh[nt], acc[mt][nt], 0, 0, 0);
        acc[mt][nt] = __builtin_amdgcn_mfma_f32_16x16x32_bf16(Afl[mt], Bfh[nt], acc[mt][nt], 0, 0, 0);
        acc[mt][nt] = __builtin_amdgcn_mfma_f32_16x16x32_bf16(Afh[mt], Bfl[nt], acc[mt][nt], 0, 0, 0);
      }
    __syncthreads();
  }
  #pragma unroll
  for (int nt=0;nt<4;++nt){
    float m = NEG_INF;
    #pragma unroll
    for (int mt=0;mt<2;++mt)
      #pragma unroll
      for (int r=0;r<4;++r) m = fmaxf(m, acc[mt][nt][r]);
    m = fmaxf(m, __shfl_xor(m, 16, 64));
    m = fmaxf(m, __shfl_xor(m, 32, 64));
    if (quad == 0){
      const int o = o0 + nt*16 + lane15;
      float vv = fmaxf(m * bn_scale(g[o]) + bb[o], 0.f);
      atomicMax((int*)&out5[(size_t)b*1024 + o], __float_as_int(vv));
    }
  }
}

__global__ void zero_kernel(float* __restrict__ p, int nfloats){
  int i = blockIdx.x*blockDim.x + threadIdx.x;
  if (i < nfloats) p[i] = 0.f;
}

// ---------------- FC layers ----------------
__global__ void fc_kernel(const float* __restrict__ in, const float* __restrict__ w,
                          const float* __restrict__ g, const float* __restrict__ bb,
                          float* __restrict__ out, int IN, int O){
  int i = blockIdx.x*blockDim.x + threadIdx.x;
  if (i >= BATCH*O) return;
  int b = i / O, o = i - b*O;
  const float* inb = in + (size_t)b*IN;
  const float* wo  = w + (size_t)o*IN;
  float s = 0.f;
  for (int c=0;c<IN;++c) s += inb[c]*wo[c];
  if (g){ s = s*bn_scale(g[o]) + bb[o]; s = fmaxf(s, 0.f); }
  out[i] = s;
}

extern "C" void kernel_launch(void* const* d_in, const int* in_sizes, int n_in,
                              void* d_out, int out_size, void* d_ws, size_t ws_size,
                              hipStream_t stream){
  const float* x   = (const float*)d_in[0];
  const float* w1  = (const float*)d_in[1];
  const float* w2  = (const float*)d_in[2];
  const float* w3  = (const float*)d_in[3];
  const float* w4  = (const float*)d_in[4];
  const float* w5  = (const float*)d_in[5];
  const float* fw1 = (const float*)d_in[6];
  const float* fw2 = (const float*)d_in[7];
  const float* fw3 = (const float*)d_in[8];
  const float* g1 = (const float*)d_in[9];  const float* b1 = (const float*)d_in[10];
  const float* g2 = (const float*)d_in[11]; const float* b2 = (const float*)d_in[12];
  const float* g3 = (const float*)d_in[13]; const float* b3 = (const float*)d_in[14];
  const float* g4 = (const float*)d_in[15]; const float* b4 = (const float*)d_in[16];
  const float* g5 = (const float*)d_in[17]; const float* b5 = (const float*)d_in[18];
  const float* g6 = (const float*)d_in[19]; const float* b6 = (const float*)d_in[20];
  const float* g7 = (const float*)d_in[21]; const float* b7 = (const float*)d_in[22];

  float* ws = (float*)d_ws;
  size_t off = 0;
  // x1..x3 channel-major; this 4.19M-float region is later reused as xcat_lo
  float* x1  = ws + off; off += (size_t)BATCH*64*NPTS;
  float* x2  = ws + off; off += (size_t)BATCH*64*NPTS;
  float* x3  = ws + off; off += (size_t)BATCH*128*NPTS;
  unsigned short* xcat_lo = (unsigned short*)x1;           // alias: x1..x3 dead before xcat runs
  unsigned short* xcat_hi = (unsigned short*)(ws + off); off += (size_t)BATCH*256*NPTS; // = B*N*512 bf16
  float* x1T = ws + off; off += (size_t)BATCH*64*NPTS;
  float* x2T = ws + off; off += (size_t)BATCH*64*NPTS;
  float* x3T = ws + off; off += (size_t)BATCH*128*NPTS;
  float* x4T = ws + off; off += (size_t)BATCH*256*NPTS;
  float* xT0 = ws + off; off += (size_t)BATCH*3*NPTS;
  float* sq  = ws + off; off += (size_t)BATCH*NPTS;
  int*  idx  = (int*)(ws + off); off += (size_t)BATCH*NPTS*KNN;
  float* out5 = ws + off; off += BATCH*1024;
  float* h6 = ws + off;   off += BATCH*512;
  float* h7 = ws + off;   off += BATCH*256;
  float* wnT1 = ws + off; off += 3*64;
  float* wdT1 = ws + off; off += 3*64;
  unsigned short* wn2 = (unsigned short*)(ws + off); off += 64*64/2;
  unsigned short* wd2 = (unsigned short*)(ws + off); off += 64*64/2;
  unsigned short* wn3 = (unsigned short*)(ws + off); off += 128*64/2;
  unsigned short* wd3 = (unsigned short*)(ws + off); off += 128*64/2;
  unsigned short* wn4 = (unsigned short*)(ws + off); off += 256*128/2;
  unsigned short* wd4 = (unsigned short*)(ws + off); off += 256*128/2;
  unsigned short* w5hi = (unsigned short*)(ws + off); off += 1024*512/2;
  unsigned short* w5lo = (unsigned short*)(ws + off); off += 1024*512/2;

  dim3 gridKNN(NPTS/8, BATCH);
  dim3 gridEC(NPTS/4, BATCH);

  // layer 1 (C=3 -> 64, fp32)
  xt0_kernel<<<64, 256, 0, stream>>>(x, xT0);
  sqnorm_kernel<<<64, 256, 0, stream>>>(x, sq, 3);
  knn_kernel<3><<<gridKNN, 256, 0, stream>>>(x, sq, idx);
  wprep_kernel<<<1, 256, 0, stream>>>(w1, wnT1, wdT1, 64, 3);
  edgeconv1_kernel<<<gridEC, 256, 0, stream>>>(xT0, idx, wnT1, wdT1, g1, b1, x1T);
  transpose2d_kernel<<<dim3(2,64,BATCH), 256, 0, stream>>>(x1T, x1, NPTS, 64);
  // layer 2 (C=64 -> 64, bf16 MFMA)
  sqnorm_kernel<<<64, 256, 0, stream>>>(x1, sq, 64);
  knn_kernel<64><<<gridKNN, 256, 0, stream>>>(x1, sq, idx);
  wprep_bf_kernel<<<16, 256, 0, stream>>>(w2, wn2, wd2, 64, 64);
  edgeconv_mfma<64,64><<<gridEC, 256, 0, stream>>>(x1T, idx, wn2, wd2, g2, b2, x2T);
  transpose2d_kernel<<<dim3(2,64,BATCH), 256, 0, stream>>>(x2T, x2, NPTS, 64);
  // layer 3 (C=64 -> 128, bf16 MFMA)
  sqnorm_kernel<<<64, 256, 0, stream>>>(x2, sq, 64);
  knn_kernel<64><<<gridKNN, 256, 0, stream>>>(x2, sq, idx);
  wprep_bf_kernel<<<32, 256, 0, stream>>>(w3, wn3, wd3, 128, 64);
  edgeconv_mfma<64,128><<<gridEC, 256, 0, stream>>>(x2T, idx, wn3, wd3, g3, b3, x3T);
  transpose2d_kernel<<<dim3(4,64,BATCH), 256, 0, stream>>>(x3T, x3, NPTS, 128);
  // layer 4 (C=128 -> 256, bf16 MFMA)
  sqnorm_kernel<<<64, 256, 0, stream>>>(x3, sq, 128);
  knn_kernel<128><<<gridKNN, 256, 0, stream>>>(x3, sq, idx);
  wprep_bf_kernel<<<128, 256, 0, stream>>>(w4, wn4, wd4, 256, 128);
  edgeconv_mfma<128,256><<<gridEC, 256, 0, stream>>>(x3T, idx, wn4, wd4, g4, b4, x4T);
  // conv5 (split-bf16 MFMA, LDS-staged) + global max over n
  xcat_kernel<<<(BATCH*NPTS*128)/256, 256, 0, stream>>>(x1T, x2T, x3T, x4T, xcat_hi, xcat_lo);
  bfsplit_kernel<<<512, 256, 0, stream>>>(w5, w5hi, w5lo, 1024*512/4);
  zero_kernel<<<32, 256, 0, stream>>>(out5, BATCH*1024);
  conv5_v3<<<dim3(BATCH*NPTS/128, 16), 256, 0, stream>>>(xcat_hi, xcat_lo, w5hi, w5lo, g5, b5, out5);
  // FC head
  fc_kernel<<<16, 256, 0, stream>>>(out5, fw1, g6, b6, h6, 1024, 512);
  fc_kernel<<<8, 256, 0, stream>>>(h6, fw2, g7, b7, h7, 512, 256);
  fc_kernel<<<2, 256, 0, stream>>>(h7, fw3, nullptr, nullptr, (float*)d_out, 256, 40);
}

// Round 13
// 1128.224 us; speedup vs baseline: 1.2644x; 1.0869x over previous
//
#include <hip/hip_runtime.h>
#include <hip/hip_bf16.h>
#include <math.h>

#define BATCH 8
#define NPTS  2048
#define KNN   20
#define NEG_INF (-3.402823466e38f)

static __device__ __forceinline__ float bn_scale(float g){ return g * rsqrtf(1.0f + 1e-5f); }

// bf16 round-to-nearest-even
static __device__ __forceinline__ unsigned short bf16r(float f){
  unsigned int u = __float_as_uint(f);
  unsigned int r = (u + 0x7fffu + ((u >> 16) & 1u)) >> 16;
  return (unsigned short)r;
}
static __device__ __forceinline__ float bf2f(unsigned short h){
  return __uint_as_float((unsigned int)h << 16);
}
// ordered-int encode/decode for float max via atomicMax(uint)
static __device__ __forceinline__ unsigned int fenc(float f){
  unsigned int u = __float_as_uint(f);
  return (u & 0x80000000u) ? ~u : (u | 0x80000000u);
}
static __device__ __forceinline__ float fdec(unsigned int e){
  return __uint_as_float((e & 0x80000000u) ? (e & 0x7fffffffu) : ~e);
}

using bfrag = __attribute__((ext_vector_type(8))) short;  // 8 bf16 (4 VGPRs)
using f32x4 = __attribute__((ext_vector_type(4))) float;  // 4 fp32 acc

// ---------------- squared norms per point (reads channel-major [C][N]) ----------------
__global__ void sqnorm_kernel(const float* __restrict__ X, float* __restrict__ sq, int C){
  int i = blockIdx.x*blockDim.x + threadIdx.x;
  if (i >= BATCH*NPTS) return;
  int b = i / NPTS, n = i - b*NPTS;
  const float* xb = X + (size_t)b*C*NPTS + n;
  float s = 0.f;
  for (int c=0;c<C;++c){ float v = xb[(size_t)c*NPTS]; s += v*v; }
  sq[i] = s;
}

// ---------------- kNN v7: v3 distance phase + per-lane top-4 register queue -----------
// Selection: initial scan builds a sorted (value desc, idx asc) top-4 per lane via a
// branch-free insertion network (8 regs). Extraction rounds promote from registers
// (~15 ops) instead of a 32-deep LDS rescan (~250 cyc). A lane refills from LDS only
// after consuming all 4 (needs >=5 of the top-20 in one lane - rare), with an order
// filter vs the last consumed (value,idx) so results stay bit-exact vs lax.top_k.
template<int C>
__global__ __launch_bounds__(256, 2) void knn_kernel(const float* __restrict__ X,
                                                     const float* __restrict__ sq,
                                                     int* __restrict__ idxout){
  const int b = blockIdx.y;
  const int n0 = blockIdx.x * 8;
  const int t = threadIdx.x;
  __shared__ __align__(16) float dist[4][NPTS];
  __shared__ float ctrs[C][8];
  __shared__ float sqn[8];
  const float* xb = X + (size_t)b*C*NPTS;
  for (int i=t; i<C*8; i+=256){
    int c = i >> 3, p = i & 7;
    ctrs[c][p] = xb[(size_t)c*NPTS + n0 + p];
  }
  if (t < 8) sqn[t] = sq[b*NPTS + n0 + t];
  __syncthreads();

  const int m0 = t * 8;
  float acc[8][8];
  #pragma unroll
  for (int i=0;i<8;++i)
    #pragma unroll
    for (int j=0;j<8;++j) acc[i][j] = 0.f;
  for (int c=0;c<C;++c){
    const float4 xa = *(const float4*)&xb[(size_t)c*NPTS + m0];
    const float4 xc = *(const float4*)&xb[(size_t)c*NPTS + m0 + 4];
    const float xm[8] = {xa.x,xa.y,xa.z,xa.w,xc.x,xc.y,xc.z,xc.w};
    #pragma unroll
    for (int i=0;i<8;++i){
      const float cv = ctrs[c][i];
      #pragma unroll
      for (int j=0;j<8;++j) acc[i][j] += cv*xm[j];
    }
  }
  {
    const float4 sa = *(const float4*)&sq[b*NPTS + m0];
    const float4 sb = *(const float4*)&sq[b*NPTS + m0 + 4];
    const float sm[8] = {sa.x,sa.y,sa.z,sa.w,sb.x,sb.y,sb.z,sb.w};
    #pragma unroll
    for (int i=0;i<8;++i){
      const float si = sqn[i];
      #pragma unroll
      for (int j=0;j<8;++j) acc[i][j] = 2.f*acc[i][j] - si - sm[j];
    }
  }

  const int wv = t >> 6, lane = t & 63;
  #pragma unroll
  for (int rep=0; rep<2; ++rep){
    #pragma unroll
    for (int i=0;i<4;++i){
      *(float4*)&dist[i][m0]   = make_float4(acc[rep*4+i][0],acc[rep*4+i][1],acc[rep*4+i][2],acc[rep*4+i][3]);
      *(float4*)&dist[i][m0+4] = make_float4(acc[rep*4+i][4],acc[rep*4+i][5],acc[rep*4+i][6],acc[rep*4+i][7]);
    }
    __syncthreads();
    // initial scan: build per-lane sorted top-4 (value desc, idx asc) in registers
    float s0=NEG_INF,s1=NEG_INF,s2=NEG_INF,s3=NEG_INF;
    int   i0=0x7fffffff,i1=0x7fffffff,i2=0x7fffffff,i3=0x7fffffff;
    #pragma unroll
    for (int j=0;j<32;++j){
      const float v = dist[wv][lane + 64*j];
      const int   m = lane + 64*j;
      const bool b0 = v > s0, b1 = v > s1, b2 = v > s2, b3 = v > s3;  // strict: stable ties
      const float n0 = b0 ? v : s0;            const int q0 = b0 ? m : i0;
      const float n1 = b0 ? s0 : (b1 ? v : s1); const int q1 = b0 ? i0 : (b1 ? m : i1);
      const float n2 = b1 ? s1 : (b2 ? v : s2); const int q2 = b1 ? i1 : (b2 ? m : i2);
      const float n3 = b2 ? s2 : (b3 ? v : s3); const int q3 = b2 ? i2 : (b3 ? m : i3);
      s0=n0;s1=n1;s2=n2;s3=n3; i0=q0;i1=q1;i2=q2;i3=q3;
    }
    int rem = 4;
    int* row = idxout + ((size_t)b*NPTS + n0 + rep*4 + wv)*KNN;
    for (int sel=0; sel<KNN; ++sel){
      float bv = s0; int bi = i0;   // head of this lane's queue (rem >= 1 invariant)
      #pragma unroll
      for (int off=32; off>0; off>>=1){
        float ov = __shfl_down(bv, off, 64);
        int   oi = __shfl_down(bi, off, 64);
        if (ov > bv || (ov == bv && oi < bi)){ bv = ov; bi = oi; }
      }
      const int widx = __shfl(bi, 0, 64);
      if (lane == 0) row[sel] = widx;
      if ((widx & 63) == lane){
        const float lastv = s0; const int lasti = i0;
        s0=s1;i0=i1; s1=s2;i1=i2; s2=s3;i2=i3;
        rem--;
        if (rem == 0){
          // refill: next candidate in (value desc, idx asc) order after (lastv,lasti)
          float nv = NEG_INF; int ni = 0x7fffffff;
          #pragma unroll
          for (int j=0;j<32;++j){
            const float vv = dist[wv][lane + 64*j];
            const int   mi = lane + 64*j;
            const bool ok = (vv < lastv) || (vv == lastv && mi > lasti);
            if (ok && vv > nv){ nv = vv; ni = mi; }
          }
          s0 = nv; i0 = ni; rem = 1;
        }
      }
    }
    __syncthreads();   // all waves done reading the slab before rep 1 overwrites it
  }
}

// ---------------- fp32 weight prep (layer 1 only): wnT[c][o], wdT[c][o] ----------------
__global__ void wprep_kernel(const float* __restrict__ w, float* __restrict__ wnT,
                             float* __restrict__ wdT, int O, int C){
  int i = blockIdx.x*blockDim.x + threadIdx.x;
  if (i >= O*C) return;
  int c = i / O, o = i - c*O;
  float a = w[(size_t)o*2*C + c];
  wnT[(size_t)c*O + o] = a;
  wdT[(size_t)c*O + o] = w[(size_t)o*2*C + C + c] - a;
}

// ---------------- bf16 weight prep (layers 2-4): wn[o][c], wd[o][c] (k contiguous) -----
__global__ void wprep_bf_kernel(const float* __restrict__ w, unsigned short* __restrict__ wn,
                                unsigned short* __restrict__ wd, int O, int C){
  int i = blockIdx.x*blockDim.x + threadIdx.x;
  if (i >= O*C) return;
  int o = i / C, c = i - o*C;
  float a = w[(size_t)o*2*C + c];
  float d = w[(size_t)o*2*C + C + c] - a;
  wn[(size_t)o*C + c] = bf16r(a);
  wd[(size_t)o*C + c] = bf16r(d);
}

// ---------------- split-bf16 weight convert (conv5): hi = bf16(w), lo = bf16(w-hi) ------
__global__ void bfsplit_kernel(const float* __restrict__ in, unsigned short* __restrict__ hi,
                               unsigned short* __restrict__ lo, int nq){
  int i = blockIdx.x*blockDim.x + threadIdx.x;
  if (i >= nq) return;
  float4 v = *(const float4*)&in[(size_t)i*4];
  unsigned short h0=bf16r(v.x), h1=bf16r(v.y), h2=bf16r(v.z), h3=bf16r(v.w);
  unsigned short l0=bf16r(v.x-bf2f(h0)), l1=bf16r(v.y-bf2f(h1)),
                 l2=bf16r(v.z-bf2f(h2)), l3=bf16r(v.w-bf2f(h3));
  *(uint2*)&hi[(size_t)i*4] = make_uint2((unsigned)h0|((unsigned)h1<<16), (unsigned)h2|((unsigned)h3<<16));
  *(uint2*)&lo[(size_t)i*4] = make_uint2((unsigned)l0|((unsigned)l1<<16), (unsigned)l2|((unsigned)l3<<16));
}

// ---------------- xcat: concat x1T..x4T -> split-bf16 [b][n][512] ----------------
__global__ __launch_bounds__(256) void xcat_kernel(const float* __restrict__ x1T,
    const float* __restrict__ x2T, const float* __restrict__ x3T, const float* __restrict__ x4T,
    unsigned short* __restrict__ xhi, unsigned short* __restrict__ xlo){
  int i = blockIdx.x*blockDim.x + threadIdx.x;   // quad index over B*N*128
  if (i >= BATCH*NPTS*128) return;
  int q = i & 127, bn_ = i >> 7;
  int k = q*4;
  const float* src; int kk;
  if (k < 64)      { src = x1T + (size_t)bn_*64;  kk = k; }
  else if (k <128) { src = x2T + (size_t)bn_*64;  kk = k-64; }
  else if (k <256) { src = x3T + (size_t)bn_*128; kk = k-128; }
  else             { src = x4T + (size_t)bn_*256; kk = k-256; }
  float4 v = *(const float4*)&src[kk];
  unsigned short h0=bf16r(v.x), h1=bf16r(v.y), h2=bf16r(v.z), h3=bf16r(v.w);
  unsigned short l0=bf16r(v.x-bf2f(h0)), l1=bf16r(v.y-bf2f(h1)),
                 l2=bf16r(v.z-bf2f(h2)), l3=bf16r(v.w-bf2f(h3));
  *(uint2*)&xhi[(size_t)i*4] = make_uint2((unsigned)h0|((unsigned)h1<<16), (unsigned)h2|((unsigned)h3<<16));
  *(uint2*)&xlo[(size_t)i*4] = make_uint2((unsigned)l0|((unsigned)l1<<16), (unsigned)l2|((unsigned)l3<<16));
}

// ---------------- generic tiled transpose: in[R][Cc] -> out[Cc][R], per z-slice ----------------
__global__ __launch_bounds__(256) void transpose2d_kernel(const float* __restrict__ in,
    float* __restrict__ out, int R, int Cc){
  __shared__ float tile[32][33];
  const size_t boff = (size_t)blockIdx.z * (size_t)R * Cc;
  const int c0 = blockIdx.x*32, r0 = blockIdx.y*32;
  const int tx = threadIdx.x & 31, ty = threadIdx.x >> 5;
  #pragma unroll
  for (int j=0;j<4;++j){
    int r = ty*4 + j;
    tile[r][tx] = in[boff + (size_t)(r0+r)*Cc + c0 + tx];
  }
  __syncthreads();
  #pragma unroll
  for (int j=0;j<4;++j){
    int r = ty*4 + j;
    out[boff + (size_t)(c0+r)*R + r0 + tx] = tile[tx][r];
  }
}

// ---------------- x -> xT0 [N][3] ----------------
__global__ void xt0_kernel(const float* __restrict__ x, float* __restrict__ xT0){
  int i = blockIdx.x*blockDim.x + threadIdx.x;
  if (i >= BATCH*NPTS) return;
  int b = i / NPTS, n = i - b*NPTS;
  const float* xb = x + (size_t)b*3*NPTS;
  float v0 = xb[n], v1 = xb[NPTS + n], v2 = xb[2*NPTS + n];
  float* o = xT0 + ((size_t)b*NPTS + n)*3;
  o[0]=v0; o[1]=v1; o[2]=v2;
}

// ---------------- edge conv layer 1 (C=3, fp32): 4 points per block ----------------
__global__ __launch_bounds__(256) void edgeconv1_kernel(const float* __restrict__ xT0,
    const int* __restrict__ idx, const float* __restrict__ wnT, const float* __restrict__ wdT,
    const float* __restrict__ g, const float* __restrict__ bb, float* __restrict__ outT){
  const int b = blockIdx.y, n0 = blockIdx.x*4, t = threadIdx.x;
  __shared__ float nbr[4][KNN][3];
  __shared__ float ctr[4][3];
  __shared__ int   idxs[4][KNN];
  const float* xb = xT0 + (size_t)b*NPTS*3;
  if (t < 4*KNN) idxs[t/KNN][t%KNN] = idx[((size_t)b*NPTS + n0 + t/KNN)*KNN + (t%KNN)];
  if (t >= 128 && t < 140){ int i = t-128; ctr[i/3][i%3] = xb[(size_t)(n0 + i/3)*3 + i%3]; }
  __syncthreads();
  for (int i=t; i<4*KNN*3; i+=256){
    int p = i/(KNN*3), r = i - p*(KNN*3), k = r/3, c = r - k*3;
    nbr[p][k][c] = xb[(size_t)idxs[p][k]*3 + c];
  }
  __syncthreads();
  const int p = t >> 6, o = t & 63;
  const float wn0 = wnT[o], wn1 = wnT[64+o], wn2 = wnT[128+o];
  const float cst = ctr[p][0]*wdT[o] + ctr[p][1]*wdT[64+o] + ctr[p][2]*wdT[128+o];
  float best = NEG_INF;
  #pragma unroll
  for (int k=0;k<KNN;++k){
    float a = nbr[p][k][0]*wn0 + nbr[p][k][1]*wn1 + nbr[p][k][2]*wn2;
    best = fmaxf(best, a);
  }
  float vv = (best + cst) * bn_scale(g[o]) + bb[o];
  outT[((size_t)b*NPTS + n0 + p)*64 + o] = fmaxf(vv, 0.f);
}

// ---------------- edge conv MFMA (bf16): block = 4 points ----------------
template<int C, int O>
__global__ __launch_bounds__(256) void edgeconv_mfma(const float* __restrict__ xT,
    const int* __restrict__ idx,
    const unsigned short* __restrict__ wn_bf, const unsigned short* __restrict__ wd_bf,
    const float* __restrict__ g, const float* __restrict__ bb, float* __restrict__ outT){
  constexpr int ROWS = 112;        // 7 m-tiles of 16
  constexpr int CP   = C + 8;      // padded row (bf16): 16B-aligned stride, conflict-free b128
  constexpr int KS   = C / 32;     // k-steps per tile
  constexpr int NTW  = O / 64;     // n-tiles per wave (O/16 tiles over 4 waves)
  __shared__ __align__(16) unsigned short A[ROWS][CP];
  __shared__ unsigned int res[4][O];
  __shared__ float cst_s[4][O];
  __shared__ int idxs[4][KNN];
  const int b = blockIdx.y, n0 = blockIdx.x*4, t = threadIdx.x;
  const float* xTb = xT + (size_t)b*NPTS*C;
  if (t < 4*KNN) idxs[t/KNN][t%KNN] = idx[((size_t)b*NPTS + n0 + t/KNN)*KNN + (t%KNN)];
  for (int i=t; i<4*O; i+=256) res[i/O][i & (O-1)] = 0u;   // 0 < fenc(any finite)
  __syncthreads();
  for (int i=t; i<ROWS*(C/4); i+=256){
    int r = i/(C/4), c4 = i - r*(C/4);
    float4 v = make_float4(0.f,0.f,0.f,0.f);
    if (r < 96){
      int p = r/24, kk = r - p*24;
      int src = idxs[p][kk < KNN ? kk : 0];        // pad rows duplicate nbr 0 (max-neutral)
      v = *(const float4*)&xTb[(size_t)src*C + c4*4];
    } else if (r < 100){
      v = *(const float4*)&xTb[(size_t)(n0 + (r-96))*C + c4*4];
    }
    unsigned int lo = (unsigned int)bf16r(v.x) | ((unsigned int)bf16r(v.y) << 16);
    unsigned int hi = (unsigned int)bf16r(v.z) | ((unsigned int)bf16r(v.w) << 16);
    *(uint2*)&A[r][c4*4] = make_uint2(lo, hi);
  }
  __syncthreads();

  const int wv = t >> 6, l = t & 63;
  const int lane15 = l & 15, quad = l >> 4;
  bfrag Bn[NTW][KS];
  #pragma unroll
  for (int nt=0; nt<NTW; ++nt){
    const int col = (wv*NTW + nt)*16 + lane15;
    #pragma unroll
    for (int s=0; s<KS; ++s)
      Bn[nt][s] = *(const bfrag*)&wn_bf[(size_t)col*C + s*32 + quad*8];
  }
  #pragma unroll
  for (int mt=0; mt<7; ++mt){
    bfrag Af[KS];
    #pragma unroll
    for (int s=0; s<KS; ++s)
      Af[s] = *(const bfrag*)&A[mt*16 + lane15][s*32 + quad*8];
    if (mt < 6){
      const int rbase = mt*16 + quad*4;
      const int p = rbase / 24;
      #pragma unroll
      for (int nt=0; nt<NTW; ++nt){
        f32x4 acc = {0.f,0.f,0.f,0.f};
        #pragma unroll
        for (int s=0; s<KS; ++s)
          acc = __builtin_amdgcn_mfma_f32_16x16x32_bf16(Af[s], Bn[nt][s], acc, 0, 0, 0);
        float m = fmaxf(fmaxf(acc[0], acc[1]), fmaxf(acc[2], acc[3]));
        const int col = (wv*NTW + nt)*16 + lane15;
        atomicMax(&res[p][col], fenc(m));
      }
    } else {
      #pragma unroll
      for (int nt=0; nt<NTW; ++nt){
        const int col = (wv*NTW + nt)*16 + lane15;
        f32x4 acc = {0.f,0.f,0.f,0.f};
        #pragma unroll
        for (int s=0; s<KS; ++s){
          bfrag Bd = *(const bfrag*)&wd_bf[(size_t)col*C + s*32 + quad*8];
          acc = __builtin_amdgcn_mfma_f32_16x16x32_bf16(Af[s], Bd, acc, 0, 0, 0);
        }
        if (quad == 0){
          #pragma unroll
          for (int r=0;r<4;++r) cst_s[r][col] = acc[r];
        }
      }
    }
  }
  __syncthreads();
  for (int i=t; i<4*O; i+=256){
    int p = i/O, o = i - p*O;
    float mx = fdec(res[p][o]);
    float vv = (mx + cst_s[p][o]) * bn_scale(g[o]) + bb[o];
    outT[((size_t)b*NPTS + n0 + p)*O + o] = fmaxf(vv, 0.f);
  }
}

// ---------------- conv5 v3: LDS-staged split-bf16 MFMA GEMM + max over n ----------------
__global__ __launch_bounds__(256) void conv5_v3(const unsigned short* __restrict__ xhi,
    const unsigned short* __restrict__ xlo, const unsigned short* __restrict__ whi,
    const unsigned short* __restrict__ wlo, const float* __restrict__ g,
    const float* __restrict__ bb, float* __restrict__ out5){
  __shared__ __align__(16) unsigned short Ah_s[128*32];
  __shared__ __align__(16) unsigned short Al_s[128*32];
  __shared__ __align__(16) unsigned short Bh_s[64*32];
  __shared__ __align__(16) unsigned short Bl_s[64*32];
  const int t = threadIdx.x;
  const int row0 = blockIdx.x*128, o0 = blockIdx.y*64;
  const int b = row0 / NPTS;   // 128 | NPTS, so a block never straddles batches
  const int wv = t >> 6, l = t & 63, lane15 = l & 15, quad = l >> 4;
  const int ar = t >> 2, ac = (t & 3)*8;
  const unsigned short* gAh0 = xhi + (size_t)(row0 + ar)*512 + ac;
  const unsigned short* gAh1 = xhi + (size_t)(row0 + 64 + ar)*512 + ac;
  const unsigned short* gAl0 = xlo + (size_t)(row0 + ar)*512 + ac;
  const unsigned short* gAl1 = xlo + (size_t)(row0 + 64 + ar)*512 + ac;
  const unsigned short* gBh  = whi + (size_t)(o0 + ar)*512 + ac;
  const unsigned short* gBl  = wlo + (size_t)(o0 + ar)*512 + ac;

  uint4 pf0 = *(const uint4*)gAh0;
  uint4 pf1 = *(const uint4*)gAh1;
  uint4 pf2 = *(const uint4*)gAl0;
  uint4 pf3 = *(const uint4*)gAl1;
  uint4 pf4 = *(const uint4*)gBh;
  uint4 pf5 = *(const uint4*)gBl;

  f32x4 acc[2][4];
  #pragma unroll
  for (int mt=0;mt<2;++mt)
    #pragma unroll
    for (int nt=0;nt<4;++nt) acc[mt][nt] = (f32x4){0.f,0.f,0.f,0.f};

  for (int ks=0; ks<16; ++ks){
    *(uint4*)&Ah_s[t*8]        = pf0;
    *(uint4*)&Ah_s[2048 + t*8] = pf1;
    *(uint4*)&Al_s[t*8]        = pf2;
    *(uint4*)&Al_s[2048 + t*8] = pf3;
    *(uint4*)&Bh_s[t*8]        = pf4;
    *(uint4*)&Bl_s[t*8]        = pf5;
    __syncthreads();
    if (ks < 15){
      const int koff = (ks+1)*32;
      pf0 = *(const uint4*)(gAh0 + koff);
      pf1 = *(const uint4*)(gAh1 + koff);
      pf2 = *(const uint4*)(gAl0 + koff);
      pf3 = *(const uint4*)(gAl1 + koff);
      pf4 = *(const uint4*)(gBh  + koff);
      pf5 = *(const uint4*)(gBl  + koff);
    }
    bfrag Afh[2], Afl[2], Bfh[4], Bfl[4];
    #pragma unroll
    for (int mt=0;mt<2;++mt){
      const int m = wv*32 + mt*16 + lane15;
      Afh[mt] = *(const bfrag*)&Ah_s[m*32 + quad*8];
      Afl[mt] = *(const bfrag*)&Al_s[m*32 + quad*8];
    }
    #pragma unroll
    for (int nt=0;nt<4;++nt){
      const int oc = nt*16 + lane15;
      Bfh[nt] = *(const bfrag*)&Bh_s[oc*32 + quad*8];
      Bfl[nt] = *(const bfrag*)&Bl_s[oc*32 + quad*8];
    }
    #pragma unroll
    for (int mt=0;mt<2;++mt)
      #pragma unroll
      for (int nt=0;nt<4;++nt){
        acc[mt][nt] = __builtin_amdgcn_mfma_f32_16x16x32_bf16(Afh[mt], Bfh[nt], acc[mt][nt], 0, 0, 0);
        acc[mt][nt] = __builtin_amdgcn_mfma_f32_16x16x32_bf16(Afl[mt], Bfh[nt], acc[mt][nt], 0, 0, 0);
        acc[mt][nt] = __builtin_amdgcn_mfma_f32_16x16x32_bf16(Afh[mt], Bfl[nt], acc[mt][nt], 0, 0, 0);
      }
    __syncthreads();
  }
  #pragma unroll
  for (int nt=0;nt<4;++nt){
    float m = NEG_INF;
    #pragma unroll
    for (int mt=0;mt<2;++mt)
      #pragma unroll
      for (int r=0;r<4;++r) m = fmaxf(m, acc[mt][nt][r]);
    m = fmaxf(m, __shfl_xor(m, 16, 64));
    m = fmaxf(m, __shfl_xor(m, 32, 64));
    if (quad == 0){
      const int o = o0 + nt*16 + lane15;
      float vv = fmaxf(m * bn_scale(g[o]) + bb[o], 0.f);
      atomicMax((int*)&out5[(size_t)b*1024 + o], __float_as_int(vv));
    }
  }
}

__global__ void zero_kernel(float* __restrict__ p, int nfloats){
  int i = blockIdx.x*blockDim.x + threadIdx.x;
  if (i < nfloats) p[i] = 0.f;
}

// ---------------- FC layers ----------------
__global__ void fc_kernel(const float* __restrict__ in, const float* __restrict__ w,
                          const float* __restrict__ g, const float* __restrict__ bb,
                          float* __restrict__ out, int IN, int O){
  int i = blockIdx.x*blockDim.x + threadIdx.x;
  if (i >= BATCH*O) return;
  int b = i / O, o = i - b*O;
  const float* inb = in + (size_t)b*IN;
  const float* wo  = w + (size_t)o*IN;
  float s = 0.f;
  for (int c=0;c<IN;++c) s += inb[c]*wo[c];
  if (g){ s = s*bn_scale(g[o]) + bb[o]; s = fmaxf(s, 0.f); }
  out[i] = s;
}

extern "C" void kernel_launch(void* const* d_in, const int* in_sizes, int n_in,
                              void* d_out, int out_size, void* d_ws, size_t ws_size,
                              hipStream_t stream){
  const float* x   = (const float*)d_in[0];
  const float* w1  = (const float*)d_in[1];
  const float* w2  = (const float*)d_in[2];
  const float* w3  = (const float*)d_in[3];
  const float* w4  = (const float*)d_in[4];
  const float* w5  = (const float*)d_in[5];
  const float* fw1 = (const float*)d_in[6];
  const float* fw2 = (const float*)d_in[7];
  const float* fw3 = (const float*)d_in[8];
  const float* g1 = (const float*)d_in[9];  const float* b1 = (const float*)d_in[10];
  const float* g2 = (const float*)d_in[11]; const float* b2 = (const float*)d_in[12];
  const float* g3 = (const float*)d_in[13]; const float* b3 = (const float*)d_in[14];
  const float* g4 = (const float*)d_in[15]; const float* b4 = (const float*)d_in[16];
  const float* g5 = (const float*)d_in[17]; const float* b5 = (const float*)d_in[18];
  const float* g6 = (const float*)d_in[19]; const float* b6 = (const float*)d_in[20];
  const float* g7 = (const float*)d_in[21]; const float* b7 = (const float*)d_in[22];

  float* ws = (float*)d_ws;
  size_t off = 0;
  // x1..x3 channel-major; this 4.19M-float region is later reused as xcat_lo
  float* x1  = ws + off; off += (size_t)BATCH*64*NPTS;
  float* x2  = ws + off; off += (size_t)BATCH*64*NPTS;
  float* x3  = ws + off; off += (size_t)BATCH*128*NPTS;
  unsigned short* xcat_lo = (unsigned short*)x1;           // alias: x1..x3 dead before xcat runs
  unsigned short* xcat_hi = (unsigned short*)(ws + off); off += (size_t)BATCH*256*NPTS; // = B*N*512 bf16
  float* x1T = ws + off; off += (size_t)BATCH*64*NPTS;
  float* x2T = ws + off; off += (size_t)BATCH*64*NPTS;
  float* x3T = ws + off; off += (size_t)BATCH*128*NPTS;
  float* x4T = ws + off; off += (size_t)BATCH*256*NPTS;
  float* xT0 = ws + off; off += (size_t)BATCH*3*NPTS;
  float* sq  = ws + off; off += (size_t)BATCH*NPTS;
  int*  idx  = (int*)(ws + off); off += (size_t)BATCH*NPTS*KNN;
  float* out5 = ws + off; off += BATCH*1024;
  float* h6 = ws + off;   off += BATCH*512;
  float* h7 = ws + off;   off += BATCH*256;
  float* wnT1 = ws + off; off += 3*64;
  float* wdT1 = ws + off; off += 3*64;
  unsigned short* wn2 = (unsigned short*)(ws + off); off += 64*64/2;
  unsigned short* wd2 = (unsigned short*)(ws + off); off += 64*64/2;
  unsigned short* wn3 = (unsigned short*)(ws + off); off += 128*64/2;
  unsigned short* wd3 = (unsigned short*)(ws + off); off += 128*64/2;
  unsigned short* wn4 = (unsigned short*)(ws + off); off += 256*128/2;
  unsigned short* wd4 = (unsigned short*)(ws + off); off += 256*128/2;
  unsigned short* w5hi = (unsigned short*)(ws + off); off += 1024*512/2;
  unsigned short* w5lo = (unsigned short*)(ws + off); off += 1024*512/2;

  dim3 gridKNN(NPTS/8, BATCH);
  dim3 gridEC(NPTS/4, BATCH);

  // layer 1 (C=3 -> 64, fp32)
  xt0_kernel<<<64, 256, 0, stream>>>(x, xT0);
  sqnorm_kernel<<<64, 256, 0, stream>>>(x, sq, 3);
  knn_kernel<3><<<gridKNN, 256, 0, stream>>>(x, sq, idx);
  wprep_kernel<<<1, 256, 0, stream>>>(w1, wnT1, wdT1, 64, 3);
  edgeconv1_kernel<<<gridEC, 256, 0, stream>>>(xT0, idx, wnT1, wdT1, g1, b1, x1T);
  transpose2d_kernel<<<dim3(2,64,BATCH), 256, 0, stream>>>(x1T, x1, NPTS, 64);
  // layer 2 (C=64 -> 64, bf16 MFMA)
  sqnorm_kernel<<<64, 256, 0, stream>>>(x1, sq, 64);
  knn_kernel<64><<<gridKNN, 256, 0, stream>>>(x1, sq, idx);
  wprep_bf_kernel<<<16, 256, 0, stream>>>(w2, wn2, wd2, 64, 64);
  edgeconv_mfma<64,64><<<gridEC, 256, 0, stream>>>(x1T, idx, wn2, wd2, g2, b2, x2T);
  transpose2d_kernel<<<dim3(2,64,BATCH), 256, 0, stream>>>(x2T, x2, NPTS, 64);
  // layer 3 (C=64 -> 128, bf16 MFMA)
  sqnorm_kernel<<<64, 256, 0, stream>>>(x2, sq, 64);
  knn_kernel<64><<<gridKNN, 256, 0, stream>>>(x2, sq, idx);
  wprep_bf_kernel<<<32, 256, 0, stream>>>(w3, wn3, wd3, 128, 64);
  edgeconv_mfma<64,128><<<gridEC, 256, 0, stream>>>(x2T, idx, wn3, wd3, g3, b3, x3T);
  transpose2d_kernel<<<dim3(4,64,BATCH), 256, 0, stream>>>(x3T, x3, NPTS, 128);
  // layer 4 (C=128 -> 256, bf16 MFMA)
  sqnorm_kernel<<<64, 256, 0, stream>>>(x3, sq, 128);
  knn_kernel<128><<<gridKNN, 256, 0, stream>>>(x3, sq, idx);
  wprep_bf_kernel<<<128, 256, 0, stream>>>(w4, wn4, wd4, 256, 128);
  edgeconv_mfma<128,256><<<gridEC, 256, 0, stream>>>(x3T, idx, wn4, wd4, g4, b4, x4T);
  // conv5 (split-bf16 MFMA, LDS-staged) + global max over n
  xcat_kernel<<<(BATCH*NPTS*128)/256, 256, 0, stream>>>(x1T, x2T, x3T, x4T, xcat_hi, xcat_lo);
  bfsplit_kernel<<<512, 256, 0, stream>>>(w5, w5hi, w5lo, 1024*512/4);
  zero_kernel<<<32, 256, 0, stream>>>(out5, BATCH*1024);
  conv5_v3<<<dim3(BATCH*NPTS/128, 16), 256, 0, stream>>>(xcat_hi, xcat_lo, w5hi, w5lo, g5, b5, out5);
  // FC head
  fc_kernel<<<16, 256, 0, stream>>>(out5, fw1, g6, b6, h6, 1024, 512);
  fc_kernel<<<8, 256, 0, stream>>>(h6, fw2, g7, b7, h7, 512, 256);
  fc_kernel<<<2, 256, 0, stream>>>(h7, fw3, nullptr, nullptr, (float*)d_out, 256, 40);
}

// Round 14
// 1061.909 us; speedup vs baseline: 1.3434x; 1.0624x over previous
//
#include <hip/hip_runtime.h>
#include <hip/hip_bf16.h>
#include <math.h>

#define BATCH 8
#define NPTS  2048
#define KNN   20
#define NEG_INF (-3.402823466e38f)

static __device__ __forceinline__ float bn_scale(float g){ return g * rsqrtf(1.0f + 1e-5f); }

// bf16 round-to-nearest-even
static __device__ __forceinline__ unsigned short bf16r(float f){
  unsigned int u = __float_as_uint(f);
  unsigned int r = (u + 0x7fffu + ((u >> 16) & 1u)) >> 16;
  return (unsigned short)r;
}
static __device__ __forceinline__ float bf2f(unsigned short h){
  return __uint_as_float((unsigned int)h << 16);
}
// ordered-int encode/decode for float max via atomicMax(uint)
static __device__ __forceinline__ unsigned int fenc(float f){
  unsigned int u = __float_as_uint(f);
  return (u & 0x80000000u) ? ~u : (u | 0x80000000u);
}
static __device__ __forceinline__ float fdec(unsigned int e){
  return __uint_as_float((e & 0x80000000u) ? (e & 0x7fffffffu) : ~e);
}

using bfrag = __attribute__((ext_vector_type(8))) short;  // 8 bf16 (4 VGPRs)
using f32x4 = __attribute__((ext_vector_type(4))) float;  // 4 fp32 acc

// ---- DPP-based wave argmax step: merge (bv,bi) with lane (i - shift) per CTRL ----
// update_dpp injects the identity (NEG_INF, INT_MAX) into invalid lanes, so the
// lexicographic (value desc, idx asc) max is preserved. VALU-pipe (~2cyc) vs
// ds_bpermute (~30-60cyc) that __shfl_down compiles to on CDNA.
template<int CTRL>
static __device__ __forceinline__ void dpp_amax(float &bv, int &bi){
  int ov_i = __builtin_amdgcn_update_dpp(__float_as_int(NEG_INF), __float_as_int(bv),
                                         CTRL, 0xf, 0xf, false);
  int oi   = __builtin_amdgcn_update_dpp(0x7fffffff, bi, CTRL, 0xf, 0xf, false);
  float ov = __int_as_float(ov_i);
  if (ov > bv || (ov == bv && oi < bi)){ bv = ov; bi = oi; }
}
// full 64-lane argmax: result in lane 63; returns winner idx broadcast to all lanes
static __device__ __forceinline__ int wave_argmax_idx(float bv, int bi){
  dpp_amax<0x111>(bv, bi);   // row_shr:1
  dpp_amax<0x112>(bv, bi);   // row_shr:2
  dpp_amax<0x114>(bv, bi);   // row_shr:4
  dpp_amax<0x118>(bv, bi);   // row_shr:8  -> lane 15 of each row holds row max
  dpp_amax<0x142>(bv, bi);   // row_bcast:15 -> lane 31 / 63 hold half maxes
  dpp_amax<0x143>(bv, bi);   // row_bcast:31 -> lane 63 holds global max
  return __builtin_amdgcn_readlane(bi, 63);
}

// ---------------- squared norms per point (reads channel-major [C][N]) ----------------
__global__ void sqnorm_kernel(const float* __restrict__ X, float* __restrict__ sq, int C){
  int i = blockIdx.x*blockDim.x + threadIdx.x;
  if (i >= BATCH*NPTS) return;
  int b = i / NPTS, n = i - b*NPTS;
  const float* xb = X + (size_t)b*C*NPTS + n;
  float s = 0.f;
  for (int c=0;c<C;++c){ float v = xb[(size_t)c*NPTS]; s += v*v; }
  sq[i] = s;
}

// ---------------- kNN v8: v7 (top-4 register queue) + DPP argmax reduction -----------
template<int C>
__global__ __launch_bounds__(256, 2) void knn_kernel(const float* __restrict__ X,
                                                     const float* __restrict__ sq,
                                                     int* __restrict__ idxout){
  const int b = blockIdx.y;
  const int n0 = blockIdx.x * 8;
  const int t = threadIdx.x;
  __shared__ __align__(16) float dist[4][NPTS];
  __shared__ float ctrs[C][8];
  __shared__ float sqn[8];
  const float* xb = X + (size_t)b*C*NPTS;
  for (int i=t; i<C*8; i+=256){
    int c = i >> 3, p = i & 7;
    ctrs[c][p] = xb[(size_t)c*NPTS + n0 + p];
  }
  if (t < 8) sqn[t] = sq[b*NPTS + n0 + t];
  __syncthreads();

  const int m0 = t * 8;
  float acc[8][8];
  #pragma unroll
  for (int i=0;i<8;++i)
    #pragma unroll
    for (int j=0;j<8;++j) acc[i][j] = 0.f;
  for (int c=0;c<C;++c){
    const float4 xa = *(const float4*)&xb[(size_t)c*NPTS + m0];
    const float4 xc = *(const float4*)&xb[(size_t)c*NPTS + m0 + 4];
    const float xm[8] = {xa.x,xa.y,xa.z,xa.w,xc.x,xc.y,xc.z,xc.w};
    #pragma unroll
    for (int i=0;i<8;++i){
      const float cv = ctrs[c][i];
      #pragma unroll
      for (int j=0;j<8;++j) acc[i][j] += cv*xm[j];
    }
  }
  {
    const float4 sa = *(const float4*)&sq[b*NPTS + m0];
    const float4 sb = *(const float4*)&sq[b*NPTS + m0 + 4];
    const float sm[8] = {sa.x,sa.y,sa.z,sa.w,sb.x,sb.y,sb.z,sb.w};
    #pragma unroll
    for (int i=0;i<8;++i){
      const float si = sqn[i];
      #pragma unroll
      for (int j=0;j<8;++j) acc[i][j] = 2.f*acc[i][j] - si - sm[j];
    }
  }

  const int wv = t >> 6, lane = t & 63;
  #pragma unroll
  for (int rep=0; rep<2; ++rep){
    #pragma unroll
    for (int i=0;i<4;++i){
      *(float4*)&dist[i][m0]   = make_float4(acc[rep*4+i][0],acc[rep*4+i][1],acc[rep*4+i][2],acc[rep*4+i][3]);
      *(float4*)&dist[i][m0+4] = make_float4(acc[rep*4+i][4],acc[rep*4+i][5],acc[rep*4+i][6],acc[rep*4+i][7]);
    }
    __syncthreads();
    // initial scan: build per-lane sorted top-4 (value desc, idx asc) in registers
    float s0=NEG_INF,s1=NEG_INF,s2=NEG_INF,s3=NEG_INF;
    int   i0=0x7fffffff,i1=0x7fffffff,i2=0x7fffffff,i3=0x7fffffff;
    #pragma unroll
    for (int j=0;j<32;++j){
      const float v = dist[wv][lane + 64*j];
      const int   m = lane + 64*j;
      const bool b0 = v > s0, b1 = v > s1, b2 = v > s2, b3 = v > s3;  // strict: stable ties
      const float n0 = b0 ? v : s0;            const int q0 = b0 ? m : i0;
      const float n1 = b0 ? s0 : (b1 ? v : s1); const int q1 = b0 ? i0 : (b1 ? m : i1);
      const float n2 = b1 ? s1 : (b2 ? v : s2); const int q2 = b1 ? i1 : (b2 ? m : i2);
      const float n3 = b2 ? s2 : (b3 ? v : s3); const int q3 = b2 ? i2 : (b3 ? m : i3);
      s0=n0;s1=n1;s2=n2;s3=n3; i0=q0;i1=q1;i2=q2;i3=q3;
    }
    int rem = 4;
    int* row = idxout + ((size_t)b*NPTS + n0 + rep*4 + wv)*KNN;
    for (int sel=0; sel<KNN; ++sel){
      const int widx = wave_argmax_idx(s0, i0);   // DPP reduction over queue heads
      if (lane == 0) row[sel] = widx;
      if ((widx & 63) == lane){
        const float lastv = s0; const int lasti = i0;
        s0=s1;i0=i1; s1=s2;i1=i2; s2=s3;i2=i3;
        rem--;
        if (rem == 0){
          // refill: next candidate in (value desc, idx asc) order after (lastv,lasti)
          float nv = NEG_INF; int ni = 0x7fffffff;
          #pragma unroll
          for (int j=0;j<32;++j){
            const float vv = dist[wv][lane + 64*j];
            const int   mi = lane + 64*j;
            const bool ok = (vv < lastv) || (vv == lastv && mi > lasti);
            if (ok && vv > nv){ nv = vv; ni = mi; }
          }
          s0 = nv; i0 = ni; rem = 1;
        }
      }
    }
    __syncthreads();   // all waves done reading the slab before rep 1 overwrites it
  }
}

// ---------------- fp32 weight prep (layer 1 only): wnT[c][o], wdT[c][o] ----------------
__global__ void wprep_kernel(const float* __restrict__ w, float* __restrict__ wnT,
                             float* __restrict__ wdT, int O, int C){
  int i = blockIdx.x*blockDim.x + threadIdx.x;
  if (i >= O*C) return;
  int c = i / O, o = i - c*O;
  float a = w[(size_t)o*2*C + c];
  wnT[(size_t)c*O + o] = a;
  wdT[(size_t)c*O + o] = w[(size_t)o*2*C + C + c] - a;
}

// ---------------- bf16 weight prep (layers 2-4): wn[o][c], wd[o][c] (k contiguous) -----
__global__ void wprep_bf_kernel(const float* __restrict__ w, unsigned short* __restrict__ wn,
                                unsigned short* __restrict__ wd, int O, int C){
  int i = blockIdx.x*blockDim.x + threadIdx.x;
  if (i >= O*C) return;
  int o = i / C, c = i - o*C;
  float a = w[(size_t)o*2*C + c];
  float d = w[(size_t)o*2*C + C + c] - a;
  wn[(size_t)o*C + c] = bf16r(a);
  wd[(size_t)o*C + c] = bf16r(d);
}

// ---------------- split-bf16 weight convert (conv5): hi = bf16(w), lo = bf16(w-hi) ------
__global__ void bfsplit_kernel(const float* __restrict__ in, unsigned short* __restrict__ hi,
                               unsigned short* __restrict__ lo, int nq){
  int i = blockIdx.x*blockDim.x + threadIdx.x;
  if (i >= nq) return;
  float4 v = *(const float4*)&in[(size_t)i*4];
  unsigned short h0=bf16r(v.x), h1=bf16r(v.y), h2=bf16r(v.z), h3=bf16r(v.w);
  unsigned short l0=bf16r(v.x-bf2f(h0)), l1=bf16r(v.y-bf2f(h1)),
                 l2=bf16r(v.z-bf2f(h2)), l3=bf16r(v.w-bf2f(h3));
  *(uint2*)&hi[(size_t)i*4] = make_uint2((unsigned)h0|((unsigned)h1<<16), (unsigned)h2|((unsigned)h3<<16));
  *(uint2*)&lo[(size_t)i*4] = make_uint2((unsigned)l0|((unsigned)l1<<16), (unsigned)l2|((unsigned)l3<<16));
}

// ---------------- xcat: concat x1T..x4T -> split-bf16 [b][n][512] ----------------
__global__ __launch_bounds__(256) void xcat_kernel(const float* __restrict__ x1T,
    const float* __restrict__ x2T, const float* __restrict__ x3T, const float* __restrict__ x4T,
    unsigned short* __restrict__ xhi, unsigned short* __restrict__ xlo){
  int i = blockIdx.x*blockDim.x + threadIdx.x;   // quad index over B*N*128
  if (i >= BATCH*NPTS*128) return;
  int q = i & 127, bn_ = i >> 7;
  int k = q*4;
  const float* src; int kk;
  if (k < 64)      { src = x1T + (size_t)bn_*64;  kk = k; }
  else if (k <128) { src = x2T + (size_t)bn_*64;  kk = k-64; }
  else if (k <256) { src = x3T + (size_t)bn_*128; kk = k-128; }
  else             { src = x4T + (size_t)bn_*256; kk = k-256; }
  float4 v = *(const float4*)&src[kk];
  unsigned short h0=bf16r(v.x), h1=bf16r(v.y), h2=bf16r(v.z), h3=bf16r(v.w);
  unsigned short l0=bf16r(v.x-bf2f(h0)), l1=bf16r(v.y-bf2f(h1)),
                 l2=bf16r(v.z-bf2f(h2)), l3=bf16r(v.w-bf2f(h3));
  *(uint2*)&xhi[(size_t)i*4] = make_uint2((unsigned)h0|((unsigned)h1<<16), (unsigned)h2|((unsigned)h3<<16));
  *(uint2*)&xlo[(size_t)i*4] = make_uint2((unsigned)l0|((unsigned)l1<<16), (unsigned)l2|((unsigned)l3<<16));
}

// ---------------- generic tiled transpose: in[R][Cc] -> out[Cc][R], per z-slice ----------------
__global__ __launch_bounds__(256) void transpose2d_kernel(const float* __restrict__ in,
    float* __restrict__ out, int R, int Cc){
  __shared__ float tile[32][33];
  const size_t boff = (size_t)blockIdx.z * (size_t)R * Cc;
  const int c0 = blockIdx.x*32, r0 = blockIdx.y*32;
  const int tx = threadIdx.x & 31, ty = threadIdx.x >> 5;
  #pragma unroll
  for (int j=0;j<4;++j){
    int r = ty*4 + j;
    tile[r][tx] = in[boff + (size_t)(r0+r)*Cc + c0 + tx];
  }
  __syncthreads();
  #pragma unroll
  for (int j=0;j<4;++j){
    int r = ty*4 + j;
    out[boff + (size_t)(c0+r)*R + r0 + tx] = tile[tx][r];
  }
}

// ---------------- x -> xT0 [N][3] ----------------
__global__ void xt0_kernel(const float* __restrict__ x, float* __restrict__ xT0){
  int i = blockIdx.x*blockDim.x + threadIdx.x;
  if (i >= BATCH*NPTS) return;
  int b = i / NPTS, n = i - b*NPTS;
  const float* xb = x + (size_t)b*3*NPTS;
  float v0 = xb[n], v1 = xb[NPTS + n], v2 = xb[2*NPTS + n];
  float* o = xT0 + ((size_t)b*NPTS + n)*3;
  o[0]=v0; o[1]=v1; o[2]=v2;
}

// ---------------- edge conv layer 1 (C=3, fp32): 4 points per block ----------------
__global__ __launch_bounds__(256) void edgeconv1_kernel(const float* __restrict__ xT0,
    const int* __restrict__ idx, const float* __restrict__ wnT, const float* __restrict__ wdT,
    const float* __restrict__ g, const float* __restrict__ bb, float* __restrict__ outT){
  const int b = blockIdx.y, n0 = blockIdx.x*4, t = threadIdx.x;
  __shared__ float nbr[4][KNN][3];
  __shared__ float ctr[4][3];
  __shared__ int   idxs[4][KNN];
  const float* xb = xT0 + (size_t)b*NPTS*3;
  if (t < 4*KNN) idxs[t/KNN][t%KNN] = idx[((size_t)b*NPTS + n0 + t/KNN)*KNN + (t%KNN)];
  if (t >= 128 && t < 140){ int i = t-128; ctr[i/3][i%3] = xb[(size_t)(n0 + i/3)*3 + i%3]; }
  __syncthreads();
  for (int i=t; i<4*KNN*3; i+=256){
    int p = i/(KNN*3), r = i - p*(KNN*3), k = r/3, c = r - k*3;
    nbr[p][k][c] = xb[(size_t)idxs[p][k]*3 + c];
  }
  __syncthreads();
  const int p = t >> 6, o = t & 63;
  const float wn0 = wnT[o], wn1 = wnT[64+o], wn2 = wnT[128+o];
  const float cst = ctr[p][0]*wdT[o] + ctr[p][1]*wdT[64+o] + ctr[p][2]*wdT[128+o];
  float best = NEG_INF;
  #pragma unroll
  for (int k=0;k<KNN;++k){
    float a = nbr[p][k][0]*wn0 + nbr[p][k][1]*wn1 + nbr[p][k][2]*wn2;
    best = fmaxf(best, a);
  }
  float vv = (best + cst) * bn_scale(g[o]) + bb[o];
  outT[((size_t)b*NPTS + n0 + p)*64 + o] = fmaxf(vv, 0.f);
}

// ---------------- edge conv MFMA (bf16): block = 4 points ----------------
template<int C, int O>
__global__ __launch_bounds__(256) void edgeconv_mfma(const float* __restrict__ xT,
    const int* __restrict__ idx,
    const unsigned short* __restrict__ wn_bf, const unsigned short* __restrict__ wd_bf,
    const float* __restrict__ g, const float* __restrict__ bb, float* __restrict__ outT){
  constexpr int ROWS = 112;        // 7 m-tiles of 16
  constexpr int CP   = C + 8;      // padded row (bf16): 16B-aligned stride, conflict-free b128
  constexpr int KS   = C / 32;     // k-steps per tile
  constexpr int NTW  = O / 64;     // n-tiles per wave (O/16 tiles over 4 waves)
  __shared__ __align__(16) unsigned short A[ROWS][CP];
  __shared__ unsigned int res[4][O];
  __shared__ float cst_s[4][O];
  __shared__ int idxs[4][KNN];
  const int b = blockIdx.y, n0 = blockIdx.x*4, t = threadIdx.x;
  const float* xTb = xT + (size_t)b*NPTS*C;
  if (t < 4*KNN) idxs[t/KNN][t%KNN] = idx[((size_t)b*NPTS + n0 + t/KNN)*KNN + (t%KNN)];
  for (int i=t; i<4*O; i+=256) res[i/O][i & (O-1)] = 0u;   // 0 < fenc(any finite)
  __syncthreads();
  for (int i=t; i<ROWS*(C/4); i+=256){
    int r = i/(C/4), c4 = i - r*(C/4);
    float4 v = make_float4(0.f,0.f,0.f,0.f);
    if (r < 96){
      int p = r/24, kk = r - p*24;
      int src = idxs[p][kk < KNN ? kk : 0];        // pad rows duplicate nbr 0 (max-neutral)
      v = *(const float4*)&xTb[(size_t)src*C + c4*4];
    } else if (r < 100){
      v = *(const float4*)&xTb[(size_t)(n0 + (r-96))*C + c4*4];
    }
    unsigned int lo = (unsigned int)bf16r(v.x) | ((unsigned int)bf16r(v.y) << 16);
    unsigned int hi = (unsigned int)bf16r(v.z) | ((unsigned int)bf16r(v.w) << 16);
    *(uint2*)&A[r][c4*4] = make_uint2(lo, hi);
  }
  __syncthreads();

  const int wv = t >> 6, l = t & 63;
  const int lane15 = l & 15, quad = l >> 4;
  bfrag Bn[NTW][KS];
  #pragma unroll
  for (int nt=0; nt<NTW; ++nt){
    const int col = (wv*NTW + nt)*16 + lane15;
    #pragma unroll
    for (int s=0; s<KS; ++s)
      Bn[nt][s] = *(const bfrag*)&wn_bf[(size_t)col*C + s*32 + quad*8];
  }
  #pragma unroll
  for (int mt=0; mt<7; ++mt){
    bfrag Af[KS];
    #pragma unroll
    for (int s=0; s<KS; ++s)
      Af[s] = *(const bfrag*)&A[mt*16 + lane15][s*32 + quad*8];
    if (mt < 6){
      const int rbase = mt*16 + quad*4;
      const int p = rbase / 24;
      #pragma unroll
      for (int nt=0; nt<NTW; ++nt){
        f32x4 acc = {0.f,0.f,0.f,0.f};
        #pragma unroll
        for (int s=0; s<KS; ++s)
          acc = __builtin_amdgcn_mfma_f32_16x16x32_bf16(Af[s], Bn[nt][s], acc, 0, 0, 0);
        float m = fmaxf(fmaxf(acc[0], acc[1]), fmaxf(acc[2], acc[3]));
        const int col = (wv*NTW + nt)*16 + lane15;
        atomicMax(&res[p][col], fenc(m));
      }
    } else {
      #pragma unroll
      for (int nt=0; nt<NTW; ++nt){
        const int col = (wv*NTW + nt)*16 + lane15;
        f32x4 acc = {0.f,0.f,0.f,0.f};
        #pragma unroll
        for (int s=0; s<KS; ++s){
          bfrag Bd = *(const bfrag*)&wd_bf[(size_t)col*C + s*32 + quad*8];
          acc = __builtin_amdgcn_mfma_f32_16x16x32_bf16(Af[s], Bd, acc, 0, 0, 0);
        }
        if (quad == 0){
          #pragma unroll
          for (int r=0;r<4;++r) cst_s[r][col] = acc[r];
        }
      }
    }
  }
  __syncthreads();
  for (int i=t; i<4*O; i+=256){
    int p = i/O, o = i - p*O;
    float mx = fdec(res[p][o]);
    float vv = (mx + cst_s[p][o]) * bn_scale(g[o]) + bb[o];
    outT[((size_t)b*NPTS + n0 + p)*O + o] = fmaxf(vv, 0.f);
  }
}

// ---------------- conv5 v3: LDS-staged split-bf16 MFMA GEMM + max over n ----------------
__global__ __launch_bounds__(256) void conv5_v3(const unsigned short* __restrict__ xhi,
    const unsigned short* __restrict__ xlo, const unsigned short* __restrict__ whi,
    const unsigned short* __restrict__ wlo, const float* __restrict__ g,
    const float* __restrict__ bb, float* __restrict__ out5){
  __shared__ __align__(16) unsigned short Ah_s[128*32];
  __shared__ __align__(16) unsigned short Al_s[128*32];
  __shared__ __align__(16) unsigned short Bh_s[64*32];
  __shared__ __align__(16) unsigned short Bl_s[64*32];
  const int t = threadIdx.x;
  const int row0 = blockIdx.x*128, o0 = blockIdx.y*64;
  const int b = row0 / NPTS;   // 128 | NPTS, so a block never straddles batches
  const int wv = t >> 6, l = t & 63, lane15 = l & 15, quad = l >> 4;
  const int ar = t >> 2, ac = (t & 3)*8;
  const unsigned short* gAh0 = xhi + (size_t)(row0 + ar)*512 + ac;
  const unsigned short* gAh1 = xhi + (size_t)(row0 + 64 + ar)*512 + ac;
  const unsigned short* gAl0 = xlo + (size_t)(row0 + ar)*512 + ac;
  const unsigned short* gAl1 = xlo + (size_t)(row0 + 64 + ar)*512 + ac;
  const unsigned short* gBh  = whi + (size_t)(o0 + ar)*512 + ac;
  const unsigned short* gBl  = wlo + (size_t)(o0 + ar)*512 + ac;

  uint4 pf0 = *(const uint4*)gAh0;
  uint4 pf1 = *(const uint4*)gAh1;
  uint4 pf2 = *(const uint4*)gAl0;
  uint4 pf3 = *(const uint4*)gAl1;
  uint4 pf4 = *(const uint4*)gBh;
  uint4 pf5 = *(const uint4*)gBl;

  f32x4 acc[2][4];
  #pragma unroll
  for (int mt=0;mt<2;++mt)
    #pragma unroll
    for (int nt=0;nt<4;++nt) acc[mt][nt] = (f32x4){0.f,0.f,0.f,0.f};

  for (int ks=0; ks<16; ++ks){
    *(uint4*)&Ah_s[t*8]        = pf0;
    *(uint4*)&Ah_s[2048 + t*8] = pf1;
    *(uint4*)&Al_s[t*8]        = pf2;
    *(uint4*)&Al_s[2048 + t*8] = pf3;
    *(uint4*)&Bh_s[t*8]        = pf4;
    *(uint4*)&Bl_s[t*8]        = pf5;
    __syncthreads();
    if (ks < 15){
      const int koff = (ks+1)*32;
      pf0 = *(const uint4*)(gAh0 + koff);
      pf1 = *(const uint4*)(gAh1 + koff);
      pf2 = *(const uint4*)(gAl0 + koff);
      pf3 = *(const uint4*)(gAl1 + koff);
      pf4 = *(const uint4*)(gBh  + koff);
      pf5 = *(const uint4*)(gBl  + koff);
    }
    bfrag Afh[2], Afl[2], Bfh[4], Bfl[4];
    #pragma unroll
    for (int mt=0;mt<2;++mt){
      const int m = wv*32 + mt*16 + lane15;
      Afh[mt] = *(const bfrag*)&Ah_s[m*32 + quad*8];
      Afl[mt] = *(const bfrag*)&Al_s[m*32 + quad*8];
    }
    #pragma unroll
    for (int nt=0;nt<4;++nt){
      const int oc = nt*16 + lane15;
      Bfh[nt] = *(const bfrag*)&Bh_s[oc*32 + quad*8];
      Bfl[nt] = *(const bfrag*)&Bl_s[oc*32 + quad*8];
    }
    #pragma unroll
    for (int mt=0;mt<2;++mt)
      #pragma unroll
      for (int nt=0;nt<4;++nt){
        acc[mt][nt] = __builtin_amdgcn_mfma_f32_16x16x32_bf16(Afh[mt], Bfh[nt], acc[mt][nt], 0, 0, 0);
        acc[mt][nt] = __builtin_amdgcn_mfma_f32_16x16x32_bf16(Afl[mt], Bfh[nt], acc[mt][nt], 0, 0, 0);
        acc[mt][nt] = __builtin_amdgcn_mfma_f32_16x16x32_bf16(Afh[mt], Bfl[nt], acc[mt][nt], 0, 0, 0);
      }
    __syncthreads();
  }
  #pragma unroll
  for (int nt=0;nt<4;++nt){
    float m = NEG_INF;
    #pragma unroll
    for (int mt=0;mt<2;++mt)
      #pragma unroll
      for (int r=0;r<4;++r) m = fmaxf(m, acc[mt][nt][r]);
    m = fmaxf(m, __shfl_xor(m, 16, 64));
    m = fmaxf(m, __shfl_xor(m, 32, 64));
    if (quad == 0){
      const int o = o0 + nt*16 + lane15;
      float vv = fmaxf(m * bn_scale(g[o]) + bb[o], 0.f);
      atomicMax((int*)&out5[(size_t)b*1024 + o], __float_as_int(vv));
    }
  }
}

__global__ void zero_kernel(float* __restrict__ p, int nfloats){
  int i = blockIdx.x*blockDim.x + threadIdx.x;
  if (i < nfloats) p[i] = 0.f;
}

// ---------------- FC layers ----------------
__global__ void fc_kernel(const float* __restrict__ in, const float* __restrict__ w,
                          const float* __restrict__ g, const float* __restrict__ bb,
                          float* __restrict__ out, int IN, int O){
  int i = blockIdx.x*blockDim.x + threadIdx.x;
  if (i >= BATCH*O) return;
  int b = i / O, o = i - b*O;
  const float* inb = in + (size_t)b*IN;
  const float* wo  = w + (size_t)o*IN;
  float s = 0.f;
  for (int c=0;c<IN;++c) s += inb[c]*wo[c];
  if (g){ s = s*bn_scale(g[o]) + bb[o]; s = fmaxf(s, 0.f); }
  out[i] = s;
}

extern "C" void kernel_launch(void* const* d_in, const int* in_sizes, int n_in,
                              void* d_out, int out_size, void* d_ws, size_t ws_size,
                              hipStream_t stream){
  const float* x   = (const float*)d_in[0];
  const float* w1  = (const float*)d_in[1];
  const float* w2  = (const float*)d_in[2];
  const float* w3  = (const float*)d_in[3];
  const float* w4  = (const float*)d_in[4];
  const float* w5  = (const float*)d_in[5];
  const float* fw1 = (const float*)d_in[6];
  const float* fw2 = (const float*)d_in[7];
  const float* fw3 = (const float*)d_in[8];
  const float* g1 = (const float*)d_in[9];  const float* b1 = (const float*)d_in[10];
  const float* g2 = (const float*)d_in[11]; const float* b2 = (const float*)d_in[12];
  const float* g3 = (const float*)d_in[13]; const float* b3 = (const float*)d_in[14];
  const float* g4 = (const float*)d_in[15]; const float* b4 = (const float*)d_in[16];
  const float* g5 = (const float*)d_in[17]; const float* b5 = (const float*)d_in[18];
  const float* g6 = (const float*)d_in[19]; const float* b6 = (const float*)d_in[20];
  const float* g7 = (const float*)d_in[21]; const float* b7 = (const float*)d_in[22];

  float* ws = (float*)d_ws;
  size_t off = 0;
  // x1..x3 channel-major; this 4.19M-float region is later reused as xcat_lo
  float* x1  = ws + off; off += (size_t)BATCH*64*NPTS;
  float* x2  = ws + off; off += (size_t)BATCH*64*NPTS;
  float* x3  = ws + off; off += (size_t)BATCH*128*NPTS;
  unsigned short* xcat_lo = (unsigned short*)x1;           // alias: x1..x3 dead before xcat runs
  unsigned short* xcat_hi = (unsigned short*)(ws + off); off += (size_t)BATCH*256*NPTS; // = B*N*512 bf16
  float* x1T = ws + off; off += (size_t)BATCH*64*NPTS;
  float* x2T = ws + off; off += (size_t)BATCH*64*NPTS;
  float* x3T = ws + off; off += (size_t)BATCH*128*NPTS;
  float* x4T = ws + off; off += (size_t)BATCH*256*NPTS;
  float* xT0 = ws + off; off += (size_t)BATCH*3*NPTS;
  float* sq  = ws + off; off += (size_t)BATCH*NPTS;
  int*  idx  = (int*)(ws + off); off += (size_t)BATCH*NPTS*KNN;
  float* out5 = ws + off; off += BATCH*1024;
  float* h6 = ws + off;   off += BATCH*512;
  float* h7 = ws + off;   off += BATCH*256;
  float* wnT1 = ws + off; off += 3*64;
  float* wdT1 = ws + off; off += 3*64;
  unsigned short* wn2 = (unsigned short*)(ws + off); off += 64*64/2;
  unsigned short* wd2 = (unsigned short*)(ws + off); off += 64*64/2;
  unsigned short* wn3 = (unsigned short*)(ws + off); off += 128*64/2;
  unsigned short* wd3 = (unsigned short*)(ws + off); off += 128*64/2;
  unsigned short* wn4 = (unsigned short*)(ws + off); off += 256*128/2;
  unsigned short* wd4 = (unsigned short*)(ws + off); off += 256*128/2;
  unsigned short* w5hi = (unsigned short*)(ws + off); off += 1024*512/2;
  unsigned short* w5lo = (unsigned short*)(ws + off); off += 1024*512/2;

  dim3 gridKNN(NPTS/8, BATCH);
  dim3 gridEC(NPTS/4, BATCH);

  // layer 1 (C=3 -> 64, fp32)
  xt0_kernel<<<64, 256, 0, stream>>>(x, xT0);
  sqnorm_kernel<<<64, 256, 0, stream>>>(x, sq, 3);
  knn_kernel<3><<<gridKNN, 256, 0, stream>>>(x, sq, idx);
  wprep_kernel<<<1, 256, 0, stream>>>(w1, wnT1, wdT1, 64, 3);
  edgeconv1_kernel<<<gridEC, 256, 0, stream>>>(xT0, idx, wnT1, wdT1, g1, b1, x1T);
  transpose2d_kernel<<<dim3(2,64,BATCH), 256, 0, stream>>>(x1T, x1, NPTS, 64);
  // layer 2 (C=64 -> 64, bf16 MFMA)
  sqnorm_kernel<<<64, 256, 0, stream>>>(x1, sq, 64);
  knn_kernel<64><<<gridKNN, 256, 0, stream>>>(x1, sq, idx);
  wprep_bf_kernel<<<16, 256, 0, stream>>>(w2, wn2, wd2, 64, 64);
  edgeconv_mfma<64,64><<<gridEC, 256, 0, stream>>>(x1T, idx, wn2, wd2, g2, b2, x2T);
  transpose2d_kernel<<<dim3(2,64,BATCH), 256, 0, stream>>>(x2T, x2, NPTS, 64);
  // layer 3 (C=64 -> 128, bf16 MFMA)
  sqnorm_kernel<<<64, 256, 0, stream>>>(x2, sq, 64);
  knn_kernel<64><<<gridKNN, 256, 0, stream>>>(x2, sq, idx);
  wprep_bf_kernel<<<32, 256, 0, stream>>>(w3, wn3, wd3, 128, 64);
  edgeconv_mfma<64,128><<<gridEC, 256, 0, stream>>>(x2T, idx, wn3, wd3, g3, b3, x3T);
  transpose2d_kernel<<<dim3(4,64,BATCH), 256, 0, stream>>>(x3T, x3, NPTS, 128);
  // layer 4 (C=128 -> 256, bf16 MFMA)
  sqnorm_kernel<<<64, 256, 0, stream>>>(x3, sq, 128);
  knn_kernel<128><<<gridKNN, 256, 0, stream>>>(x3, sq, idx);
  wprep_bf_kernel<<<128, 256, 0, stream>>>(w4, wn4, wd4, 256, 128);
  edgeconv_mfma<128,256><<<gridEC, 256, 0, stream>>>(x3T, idx, wn4, wd4, g4, b4, x4T);
  // conv5 (split-bf16 MFMA, LDS-staged) + global max over n
  xcat_kernel<<<(BATCH*NPTS*128)/256, 256, 0, stream>>>(x1T, x2T, x3T, x4T, xcat_hi, xcat_lo);
  bfsplit_kernel<<<512, 256, 0, stream>>>(w5, w5hi, w5lo, 1024*512/4);
  zero_kernel<<<32, 256, 0, stream>>>(out5, BATCH*1024);
  conv5_v3<<<dim3(BATCH*NPTS/128, 16), 256, 0, stream>>>(xcat_hi, xcat_lo, w5hi, w5lo, g5, b5, out5);
  // FC head
  fc_kernel<<<16, 256, 0, stream>>>(out5, fw1, g6, b6, h6, 1024, 512);
  fc_kernel<<<8, 256, 0, stream>>>(h6, fw2, g7, b7, h7, 512, 256);
  fc_kernel<<<2, 256, 0, stream>>>(h7, fw3, nullptr, nullptr, (float*)d_out, 256, 40);
}

// Round 15
// 908.586 us; speedup vs baseline: 1.5701x; 1.1687x over previous
//
#include <hip/hip_runtime.h>
#include <hip/hip_bf16.h>
#include <math.h>

#define BATCH 8
#define NPTS  2048
#define KNN   20
#define NEG_INF (-3.402823466e38f)

static __device__ __forceinline__ float bn_scale(float g){ return g * rsqrtf(1.0f + 1e-5f); }

// bf16 round-to-nearest-even
static __device__ __forceinline__ unsigned short bf16r(float f){
  unsigned int u = __float_as_uint(f);
  unsigned int r = (u + 0x7fffu + ((u >> 16) & 1u)) >> 16;
  return (unsigned short)r;
}
static __device__ __forceinline__ float bf2f(unsigned short h){
  return __uint_as_float((unsigned int)h << 16);
}
// ordered-int encode/decode for float max via atomicMax(uint)
static __device__ __forceinline__ unsigned int fenc(float f){
  unsigned int u = __float_as_uint(f);
  return (u & 0x80000000u) ? ~u : (u | 0x80000000u);
}
static __device__ __forceinline__ float fdec(unsigned int e){
  return __uint_as_float((e & 0x80000000u) ? (e & 0x7fffffffu) : ~e);
}

using bfrag = __attribute__((ext_vector_type(8))) short;  // 8 bf16 (4 VGPRs)
using f32x4 = __attribute__((ext_vector_type(4))) float;  // 4 fp32 acc

// ---- DPP-based wave argmax (lexicographic value desc, idx asc); winner in lane 63 ----
template<int CTRL>
static __device__ __forceinline__ void dpp_amax(float &bv, int &bi){
  int ov_i = __builtin_amdgcn_update_dpp(__float_as_int(NEG_INF), __float_as_int(bv),
                                         CTRL, 0xf, 0xf, false);
  int oi   = __builtin_amdgcn_update_dpp(0x7fffffff, bi, CTRL, 0xf, 0xf, false);
  float ov = __int_as_float(ov_i);
  if (ov > bv || (ov == bv && oi < bi)){ bv = ov; bi = oi; }
}
static __device__ __forceinline__ int wave_argmax_idx(float bv, int bi){
  dpp_amax<0x111>(bv, bi);   // row_shr:1
  dpp_amax<0x112>(bv, bi);   // row_shr:2
  dpp_amax<0x114>(bv, bi);   // row_shr:4
  dpp_amax<0x118>(bv, bi);   // row_shr:8
  dpp_amax<0x142>(bv, bi);   // row_bcast:15
  dpp_amax<0x143>(bv, bi);   // row_bcast:31
  return __builtin_amdgcn_readlane(bi, 63);
}
// ---- DPP wave sum (identity 0.0 injected); total broadcast from lane 63 ----
template<int CTRL>
static __device__ __forceinline__ float dpp_fadd(float v){
  int ov = __builtin_amdgcn_update_dpp(0, __float_as_int(v), CTRL, 0xf, 0xf, false);
  return v + __int_as_float(ov);
}
static __device__ __forceinline__ float wave_sum(float v){
  v = dpp_fadd<0x111>(v); v = dpp_fadd<0x112>(v);
  v = dpp_fadd<0x114>(v); v = dpp_fadd<0x118>(v);
  v = dpp_fadd<0x142>(v); v = dpp_fadd<0x143>(v);
  return __int_as_float(__builtin_amdgcn_readlane(__float_as_int(v), 63));
}

// ---------------- squared norms per point (reads channel-major [C][N]) ----------------
__global__ void sqnorm_kernel(const float* __restrict__ X, float* __restrict__ sq, int C){
  int i = blockIdx.x*blockDim.x + threadIdx.x;
  if (i >= BATCH*NPTS) return;
  int b = i / NPTS, n = i - b*NPTS;
  const float* xb = X + (size_t)b*C*NPTS + n;
  float s = 0.f;
  for (int c=0;c<C;++c){ float v = xb[(size_t)c*NPTS]; s += v*v; }
  sq[i] = s;
}

// ---------------- kNN v9: v8 + point-major ctrs (float4 broadcast reads) ----------------
// ctrs[8][CPAD] point-major: per 4-channel group, 8 ds_read_b128 broadcasts replace
// 32 ds_read_b32 broadcasts (issue-slot reduction; accumulation order unchanged -> bit-exact).
template<int C>
__global__ __launch_bounds__(256, 2) void knn_kernel(const float* __restrict__ X,
                                                     const float* __restrict__ sq,
                                                     int* __restrict__ idxout){
  const int b = blockIdx.y;
  const int n0 = blockIdx.x * 8;
  const int t = threadIdx.x;
  constexpr int CPAD = (C + 3) & ~3;
  __shared__ __align__(16) float dist[4][NPTS];
  __shared__ __align__(16) float ctrs[8][CPAD];
  __shared__ float sqn[8];
  const float* xb = X + (size_t)b*C*NPTS;
  for (int i=t; i<8*C; i+=256){
    int p = i / C, c = i - p*C;
    ctrs[p][c] = xb[(size_t)c*NPTS + n0 + p];
  }
  if (t < 8) sqn[t] = sq[b*NPTS + n0 + t];
  __syncthreads();

  const int m0 = t * 8;
  float acc[8][8];
  #pragma unroll
  for (int i=0;i<8;++i)
    #pragma unroll
    for (int j=0;j<8;++j) acc[i][j] = 0.f;
  if constexpr (C >= 4){
    for (int c0=0; c0<(C & ~3); c0+=4){
      float ctf[8][4];
      #pragma unroll
      for (int p=0;p<8;++p){
        float4 q = *(const float4*)&ctrs[p][c0];
        ctf[p][0]=q.x; ctf[p][1]=q.y; ctf[p][2]=q.z; ctf[p][3]=q.w;
      }
      #pragma unroll
      for (int cc=0;cc<4;++cc){
        const int c = c0 + cc;
        const float4 xa = *(const float4*)&xb[(size_t)c*NPTS + m0];
        const float4 xc = *(const float4*)&xb[(size_t)c*NPTS + m0 + 4];
        const float xm[8] = {xa.x,xa.y,xa.z,xa.w,xc.x,xc.y,xc.z,xc.w};
        #pragma unroll
        for (int i=0;i<8;++i){
          const float cv = ctf[i][cc];
          #pragma unroll
          for (int j=0;j<8;++j) acc[i][j] += cv*xm[j];
        }
      }
    }
  }
  for (int c=(C & ~3); c<C; ++c){
    const float4 xa = *(const float4*)&xb[(size_t)c*NPTS + m0];
    const float4 xc = *(const float4*)&xb[(size_t)c*NPTS + m0 + 4];
    const float xm[8] = {xa.x,xa.y,xa.z,xa.w,xc.x,xc.y,xc.z,xc.w};
    #pragma unroll
    for (int i=0;i<8;++i){
      const float cv = ctrs[i][c];
      #pragma unroll
      for (int j=0;j<8;++j) acc[i][j] += cv*xm[j];
    }
  }
  {
    const float4 sa = *(const float4*)&sq[b*NPTS + m0];
    const float4 sb = *(const float4*)&sq[b*NPTS + m0 + 4];
    const float sm[8] = {sa.x,sa.y,sa.z,sa.w,sb.x,sb.y,sb.z,sb.w};
    #pragma unroll
    for (int i=0;i<8;++i){
      const float si = sqn[i];
      #pragma unroll
      for (int j=0;j<8;++j) acc[i][j] = 2.f*acc[i][j] - si - sm[j];
    }
  }

  const int wv = t >> 6, lane = t & 63;
  #pragma unroll
  for (int rep=0; rep<2; ++rep){
    #pragma unroll
    for (int i=0;i<4;++i){
      *(float4*)&dist[i][m0]   = make_float4(acc[rep*4+i][0],acc[rep*4+i][1],acc[rep*4+i][2],acc[rep*4+i][3]);
      *(float4*)&dist[i][m0+4] = make_float4(acc[rep*4+i][4],acc[rep*4+i][5],acc[rep*4+i][6],acc[rep*4+i][7]);
    }
    __syncthreads();
    // initial scan: per-lane sorted top-4 (value desc, idx asc) in registers
    float s0=NEG_INF,s1=NEG_INF,s2=NEG_INF,s3=NEG_INF;
    int   i0=0x7fffffff,i1=0x7fffffff,i2=0x7fffffff,i3=0x7fffffff;
    #pragma unroll
    for (int j=0;j<32;++j){
      const float v = dist[wv][lane + 64*j];
      const int   m = lane + 64*j;
      const bool b0 = v > s0, b1 = v > s1, b2 = v > s2, b3 = v > s3;  // strict: stable ties
      const float n0 = b0 ? v : s0;            const int q0 = b0 ? m : i0;
      const float n1 = b0 ? s0 : (b1 ? v : s1); const int q1 = b0 ? i0 : (b1 ? m : i1);
      const float n2 = b1 ? s1 : (b2 ? v : s2); const int q2 = b1 ? i1 : (b2 ? m : i2);
      const float n3 = b2 ? s2 : (b3 ? v : s3); const int q3 = b2 ? i2 : (b3 ? m : i3);
      s0=n0;s1=n1;s2=n2;s3=n3; i0=q0;i1=q1;i2=q2;i3=q3;
    }
    int rem = 4;
    int* row = idxout + ((size_t)b*NPTS + n0 + rep*4 + wv)*KNN;
    for (int sel=0; sel<KNN; ++sel){
      const int widx = wave_argmax_idx(s0, i0);   // DPP reduction over queue heads
      if (lane == 0) row[sel] = widx;
      if ((widx & 63) == lane){
        const float lastv = s0; const int lasti = i0;
        s0=s1;i0=i1; s1=s2;i1=i2; s2=s3;i2=i3;
        rem--;
        if (rem == 0){
          float nv = NEG_INF; int ni = 0x7fffffff;
          #pragma unroll
          for (int j=0;j<32;++j){
            const float vv = dist[wv][lane + 64*j];
            const int   mi = lane + 64*j;
            const bool ok = (vv < lastv) || (vv == lastv && mi > lasti);
            if (ok && vv > nv){ nv = vv; ni = mi; }
          }
          s0 = nv; i0 = ni; rem = 1;
        }
      }
    }
    __syncthreads();
  }
}

// ---------------- fp32 weight prep (layer 1 only): wnT[c][o], wdT[c][o] ----------------
__global__ void wprep_kernel(const float* __restrict__ w, float* __restrict__ wnT,
                             float* __restrict__ wdT, int O, int C){
  int i = blockIdx.x*blockDim.x + threadIdx.x;
  if (i >= O*C) return;
  int c = i / O, o = i - c*O;
  float a = w[(size_t)o*2*C + c];
  wnT[(size_t)c*O + o] = a;
  wdT[(size_t)c*O + o] = w[(size_t)o*2*C + C + c] - a;
}

// ---------------- bf16 weight prep (layers 2-4): wn[o][c], wd[o][c] (k contiguous) -----
__global__ void wprep_bf_kernel(const float* __restrict__ w, unsigned short* __restrict__ wn,
                                unsigned short* __restrict__ wd, int O, int C){
  int i = blockIdx.x*blockDim.x + threadIdx.x;
  if (i >= O*C) return;
  int o = i / C, c = i - o*C;
  float a = w[(size_t)o*2*C + c];
  float d = w[(size_t)o*2*C + C + c] - a;
  wn[(size_t)o*C + c] = bf16r(a);
  wd[(size_t)o*C + c] = bf16r(d);
}

// ---------------- split-bf16 weight convert (conv5): hi = bf16(w), lo = bf16(w-hi) ------
__global__ void bfsplit_kernel(const float* __restrict__ in, unsigned short* __restrict__ hi,
                               unsigned short* __restrict__ lo, int nq){
  int i = blockIdx.x*blockDim.x + threadIdx.x;
  if (i >= nq) return;
  float4 v = *(const float4*)&in[(size_t)i*4];
  unsigned short h0=bf16r(v.x), h1=bf16r(v.y), h2=bf16r(v.z), h3=bf16r(v.w);
  unsigned short l0=bf16r(v.x-bf2f(h0)), l1=bf16r(v.y-bf2f(h1)),
                 l2=bf16r(v.z-bf2f(h2)), l3=bf16r(v.w-bf2f(h3));
  *(uint2*)&hi[(size_t)i*4] = make_uint2((unsigned)h0|((unsigned)h1<<16), (unsigned)h2|((unsigned)h3<<16));
  *(uint2*)&lo[(size_t)i*4] = make_uint2((unsigned)l0|((unsigned)l1<<16), (unsigned)l2|((unsigned)l3<<16));
}

// ---------------- xcat: concat x1T..x4T -> split-bf16 [b][n][512] ----------------
__global__ __launch_bounds__(256) void xcat_kernel(const float* __restrict__ x1T,
    const float* __restrict__ x2T, const float* __restrict__ x3T, const float* __restrict__ x4T,
    unsigned short* __restrict__ xhi, unsigned short* __restrict__ xlo){
  int i = blockIdx.x*blockDim.x + threadIdx.x;   // quad index over B*N*128
  if (i >= BATCH*NPTS*128) return;
  int q = i & 127, bn_ = i >> 7;
  int k = q*4;
  const float* src; int kk;
  if (k < 64)      { src = x1T + (size_t)bn_*64;  kk = k; }
  else if (k <128) { src = x2T + (size_t)bn_*64;  kk = k-64; }
  else if (k <256) { src = x3T + (size_t)bn_*128; kk = k-128; }
  else             { src = x4T + (size_t)bn_*256; kk = k-256; }
  float4 v = *(const float4*)&src[kk];
  unsigned short h0=bf16r(v.x), h1=bf16r(v.y), h2=bf16r(v.z), h3=bf16r(v.w);
  unsigned short l0=bf16r(v.x-bf2f(h0)), l1=bf16r(v.y-bf2f(h1)),
                 l2=bf16r(v.z-bf2f(h2)), l3=bf16r(v.w-bf2f(h3));
  *(uint2*)&xhi[(size_t)i*4] = make_uint2((unsigned)h0|((unsigned)h1<<16), (unsigned)h2|((unsigned)h3<<16));
  *(uint2*)&xlo[(size_t)i*4] = make_uint2((unsigned)l0|((unsigned)l1<<16), (unsigned)l2|((unsigned)l3<<16));
}

// ---------------- generic tiled transpose: in[R][Cc] -> out[Cc][R], per z-slice ----------------
__global__ __launch_bounds__(256) void transpose2d_kernel(const float* __restrict__ in,
    float* __restrict__ out, int R, int Cc){
  __shared__ float tile[32][33];
  const size_t boff = (size_t)blockIdx.z * (size_t)R * Cc;
  const int c0 = blockIdx.x*32, r0 = blockIdx.y*32;
  const int tx = threadIdx.x & 31, ty = threadIdx.x >> 5;
  #pragma unroll
  for (int j=0;j<4;++j){
    int r = ty*4 + j;
    tile[r][tx] = in[boff + (size_t)(r0+r)*Cc + c0 + tx];
  }
  __syncthreads();
  #pragma unroll
  for (int j=0;j<4;++j){
    int r = ty*4 + j;
    out[boff + (size_t)(c0+r)*R + r0 + tx] = tile[tx][r];
  }
}

// ---------------- x -> xT0 [N][3] ----------------
__global__ void xt0_kernel(const float* __restrict__ x, float* __restrict__ xT0){
  int i = blockIdx.x*blockDim.x + threadIdx.x;
  if (i >= BATCH*NPTS) return;
  int b = i / NPTS, n = i - b*NPTS;
  const float* xb = x + (size_t)b*3*NPTS;
  float v0 = xb[n], v1 = xb[NPTS + n], v2 = xb[2*NPTS + n];
  float* o = xT0 + ((size_t)b*NPTS + n)*3;
  o[0]=v0; o[1]=v1; o[2]=v2;
}

// ---------------- edge conv layer 1 (C=3, fp32): 4 points per block ----------------
__global__ __launch_bounds__(256) void edgeconv1_kernel(const float* __restrict__ xT0,
    const int* __restrict__ idx, const float* __restrict__ wnT, const float* __restrict__ wdT,
    const float* __restrict__ g, const float* __restrict__ bb, float* __restrict__ outT){
  const int b = blockIdx.y, n0 = blockIdx.x*4, t = threadIdx.x;
  __shared__ float nbr[4][KNN][3];
  __shared__ float ctr[4][3];
  __shared__ int   idxs[4][KNN];
  const float* xb = xT0 + (size_t)b*NPTS*3;
  if (t < 4*KNN) idxs[t/KNN][t%KNN] = idx[((size_t)b*NPTS + n0 + t/KNN)*KNN + (t%KNN)];
  if (t >= 128 && t < 140){ int i = t-128; ctr[i/3][i%3] = xb[(size_t)(n0 + i/3)*3 + i%3]; }
  __syncthreads();
  for (int i=t; i<4*KNN*3; i+=256){
    int p = i/(KNN*3), r = i - p*(KNN*3), k = r/3, c = r - k*3;
    nbr[p][k][c] = xb[(size_t)idxs[p][k]*3 + c];
  }
  __syncthreads();
  const int p = t >> 6, o = t & 63;
  const float wn0 = wnT[o], wn1 = wnT[64+o], wn2 = wnT[128+o];
  const float cst = ctr[p][0]*wdT[o] + ctr[p][1]*wdT[64+o] + ctr[p][2]*wdT[128+o];
  float best = NEG_INF;
  #pragma unroll
  for (int k=0;k<KNN;++k){
    float a = nbr[p][k][0]*wn0 + nbr[p][k][1]*wn1 + nbr[p][k][2]*wn2;
    best = fmaxf(best, a);
  }
  float vv = (best + cst) * bn_scale(g[o]) + bb[o];
  outT[((size_t)b*NPTS + n0 + p)*64 + o] = fmaxf(vv, 0.f);
}

// ---------------- edge conv MFMA (bf16): block = 4 points ----------------
template<int C, int O>
__global__ __launch_bounds__(256) void edgeconv_mfma(const float* __restrict__ xT,
    const int* __restrict__ idx,
    const unsigned short* __restrict__ wn_bf, const unsigned short* __restrict__ wd_bf,
    const float* __restrict__ g, const float* __restrict__ bb, float* __restrict__ outT){
  constexpr int ROWS = 112;        // 7 m-tiles of 16
  constexpr int CP   = C + 8;      // padded row (bf16): 16B-aligned stride, conflict-free b128
  constexpr int KS   = C / 32;     // k-steps per tile
  constexpr int NTW  = O / 64;     // n-tiles per wave (O/16 tiles over 4 waves)
  __shared__ __align__(16) unsigned short A[ROWS][CP];
  __shared__ unsigned int res[4][O];
  __shared__ float cst_s[4][O];
  __shared__ int idxs[4][KNN];
  const int b = blockIdx.y, n0 = blockIdx.x*4, t = threadIdx.x;
  const float* xTb = xT + (size_t)b*NPTS*C;
  if (t < 4*KNN) idxs[t/KNN][t%KNN] = idx[((size_t)b*NPTS + n0 + t/KNN)*KNN + (t%KNN)];
  for (int i=t; i<4*O; i+=256) res[i/O][i & (O-1)] = 0u;   // 0 < fenc(any finite)
  __syncthreads();
  for (int i=t; i<ROWS*(C/4); i+=256){
    int r = i/(C/4), c4 = i - r*(C/4);
    float4 v = make_float4(0.f,0.f,0.f,0.f);
    if (r < 96){
      int p = r/24, kk = r - p*24;
      int src = idxs[p][kk < KNN ? kk : 0];        // pad rows duplicate nbr 0 (max-neutral)
      v = *(const float4*)&xTb[(size_t)src*C + c4*4];
    } else if (r < 100){
      v = *(const float4*)&xTb[(size_t)(n0 + (r-96))*C + c4*4];
    }
    unsigned int lo = (unsigned int)bf16r(v.x) | ((unsigned int)bf16r(v.y) << 16);
    unsigned int hi = (unsigned int)bf16r(v.z) | ((unsigned int)bf16r(v.w) << 16);
    *(uint2*)&A[r][c4*4] = make_uint2(lo, hi);
  }
  __syncthreads();

  const int wv = t >> 6, l = t & 63;
  const int lane15 = l & 15, quad = l >> 4;
  bfrag Bn[NTW][KS];
  #pragma unroll
  for (int nt=0; nt<NTW; ++nt){
    const int col = (wv*NTW + nt)*16 + lane15;
    #pragma unroll
    for (int s=0; s<KS; ++s)
      Bn[nt][s] = *(const bfrag*)&wn_bf[(size_t)col*C + s*32 + quad*8];
  }
  #pragma unroll
  for (int mt=0; mt<7; ++mt){
    bfrag Af[KS];
    #pragma unroll
    for (int s=0; s<KS; ++s)
      Af[s] = *(const bfrag*)&A[mt*16 + lane15][s*32 + quad*8];
    if (mt < 6){
      const int rbase = mt*16 + quad*4;
      const int p = rbase / 24;
      #pragma unroll
      for (int nt=0; nt<NTW; ++nt){
        f32x4 acc = {0.f,0.f,0.f,0.f};
        #pragma unroll
        for (int s=0; s<KS; ++s)
          acc = __builtin_amdgcn_mfma_f32_16x16x32_bf16(Af[s], Bn[nt][s], acc, 0, 0, 0);
        float m = fmaxf(fmaxf(acc[0], acc[1]), fmaxf(acc[2], acc[3]));
        const int col = (wv*NTW + nt)*16 + lane15;
        atomicMax(&res[p][col], fenc(m));
      }
    } else {
      #pragma unroll
      for (int nt=0; nt<NTW; ++nt){
        const int col = (wv*NTW + nt)*16 + lane15;
        f32x4 acc = {0.f,0.f,0.f,0.f};
        #pragma unroll
        for (int s=0; s<KS; ++s){
          bfrag Bd = *(const bfrag*)&wd_bf[(size_t)col*C + s*32 + quad*8];
          acc = __builtin_amdgcn_mfma_f32_16x16x32_bf16(Af[s], Bd, acc, 0, 0, 0);
        }
        if (quad == 0){
          #pragma unroll
          for (int r=0;r<4;++r) cst_s[r][col] = acc[r];
        }
      }
    }
  }
  __syncthreads();
  for (int i=t; i<4*O; i+=256){
    int p = i/O, o = i - p*O;
    float mx = fdec(res[p][o]);
    float vv = (mx + cst_s[p][o]) * bn_scale(g[o]) + bb[o];
    outT[((size_t)b*NPTS + n0 + p)*O + o] = fmaxf(vv, 0.f);
  }
}

// ---------------- conv5 v3: LDS-staged split-bf16 MFMA GEMM + max over n ----------------
__global__ __launch_bounds__(256) void conv5_v3(const unsigned short* __restrict__ xhi,
    const unsigned short* __restrict__ xlo, const unsigned short* __restrict__ whi,
    const unsigned short* __restrict__ wlo, const float* __restrict__ g,
    const float* __restrict__ bb, float* __restrict__ out5){
  __shared__ __align__(16) unsigned short Ah_s[128*32];
  __shared__ __align__(16) unsigned short Al_s[128*32];
  __shared__ __align__(16) unsigned short Bh_s[64*32];
  __shared__ __align__(16) unsigned short Bl_s[64*32];
  const int t = threadIdx.x;
  const int row0 = blockIdx.x*128, o0 = blockIdx.y*64;
  const int b = row0 / NPTS;   // 128 | NPTS, so a block never straddles batches
  const int wv = t >> 6, l = t & 63, lane15 = l & 15, quad = l >> 4;
  const int ar = t >> 2, ac = (t & 3)*8;
  const unsigned short* gAh0 = xhi + (size_t)(row0 + ar)*512 + ac;
  const unsigned short* gAh1 = xhi + (size_t)(row0 + 64 + ar)*512 + ac;
  const unsigned short* gAl0 = xlo + (size_t)(row0 + ar)*512 + ac;
  const unsigned short* gAl1 = xlo + (size_t)(row0 + 64 + ar)*512 + ac;
  const unsigned short* gBh  = whi + (size_t)(o0 + ar)*512 + ac;
  const unsigned short* gBl  = wlo + (size_t)(o0 + ar)*512 + ac;

  uint4 pf0 = *(const uint4*)gAh0;
  uint4 pf1 = *(const uint4*)gAh1;
  uint4 pf2 = *(const uint4*)gAl0;
  uint4 pf3 = *(const uint4*)gAl1;
  uint4 pf4 = *(const uint4*)gBh;
  uint4 pf5 = *(const uint4*)gBl;

  f32x4 acc[2][4];
  #pragma unroll
  for (int mt=0;mt<2;++mt)
    #pragma unroll
    for (int nt=0;nt<4;++nt) acc[mt][nt] = (f32x4){0.f,0.f,0.f,0.f};

  for (int ks=0; ks<16; ++ks){
    *(uint4*)&Ah_s[t*8]        = pf0;
    *(uint4*)&Ah_s[2048 + t*8] = pf1;
    *(uint4*)&Al_s[t*8]        = pf2;
    *(uint4*)&Al_s[2048 + t*8] = pf3;
    *(uint4*)&Bh_s[t*8]        = pf4;
    *(uint4*)&Bl_s[t*8]        = pf5;
    __syncthreads();
    if (ks < 15){
      const int koff = (ks+1)*32;
      pf0 = *(const uint4*)(gAh0 + koff);
      pf1 = *(const uint4*)(gAh1 + koff);
      pf2 = *(const uint4*)(gAl0 + koff);
      pf3 = *(const uint4*)(gAl1 + koff);
      pf4 = *(const uint4*)(gBh  + koff);
      pf5 = *(const uint4*)(gBl  + koff);
    }
    bfrag Afh[2], Afl[2], Bfh[4], Bfl[4];
    #pragma unroll
    for (int mt=0;mt<2;++mt){
      const int m = wv*32 + mt*16 + lane15;
      Afh[mt] = *(const bfrag*)&Ah_s[m*32 + quad*8];
      Afl[mt] = *(const bfrag*)&Al_s[m*32 + quad*8];
    }
    #pragma unroll
    for (int nt=0;nt<4;++nt){
      const int oc = nt*16 + lane15;
      Bfh[nt] = *(const bfrag*)&Bh_s[oc*32 + quad*8];
      Bfl[nt] = *(const bfrag*)&Bl_s[oc*32 + quad*8];
    }
    #pragma unroll
    for (int mt=0;mt<2;++mt)
      #pragma unroll
      for (int nt=0;nt<4;++nt){
        acc[mt][nt] = __builtin_amdgcn_mfma_f32_16x16x32_bf16(Afh[mt], Bfh[nt], acc[mt][nt], 0, 0, 0);
        acc[mt][nt] = __builtin_amdgcn_mfma_f32_16x16x32_bf16(Afl[mt], Bfh[nt], acc[mt][nt], 0, 0, 0);
        acc[mt][nt] = __builtin_amdgcn_mfma_f32_16x16x32_bf16(Afh[mt], Bfl[nt], acc[mt][nt], 0, 0, 0);
      }
    __syncthreads();
  }
  #pragma unroll
  for (int nt=0;nt<4;++nt){
    float m = NEG_INF;
    #pragma unroll
    for (int mt=0;mt<2;++mt)
      #pragma unroll
      for (int r=0;r<4;++r) m = fmaxf(m, acc[mt][nt][r]);
    m = fmaxf(m, __shfl_xor(m, 16, 64));
    m = fmaxf(m, __shfl_xor(m, 32, 64));
    if (quad == 0){
      const int o = o0 + nt*16 + lane15;
      float vv = fmaxf(m * bn_scale(g[o]) + bb[o], 0.f);
      atomicMax((int*)&out5[(size_t)b*1024 + o], __float_as_int(vv));
    }
  }
}

__global__ void zero_kernel(float* __restrict__ p, int nfloats){
  int i = blockIdx.x*blockDim.x + threadIdx.x;
  if (i < nfloats) p[i] = 0.f;
}

// ---------------- FC layers: one wave per (b,o), coalesced lane-strided reads ----------
__global__ __launch_bounds__(256) void fc_wave_kernel(const float* __restrict__ in,
    const float* __restrict__ w, const float* __restrict__ g, const float* __restrict__ bb,
    float* __restrict__ out, int IN, int O){
  const int wid = (blockIdx.x*256 + threadIdx.x) >> 6;
  const int lane = threadIdx.x & 63;
  if (wid >= BATCH*O) return;
  const int b = wid / O, o = wid - b*O;
  const float* inb = in + (size_t)b*IN;
  const float* wo  = w + (size_t)o*IN;
  float s = 0.f;
  for (int c = lane; c < IN; c += 64) s += inb[c]*wo[c];   // coalesced across the wave
  s = wave_sum(s);
  if (lane == 0){
    if (g){ s = s*bn_scale(g[o]) + bb[o]; s = fmaxf(s, 0.f); }
    out[wid] = s;
  }
}

extern "C" void kernel_launch(void* const* d_in, const int* in_sizes, int n_in,
                              void* d_out, int out_size, void* d_ws, size_t ws_size,
                              hipStream_t stream){
  const float* x   = (const float*)d_in[0];
  const float* w1  = (const float*)d_in[1];
  const float* w2  = (const float*)d_in[2];
  const float* w3  = (const float*)d_in[3];
  const float* w4  = (const float*)d_in[4];
  const float* w5  = (const float*)d_in[5];
  const float* fw1 = (const float*)d_in[6];
  const float* fw2 = (const float*)d_in[7];
  const float* fw3 = (const float*)d_in[8];
  const float* g1 = (const float*)d_in[9];  const float* b1 = (const float*)d_in[10];
  const float* g2 = (const float*)d_in[11]; const float* b2 = (const float*)d_in[12];
  const float* g3 = (const float*)d_in[13]; const float* b3 = (const float*)d_in[14];
  const float* g4 = (const float*)d_in[15]; const float* b4 = (const float*)d_in[16];
  const float* g5 = (const float*)d_in[17]; const float* b5 = (const float*)d_in[18];
  const float* g6 = (const float*)d_in[19]; const float* b6 = (const float*)d_in[20];
  const float* g7 = (const float*)d_in[21]; const float* b7 = (const float*)d_in[22];

  float* ws = (float*)d_ws;
  size_t off = 0;
  // x1..x3 channel-major; this 4.19M-float region is later reused as xcat_lo
  float* x1  = ws + off; off += (size_t)BATCH*64*NPTS;
  float* x2  = ws + off; off += (size_t)BATCH*64*NPTS;
  float* x3  = ws + off; off += (size_t)BATCH*128*NPTS;
  unsigned short* xcat_lo = (unsigned short*)x1;           // alias: x1..x3 dead before xcat runs
  unsigned short* xcat_hi = (unsigned short*)(ws + off); off += (size_t)BATCH*256*NPTS; // = B*N*512 bf16
  float* x1T = ws + off; off += (size_t)BATCH*64*NPTS;
  float* x2T = ws + off; off += (size_t)BATCH*64*NPTS;
  float* x3T = ws + off; off += (size_t)BATCH*128*NPTS;
  float* x4T = ws + off; off += (size_t)BATCH*256*NPTS;
  float* xT0 = ws + off; off += (size_t)BATCH*3*NPTS;
  float* sq  = ws + off; off += (size_t)BATCH*NPTS;
  int*  idx  = (int*)(ws + off); off += (size_t)BATCH*NPTS*KNN;
  float* out5 = ws + off; off += BATCH*1024;
  float* h6 = ws + off;   off += BATCH*512;
  float* h7 = ws + off;   off += BATCH*256;
  float* wnT1 = ws + off; off += 3*64;
  float* wdT1 = ws + off; off += 3*64;
  unsigned short* wn2 = (unsigned short*)(ws + off); off += 64*64/2;
  unsigned short* wd2 = (unsigned short*)(ws + off); off += 64*64/2;
  unsigned short* wn3 = (unsigned short*)(ws + off); off += 128*64/2;
  unsigned short* wd3 = (unsigned short*)(ws + off); off += 128*64/2;
  unsigned short* wn4 = (unsigned short*)(ws + off); off += 256*128/2;
  unsigned short* wd4 = (unsigned short*)(ws + off); off += 256*128/2;
  unsigned short* w5hi = (unsigned short*)(ws + off); off += 1024*512/2;
  unsigned short* w5lo = (unsigned short*)(ws + off); off += 1024*512/2;

  dim3 gridKNN(NPTS/8, BATCH);
  dim3 gridEC(NPTS/4, BATCH);

  // layer 1 (C=3 -> 64, fp32)
  xt0_kernel<<<64, 256, 0, stream>>>(x, xT0);
  sqnorm_kernel<<<64, 256, 0, stream>>>(x, sq, 3);
  knn_kernel<3><<<gridKNN, 256, 0, stream>>>(x, sq, idx);
  wprep_kernel<<<1, 256, 0, stream>>>(w1, wnT1, wdT1, 64, 3);
  edgeconv1_kernel<<<gridEC, 256, 0, stream>>>(xT0, idx, wnT1, wdT1, g1, b1, x1T);
  transpose2d_kernel<<<dim3(2,64,BATCH), 256, 0, stream>>>(x1T, x1, NPTS, 64);
  // layer 2 (C=64 -> 64, bf16 MFMA)
  sqnorm_kernel<<<64, 256, 0, stream>>>(x1, sq, 64);
  knn_kernel<64><<<gridKNN, 256, 0, stream>>>(x1, sq, idx);
  wprep_bf_kernel<<<16, 256, 0, stream>>>(w2, wn2, wd2, 64, 64);
  edgeconv_mfma<64,64><<<gridEC, 256, 0, stream>>>(x1T, idx, wn2, wd2, g2, b2, x2T);
  transpose2d_kernel<<<dim3(2,64,BATCH), 256, 0, stream>>>(x2T, x2, NPTS, 64);
  // layer 3 (C=64 -> 128, bf16 MFMA)
  sqnorm_kernel<<<64, 256, 0, stream>>>(x2, sq, 64);
  knn_kernel<64><<<gridKNN, 256, 0, stream>>>(x2, sq, idx);
  wprep_bf_kernel<<<32, 256, 0, stream>>>(w3, wn3, wd3, 128, 64);
  edgeconv_mfma<64,128><<<gridEC, 256, 0, stream>>>(x2T, idx, wn3, wd3, g3, b3, x3T);
  transpose2d_kernel<<<dim3(4,64,BATCH), 256, 0, stream>>>(x3T, x3, NPTS, 128);
  // layer 4 (C=128 -> 256, bf16 MFMA)
  sqnorm_kernel<<<64, 256, 0, stream>>>(x3, sq, 128);
  knn_kernel<128><<<gridKNN, 256, 0, stream>>>(x3, sq, idx);
  wprep_bf_kernel<<<128, 256, 0, stream>>>(w4, wn4, wd4, 256, 128);
  edgeconv_mfma<128,256><<<gridEC, 256, 0, stream>>>(x3T, idx, wn4, wd4, g4, b4, x4T);
  // conv5 (split-bf16 MFMA, LDS-staged) + global max over n
  xcat_kernel<<<(BATCH*NPTS*128)/256, 256, 0, stream>>>(x1T, x2T, x3T, x4T, xcat_hi, xcat_lo);
  bfsplit_kernel<<<512, 256, 0, stream>>>(w5, w5hi, w5lo, 1024*512/4);
  zero_kernel<<<32, 256, 0, stream>>>(out5, BATCH*1024);
  conv5_v3<<<dim3(BATCH*NPTS/128, 16), 256, 0, stream>>>(xcat_hi, xcat_lo, w5hi, w5lo, g5, b5, out5);
  // FC head (wave-per-output, coalesced)
  fc_wave_kernel<<<(BATCH*512*64)/256, 256, 0, stream>>>(out5, fw1, g6, b6, h6, 1024, 512);
  fc_wave_kernel<<<(BATCH*256*64)/256, 256, 0, stream>>>(h6, fw2, g7, b7, h7, 512, 256);
  fc_wave_kernel<<<(BATCH*40*64 + 255)/256, 256, 0, stream>>>(h7, fw3, nullptr, nullptr, (float*)d_out, 256, 40);
}

// Round 16
// 867.583 us; speedup vs baseline: 1.6443x; 1.0473x over previous
//
#include <hip/hip_runtime.h>
#include <hip/hip_bf16.h>
#include <math.h>

#define BATCH 8
#define NPTS  2048
#define KNN   20
#define NEG_INF (-3.402823466e38f)

static __device__ __forceinline__ float bn_scale(float g){ return g * rsqrtf(1.0f + 1e-5f); }

// bf16 round-to-nearest-even
static __device__ __forceinline__ unsigned short bf16r(float f){
  unsigned int u = __float_as_uint(f);
  unsigned int r = (u + 0x7fffu + ((u >> 16) & 1u)) >> 16;
  return (unsigned short)r;
}
static __device__ __forceinline__ float bf2f(unsigned short h){
  return __uint_as_float((unsigned int)h << 16);
}
// ordered-int encode/decode for float max via atomicMax(uint)
static __device__ __forceinline__ unsigned int fenc(float f){
  unsigned int u = __float_as_uint(f);
  return (u & 0x80000000u) ? ~u : (u | 0x80000000u);
}
static __device__ __forceinline__ float fdec(unsigned int e){
  return __uint_as_float((e & 0x80000000u) ? (e & 0x7fffffffu) : ~e);
}

using bfrag = __attribute__((ext_vector_type(8))) short;  // 8 bf16 (4 VGPRs)
using f32x4 = __attribute__((ext_vector_type(4))) float;  // 4 fp32 acc

// ---- DPP-based wave argmax (lexicographic value desc, idx asc); winner in lane 63 ----
template<int CTRL>
static __device__ __forceinline__ void dpp_amax(float &bv, int &bi){
  int ov_i = __builtin_amdgcn_update_dpp(__float_as_int(NEG_INF), __float_as_int(bv),
                                         CTRL, 0xf, 0xf, false);
  int oi   = __builtin_amdgcn_update_dpp(0x7fffffff, bi, CTRL, 0xf, 0xf, false);
  float ov = __int_as_float(ov_i);
  if (ov > bv || (ov == bv && oi < bi)){ bv = ov; bi = oi; }
}
static __device__ __forceinline__ int wave_argmax_idx(float bv, int bi){
  dpp_amax<0x111>(bv, bi);   // row_shr:1
  dpp_amax<0x112>(bv, bi);   // row_shr:2
  dpp_amax<0x114>(bv, bi);   // row_shr:4
  dpp_amax<0x118>(bv, bi);   // row_shr:8
  dpp_amax<0x142>(bv, bi);   // row_bcast:15
  dpp_amax<0x143>(bv, bi);   // row_bcast:31
  return __builtin_amdgcn_readlane(bi, 63);
}
// ---- DPP wave sum (identity 0.0 injected); total broadcast from lane 63 ----
template<int CTRL>
static __device__ __forceinline__ float dpp_fadd(float v){
  int ov = __builtin_amdgcn_update_dpp(0, __float_as_int(v), CTRL, 0xf, 0xf, false);
  return v + __int_as_float(ov);
}
static __device__ __forceinline__ float wave_sum(float v){
  v = dpp_fadd<0x111>(v); v = dpp_fadd<0x112>(v);
  v = dpp_fadd<0x114>(v); v = dpp_fadd<0x118>(v);
  v = dpp_fadd<0x142>(v); v = dpp_fadd<0x143>(v);
  return __int_as_float(__builtin_amdgcn_readlane(__float_as_int(v), 63));
}

// ---------------- squared norms per point (reads channel-major [C][N]) ----------------
__global__ void sqnorm_kernel(const float* __restrict__ X, float* __restrict__ sq, int C){
  int i = blockIdx.x*blockDim.x + threadIdx.x;
  if (i >= BATCH*NPTS) return;
  int b = i / NPTS, n = i - b*NPTS;
  const float* xb = X + (size_t)b*C*NPTS + n;
  float s = 0.f;
  for (int c=0;c<C;++c){ float v = xb[(size_t)c*NPTS]; s += v*v; }
  sq[i] = s;
}

// ---------------- kNN v8 (round-14 measured best: VGPR 56, 4 blocks/CU) ----------------
// r15's point-major ctrs regressed (VGPR 68, occ 29%): reverted to channel-major [C][8].
template<int C>
__global__ __launch_bounds__(256, 2) void knn_kernel(const float* __restrict__ X,
                                                     const float* __restrict__ sq,
                                                     int* __restrict__ idxout){
  const int b = blockIdx.y;
  const int n0 = blockIdx.x * 8;
  const int t = threadIdx.x;
  __shared__ __align__(16) float dist[4][NPTS];
  __shared__ float ctrs[C][8];
  __shared__ float sqn[8];
  const float* xb = X + (size_t)b*C*NPTS;
  for (int i=t; i<C*8; i+=256){
    int c = i >> 3, p = i & 7;
    ctrs[c][p] = xb[(size_t)c*NPTS + n0 + p];
  }
  if (t < 8) sqn[t] = sq[b*NPTS + n0 + t];
  __syncthreads();

  const int m0 = t * 8;
  float acc[8][8];
  #pragma unroll
  for (int i=0;i<8;++i)
    #pragma unroll
    for (int j=0;j<8;++j) acc[i][j] = 0.f;
  for (int c=0;c<C;++c){
    const float4 xa = *(const float4*)&xb[(size_t)c*NPTS + m0];
    const float4 xc = *(const float4*)&xb[(size_t)c*NPTS + m0 + 4];
    const float xm[8] = {xa.x,xa.y,xa.z,xa.w,xc.x,xc.y,xc.z,xc.w};
    #pragma unroll
    for (int i=0;i<8;++i){
      const float cv = ctrs[c][i];
      #pragma unroll
      for (int j=0;j<8;++j) acc[i][j] += cv*xm[j];
    }
  }
  {
    const float4 sa = *(const float4*)&sq[b*NPTS + m0];
    const float4 sb = *(const float4*)&sq[b*NPTS + m0 + 4];
    const float sm[8] = {sa.x,sa.y,sa.z,sa.w,sb.x,sb.y,sb.z,sb.w};
    #pragma unroll
    for (int i=0;i<8;++i){
      const float si = sqn[i];
      #pragma unroll
      for (int j=0;j<8;++j) acc[i][j] = 2.f*acc[i][j] - si - sm[j];
    }
  }

  const int wv = t >> 6, lane = t & 63;
  #pragma unroll
  for (int rep=0; rep<2; ++rep){
    #pragma unroll
    for (int i=0;i<4;++i){
      *(float4*)&dist[i][m0]   = make_float4(acc[rep*4+i][0],acc[rep*4+i][1],acc[rep*4+i][2],acc[rep*4+i][3]);
      *(float4*)&dist[i][m0+4] = make_float4(acc[rep*4+i][4],acc[rep*4+i][5],acc[rep*4+i][6],acc[rep*4+i][7]);
    }
    __syncthreads();
    // initial scan: per-lane sorted top-4 (value desc, idx asc) in registers
    float s0=NEG_INF,s1=NEG_INF,s2=NEG_INF,s3=NEG_INF;
    int   i0=0x7fffffff,i1=0x7fffffff,i2=0x7fffffff,i3=0x7fffffff;
    #pragma unroll
    for (int j=0;j<32;++j){
      const float v = dist[wv][lane + 64*j];
      const int   m = lane + 64*j;
      const bool b0 = v > s0, b1 = v > s1, b2 = v > s2, b3 = v > s3;  // strict: stable ties
      const float n0 = b0 ? v : s0;            const int q0 = b0 ? m : i0;
      const float n1 = b0 ? s0 : (b1 ? v : s1); const int q1 = b0 ? i0 : (b1 ? m : i1);
      const float n2 = b1 ? s1 : (b2 ? v : s2); const int q2 = b1 ? i1 : (b2 ? m : i2);
      const float n3 = b2 ? s2 : (b3 ? v : s3); const int q3 = b2 ? i2 : (b3 ? m : i3);
      s0=n0;s1=n1;s2=n2;s3=n3; i0=q0;i1=q1;i2=q2;i3=q3;
    }
    int rem = 4;
    int* row = idxout + ((size_t)b*NPTS + n0 + rep*4 + wv)*KNN;
    for (int sel=0; sel<KNN; ++sel){
      const int widx = wave_argmax_idx(s0, i0);   // DPP reduction over queue heads
      if (lane == 0) row[sel] = widx;
      if ((widx & 63) == lane){
        const float lastv = s0; const int lasti = i0;
        s0=s1;i0=i1; s1=s2;i1=i2; s2=s3;i2=i3;
        rem--;
        if (rem == 0){
          float nv = NEG_INF; int ni = 0x7fffffff;
          #pragma unroll
          for (int j=0;j<32;++j){
            const float vv = dist[wv][lane + 64*j];
            const int   mi = lane + 64*j;
            const bool ok = (vv < lastv) || (vv == lastv && mi > lasti);
            if (ok && vv > nv){ nv = vv; ni = mi; }
          }
          s0 = nv; i0 = ni; rem = 1;
        }
      }
    }
    __syncthreads();
  }
}

// ---------------- fp32 weight prep (layer 1 only): wnT[c][o], wdT[c][o] ----------------
__global__ void wprep_kernel(const float* __restrict__ w, float* __restrict__ wnT,
                             float* __restrict__ wdT, int O, int C){
  int i = blockIdx.x*blockDim.x + threadIdx.x;
  if (i >= O*C) return;
  int c = i / O, o = i - c*O;
  float a = w[(size_t)o*2*C + c];
  wnT[(size_t)c*O + o] = a;
  wdT[(size_t)c*O + o] = w[(size_t)o*2*C + C + c] - a;
}

// ---------------- bf16 weight prep (layers 2-4): wn[o][c], wd[o][c] (k contiguous) -----
__global__ void wprep_bf_kernel(const float* __restrict__ w, unsigned short* __restrict__ wn,
                                unsigned short* __restrict__ wd, int O, int C){
  int i = blockIdx.x*blockDim.x + threadIdx.x;
  if (i >= O*C) return;
  int o = i / C, c = i - o*C;
  float a = w[(size_t)o*2*C + c];
  float d = w[(size_t)o*2*C + C + c] - a;
  wn[(size_t)o*C + c] = bf16r(a);
  wd[(size_t)o*C + c] = bf16r(d);
}

// ---------------- split-bf16 weight convert (conv5): hi = bf16(w), lo = bf16(w-hi) ------
__global__ void bfsplit_kernel(const float* __restrict__ in, unsigned short* __restrict__ hi,
                               unsigned short* __restrict__ lo, int nq){
  int i = blockIdx.x*blockDim.x + threadIdx.x;
  if (i >= nq) return;
  float4 v = *(const float4*)&in[(size_t)i*4];
  unsigned short h0=bf16r(v.x), h1=bf16r(v.y), h2=bf16r(v.z), h3=bf16r(v.w);
  unsigned short l0=bf16r(v.x-bf2f(h0)), l1=bf16r(v.y-bf2f(h1)),
                 l2=bf16r(v.z-bf2f(h2)), l3=bf16r(v.w-bf2f(h3));
  *(uint2*)&hi[(size_t)i*4] = make_uint2((unsigned)h0|((unsigned)h1<<16), (unsigned)h2|((unsigned)h3<<16));
  *(uint2*)&lo[(size_t)i*4] = make_uint2((unsigned)l0|((unsigned)l1<<16), (unsigned)l2|((unsigned)l3<<16));
}

// ---------------- xcat: concat x1T..x4T -> split-bf16 [b][n][512] ----------------
__global__ __launch_bounds__(256) void xcat_kernel(const float* __restrict__ x1T,
    const float* __restrict__ x2T, const float* __restrict__ x3T, const float* __restrict__ x4T,
    unsigned short* __restrict__ xhi, unsigned short* __restrict__ xlo){
  int i = blockIdx.x*blockDim.x + threadIdx.x;   // quad index over B*N*128
  if (i >= BATCH*NPTS*128) return;
  int q = i & 127, bn_ = i >> 7;
  int k = q*4;
  const float* src; int kk;
  if (k < 64)      { src = x1T + (size_t)bn_*64;  kk = k; }
  else if (k <128) { src = x2T + (size_t)bn_*64;  kk = k-64; }
  else if (k <256) { src = x3T + (size_t)bn_*128; kk = k-128; }
  else             { src = x4T + (size_t)bn_*256; kk = k-256; }
  float4 v = *(const float4*)&src[kk];
  unsigned short h0=bf16r(v.x), h1=bf16r(v.y), h2=bf16r(v.z), h3=bf16r(v.w);
  unsigned short l0=bf16r(v.x-bf2f(h0)), l1=bf16r(v.y-bf2f(h1)),
                 l2=bf16r(v.z-bf2f(h2)), l3=bf16r(v.w-bf2f(h3));
  *(uint2*)&xhi[(size_t)i*4] = make_uint2((unsigned)h0|((unsigned)h1<<16), (unsigned)h2|((unsigned)h3<<16));
  *(uint2*)&xlo[(size_t)i*4] = make_uint2((unsigned)l0|((unsigned)l1<<16), (unsigned)l2|((unsigned)l3<<16));
}

// ---------------- generic tiled transpose: in[R][Cc] -> out[Cc][R], per z-slice ----------------
__global__ __launch_bounds__(256) void transpose2d_kernel(const float* __restrict__ in,
    float* __restrict__ out, int R, int Cc){
  __shared__ float tile[32][33];
  const size_t boff = (size_t)blockIdx.z * (size_t)R * Cc;
  const int c0 = blockIdx.x*32, r0 = blockIdx.y*32;
  const int tx = threadIdx.x & 31, ty = threadIdx.x >> 5;
  #pragma unroll
  for (int j=0;j<4;++j){
    int r = ty*4 + j;
    tile[r][tx] = in[boff + (size_t)(r0+r)*Cc + c0 + tx];
  }
  __syncthreads();
  #pragma unroll
  for (int j=0;j<4;++j){
    int r = ty*4 + j;
    out[boff + (size_t)(c0+r)*R + r0 + tx] = tile[tx][r];
  }
}

// ---------------- x -> xT0 [N][3] ----------------
__global__ void xt0_kernel(const float* __restrict__ x, float* __restrict__ xT0){
  int i = blockIdx.x*blockDim.x + threadIdx.x;
  if (i >= BATCH*NPTS) return;
  int b = i / NPTS, n = i - b*NPTS;
  const float* xb = x + (size_t)b*3*NPTS;
  float v0 = xb[n], v1 = xb[NPTS + n], v2 = xb[2*NPTS + n];
  float* o = xT0 + ((size_t)b*NPTS + n)*3;
  o[0]=v0; o[1]=v1; o[2]=v2;
}

// ---------------- edge conv layer 1 (C=3, fp32): 4 points per block ----------------
__global__ __launch_bounds__(256) void edgeconv1_kernel(const float* __restrict__ xT0,
    const int* __restrict__ idx, const float* __restrict__ wnT, const float* __restrict__ wdT,
    const float* __restrict__ g, const float* __restrict__ bb, float* __restrict__ outT){
  const int b = blockIdx.y, n0 = blockIdx.x*4, t = threadIdx.x;
  __shared__ float nbr[4][KNN][3];
  __shared__ float ctr[4][3];
  __shared__ int   idxs[4][KNN];
  const float* xb = xT0 + (size_t)b*NPTS*3;
  if (t < 4*KNN) idxs[t/KNN][t%KNN] = idx[((size_t)b*NPTS + n0 + t/KNN)*KNN + (t%KNN)];
  if (t >= 128 && t < 140){ int i = t-128; ctr[i/3][i%3] = xb[(size_t)(n0 + i/3)*3 + i%3]; }
  __syncthreads();
  for (int i=t; i<4*KNN*3; i+=256){
    int p = i/(KNN*3), r = i - p*(KNN*3), k = r/3, c = r - k*3;
    nbr[p][k][c] = xb[(size_t)idxs[p][k]*3 + c];
  }
  __syncthreads();
  const int p = t >> 6, o = t & 63;
  const float wn0 = wnT[o], wn1 = wnT[64+o], wn2 = wnT[128+o];
  const float cst = ctr[p][0]*wdT[o] + ctr[p][1]*wdT[64+o] + ctr[p][2]*wdT[128+o];
  float best = NEG_INF;
  #pragma unroll
  for (int k=0;k<KNN;++k){
    float a = nbr[p][k][0]*wn0 + nbr[p][k][1]*wn1 + nbr[p][k][2]*wn2;
    best = fmaxf(best, a);
  }
  float vv = (best + cst) * bn_scale(g[o]) + bb[o];
  outT[((size_t)b*NPTS + n0 + p)*64 + o] = fmaxf(vv, 0.f);
}

// ---------------- edge conv MFMA (bf16): block = 4 points ----------------
template<int C, int O>
__global__ __launch_bounds__(256) void edgeconv_mfma(const float* __restrict__ xT,
    const int* __restrict__ idx,
    const unsigned short* __restrict__ wn_bf, const unsigned short* __restrict__ wd_bf,
    const float* __restrict__ g, const float* __restrict__ bb, float* __restrict__ outT){
  constexpr int ROWS = 112;        // 7 m-tiles of 16
  constexpr int CP   = C + 8;      // padded row (bf16): 16B-aligned stride, conflict-free b128
  constexpr int KS   = C / 32;     // k-steps per tile
  constexpr int NTW  = O / 64;     // n-tiles per wave (O/16 tiles over 4 waves)
  __shared__ __align__(16) unsigned short A[ROWS][CP];
  __shared__ unsigned int res[4][O];
  __shared__ float cst_s[4][O];
  __shared__ int idxs[4][KNN];
  const int b = blockIdx.y, n0 = blockIdx.x*4, t = threadIdx.x;
  const float* xTb = xT + (size_t)b*NPTS*C;
  if (t < 4*KNN) idxs[t/KNN][t%KNN] = idx[((size_t)b*NPTS + n0 + t/KNN)*KNN + (t%KNN)];
  for (int i=t; i<4*O; i+=256) res[i/O][i & (O-1)] = 0u;   // 0 < fenc(any finite)
  __syncthreads();
  for (int i=t; i<ROWS*(C/4); i+=256){
    int r = i/(C/4), c4 = i - r*(C/4);
    float4 v = make_float4(0.f,0.f,0.f,0.f);
    if (r < 96){
      int p = r/24, kk = r - p*24;
      int src = idxs[p][kk < KNN ? kk : 0];        // pad rows duplicate nbr 0 (max-neutral)
      v = *(const float4*)&xTb[(size_t)src*C + c4*4];
    } else if (r < 100){
      v = *(const float4*)&xTb[(size_t)(n0 + (r-96))*C + c4*4];
    }
    unsigned int lo = (unsigned int)bf16r(v.x) | ((unsigned int)bf16r(v.y) << 16);
    unsigned int hi = (unsigned int)bf16r(v.z) | ((unsigned int)bf16r(v.w) << 16);
    *(uint2*)&A[r][c4*4] = make_uint2(lo, hi);
  }
  __syncthreads();

  const int wv = t >> 6, l = t & 63;
  const int lane15 = l & 15, quad = l >> 4;
  bfrag Bn[NTW][KS];
  #pragma unroll
  for (int nt=0; nt<NTW; ++nt){
    const int col = (wv*NTW + nt)*16 + lane15;
    #pragma unroll
    for (int s=0; s<KS; ++s)
      Bn[nt][s] = *(const bfrag*)&wn_bf[(size_t)col*C + s*32 + quad*8];
  }
  #pragma unroll
  for (int mt=0; mt<7; ++mt){
    bfrag Af[KS];
    #pragma unroll
    for (int s=0; s<KS; ++s)
      Af[s] = *(const bfrag*)&A[mt*16 + lane15][s*32 + quad*8];
    if (mt < 6){
      const int rbase = mt*16 + quad*4;
      const int p = rbase / 24;
      #pragma unroll
      for (int nt=0; nt<NTW; ++nt){
        f32x4 acc = {0.f,0.f,0.f,0.f};
        #pragma unroll
        for (int s=0; s<KS; ++s)
          acc = __builtin_amdgcn_mfma_f32_16x16x32_bf16(Af[s], Bn[nt][s], acc, 0, 0, 0);
        float m = fmaxf(fmaxf(acc[0], acc[1]), fmaxf(acc[2], acc[3]));
        const int col = (wv*NTW + nt)*16 + lane15;
        atomicMax(&res[p][col], fenc(m));
      }
    } else {
      #pragma unroll
      for (int nt=0; nt<NTW; ++nt){
        const int col = (wv*NTW + nt)*16 + lane15;
        f32x4 acc = {0.f,0.f,0.f,0.f};
        #pragma unroll
        for (int s=0; s<KS; ++s){
          bfrag Bd = *(const bfrag*)&wd_bf[(size_t)col*C + s*32 + quad*8];
          acc = __builtin_amdgcn_mfma_f32_16x16x32_bf16(Af[s], Bd, acc, 0, 0, 0);
        }
        if (quad == 0){
          #pragma unroll
          for (int r=0;r<4;++r) cst_s[r][col] = acc[r];
        }
      }
    }
  }
  __syncthreads();
  for (int i=t; i<4*O; i+=256){
    int p = i/O, o = i - p*O;
    float mx = fdec(res[p][o]);
    float vv = (mx + cst_s[p][o]) * bn_scale(g[o]) + bb[o];
    outT[((size_t)b*NPTS + n0 + p)*O + o] = fmaxf(vv, 0.f);
  }
}

// ---------------- conv5 v3: LDS-staged split-bf16 MFMA GEMM + max over n ----------------
__global__ __launch_bounds__(256) void conv5_v3(const unsigned short* __restrict__ xhi,
    const unsigned short* __restrict__ xlo, const unsigned short* __restrict__ whi,
    const unsigned short* __restrict__ wlo, const float* __restrict__ g,
    const float* __restrict__ bb, float* __restrict__ out5){
  __shared__ __align__(16) unsigned short Ah_s[128*32];
  __shared__ __align__(16) unsigned short Al_s[128*32];
  __shared__ __align__(16) unsigned short Bh_s[64*32];
  __shared__ __align__(16) unsigned short Bl_s[64*32];
  const int t = threadIdx.x;
  const int row0 = blockIdx.x*128, o0 = blockIdx.y*64;
  const int b = row0 / NPTS;   // 128 | NPTS, so a block never straddles batches
  const int wv = t >> 6, l = t & 63, lane15 = l & 15, quad = l >> 4;
  const int ar = t >> 2, ac = (t & 3)*8;
  const unsigned short* gAh0 = xhi + (size_t)(row0 + ar)*512 + ac;
  const unsigned short* gAh1 = xhi + (size_t)(row0 + 64 + ar)*512 + ac;
  const unsigned short* gAl0 = xlo + (size_t)(row0 + ar)*512 + ac;
  const unsigned short* gAl1 = xlo + (size_t)(row0 + 64 + ar)*512 + ac;
  const unsigned short* gBh  = whi + (size_t)(o0 + ar)*512 + ac;
  const unsigned short* gBl  = wlo + (size_t)(o0 + ar)*512 + ac;

  uint4 pf0 = *(const uint4*)gAh0;
  uint4 pf1 = *(const uint4*)gAh1;
  uint4 pf2 = *(const uint4*)gAl0;
  uint4 pf3 = *(const uint4*)gAl1;
  uint4 pf4 = *(const uint4*)gBh;
  uint4 pf5 = *(const uint4*)gBl;

  f32x4 acc[2][4];
  #pragma unroll
  for (int mt=0;mt<2;++mt)
    #pragma unroll
    for (int nt=0;nt<4;++nt) acc[mt][nt] = (f32x4){0.f,0.f,0.f,0.f};

  for (int ks=0; ks<16; ++ks){
    *(uint4*)&Ah_s[t*8]        = pf0;
    *(uint4*)&Ah_s[2048 + t*8] = pf1;
    *(uint4*)&Al_s[t*8]        = pf2;
    *(uint4*)&Al_s[2048 + t*8] = pf3;
    *(uint4*)&Bh_s[t*8]        = pf4;
    *(uint4*)&Bl_s[t*8]        = pf5;
    __syncthreads();
    if (ks < 15){
      const int koff = (ks+1)*32;
      pf0 = *(const uint4*)(gAh0 + koff);
      pf1 = *(const uint4*)(gAh1 + koff);
      pf2 = *(const uint4*)(gAl0 + koff);
      pf3 = *(const uint4*)(gAl1 + koff);
      pf4 = *(const uint4*)(gBh  + koff);
      pf5 = *(const uint4*)(gBl  + koff);
    }
    bfrag Afh[2], Afl[2], Bfh[4], Bfl[4];
    #pragma unroll
    for (int mt=0;mt<2;++mt){
      const int m = wv*32 + mt*16 + lane15;
      Afh[mt] = *(const bfrag*)&Ah_s[m*32 + quad*8];
      Afl[mt] = *(const bfrag*)&Al_s[m*32 + quad*8];
    }
    #pragma unroll
    for (int nt=0;nt<4;++nt){
      const int oc = nt*16 + lane15;
      Bfh[nt] = *(const bfrag*)&Bh_s[oc*32 + quad*8];
      Bfl[nt] = *(const bfrag*)&Bl_s[oc*32 + quad*8];
    }
    #pragma unroll
    for (int mt=0;mt<2;++mt)
      #pragma unroll
      for (int nt=0;nt<4;++nt){
        acc[mt][nt] = __builtin_amdgcn_mfma_f32_16x16x32_bf16(Afh[mt], Bfh[nt], acc[mt][nt], 0, 0, 0);
        acc[mt][nt] = __builtin_amdgcn_mfma_f32_16x16x32_bf16(Afl[mt], Bfh[nt], acc[mt][nt], 0, 0, 0);
        acc[mt][nt] = __builtin_amdgcn_mfma_f32_16x16x32_bf16(Afh[mt], Bfl[nt], acc[mt][nt], 0, 0, 0);
      }
    __syncthreads();
  }
  #pragma unroll
  for (int nt=0;nt<4;++nt){
    float m = NEG_INF;
    #pragma unroll
    for (int mt=0;mt<2;++mt)
      #pragma unroll
      for (int r=0;r<4;++r) m = fmaxf(m, acc[mt][nt][r]);
    m = fmaxf(m, __shfl_xor(m, 16, 64));
    m = fmaxf(m, __shfl_xor(m, 32, 64));
    if (quad == 0){
      const int o = o0 + nt*16 + lane15;
      float vv = fmaxf(m * bn_scale(g[o]) + bb[o], 0.f);
      atomicMax((int*)&out5[(size_t)b*1024 + o], __float_as_int(vv));
    }
  }
}

__global__ void zero_kernel(float* __restrict__ p, int nfloats){
  int i = blockIdx.x*blockDim.x + threadIdx.x;
  if (i < nfloats) p[i] = 0.f;
}

// ---------------- FC layers: one wave per (b,o), coalesced lane-strided reads ----------
__global__ __launch_bounds__(256) void fc_wave_kernel(const float* __restrict__ in,
    const float* __restrict__ w, const float* __restrict__ g, const float* __restrict__ bb,
    float* __restrict__ out, int IN, int O){
  const int wid = (blockIdx.x*256 + threadIdx.x) >> 6;
  const int lane = threadIdx.x & 63;
  if (wid >= BATCH*O) return;
  const int b = wid / O, o = wid - b*O;
  const float* inb = in + (size_t)b*IN;
  const float* wo  = w + (size_t)o*IN;
  float s = 0.f;
  for (int c = lane; c < IN; c += 64) s += inb[c]*wo[c];   // coalesced across the wave
  s = wave_sum(s);
  if (lane == 0){
    if (g){ s = s*bn_scale(g[o]) + bb[o]; s = fmaxf(s, 0.f); }
    out[wid] = s;
  }
}

extern "C" void kernel_launch(void* const* d_in, const int* in_sizes, int n_in,
                              void* d_out, int out_size, void* d_ws, size_t ws_size,
                              hipStream_t stream){
  const float* x   = (const float*)d_in[0];
  const float* w1  = (const float*)d_in[1];
  const float* w2  = (const float*)d_in[2];
  const float* w3  = (const float*)d_in[3];
  const float* w4  = (const float*)d_in[4];
  const float* w5  = (const float*)d_in[5];
  const float* fw1 = (const float*)d_in[6];
  const float* fw2 = (const float*)d_in[7];
  const float* fw3 = (const float*)d_in[8];
  const float* g1 = (const float*)d_in[9];  const float* b1 = (const float*)d_in[10];
  const float* g2 = (const float*)d_in[11]; const float* b2 = (const float*)d_in[12];
  const float* g3 = (const float*)d_in[13]; const float* b3 = (const float*)d_in[14];
  const float* g4 = (const float*)d_in[15]; const float* b4 = (const float*)d_in[16];
  const float* g5 = (const float*)d_in[17]; const float* b5 = (const float*)d_in[18];
  const float* g6 = (const float*)d_in[19]; const float* b6 = (const float*)d_in[20];
  const float* g7 = (const float*)d_in[21]; const float* b7 = (const float*)d_in[22];

  float* ws = (float*)d_ws;
  size_t off = 0;
  // x1..x3 channel-major; this 4.19M-float region is later reused as xcat_lo
  float* x1  = ws + off; off += (size_t)BATCH*64*NPTS;
  float* x2  = ws + off; off += (size_t)BATCH*64*NPTS;
  float* x3  = ws + off; off += (size_t)BATCH*128*NPTS;
  unsigned short* xcat_lo = (unsigned short*)x1;           // alias: x1..x3 dead before xcat runs
  unsigned short* xcat_hi = (unsigned short*)(ws + off); off += (size_t)BATCH*256*NPTS; // = B*N*512 bf16
  float* x1T = ws + off; off += (size_t)BATCH*64*NPTS;
  float* x2T = ws + off; off += (size_t)BATCH*64*NPTS;
  float* x3T = ws + off; off += (size_t)BATCH*128*NPTS;
  float* x4T = ws + off; off += (size_t)BATCH*256*NPTS;
  float* xT0 = ws + off; off += (size_t)BATCH*3*NPTS;
  float* sq  = ws + off; off += (size_t)BATCH*NPTS;
  int*  idx  = (int*)(ws + off); off += (size_t)BATCH*NPTS*KNN;
  float* out5 = ws + off; off += BATCH*1024;
  float* h6 = ws + off;   off += BATCH*512;
  float* h7 = ws + off;   off += BATCH*256;
  float* wnT1 = ws + off; off += 3*64;
  float* wdT1 = ws + off; off += 3*64;
  unsigned short* wn2 = (unsigned short*)(ws + off); off += 64*64/2;
  unsigned short* wd2 = (unsigned short*)(ws + off); off += 64*64/2;
  unsigned short* wn3 = (unsigned short*)(ws + off); off += 128*64/2;
  unsigned short* wd3 = (unsigned short*)(ws + off); off += 128*64/2;
  unsigned short* wn4 = (unsigned short*)(ws + off); off += 256*128/2;
  unsigned short* wd4 = (unsigned short*)(ws + off); off += 256*128/2;
  unsigned short* w5hi = (unsigned short*)(ws + off); off += 1024*512/2;
  unsigned short* w5lo = (unsigned short*)(ws + off); off += 1024*512/2;

  dim3 gridKNN(NPTS/8, BATCH);
  dim3 gridEC(NPTS/4, BATCH);

  // layer 1 (C=3 -> 64, fp32)
  xt0_kernel<<<64, 256, 0, stream>>>(x, xT0);
  sqnorm_kernel<<<64, 256, 0, stream>>>(x, sq, 3);
  knn_kernel<3><<<gridKNN, 256, 0, stream>>>(x, sq, idx);
  wprep_kernel<<<1, 256, 0, stream>>>(w1, wnT1, wdT1, 64, 3);
  edgeconv1_kernel<<<gridEC, 256, 0, stream>>>(xT0, idx, wnT1, wdT1, g1, b1, x1T);
  transpose2d_kernel<<<dim3(2,64,BATCH), 256, 0, stream>>>(x1T, x1, NPTS, 64);
  // layer 2 (C=64 -> 64, bf16 MFMA)
  sqnorm_kernel<<<64, 256, 0, stream>>>(x1, sq, 64);
  knn_kernel<64><<<gridKNN, 256, 0, stream>>>(x1, sq, idx);
  wprep_bf_kernel<<<16, 256, 0, stream>>>(w2, wn2, wd2, 64, 64);
  edgeconv_mfma<64,64><<<gridEC, 256, 0, stream>>>(x1T, idx, wn2, wd2, g2, b2, x2T);
  transpose2d_kernel<<<dim3(2,64,BATCH), 256, 0, stream>>>(x2T, x2, NPTS, 64);
  // layer 3 (C=64 -> 128, bf16 MFMA)
  sqnorm_kernel<<<64, 256, 0, stream>>>(x2, sq, 64);
  knn_kernel<64><<<gridKNN, 256, 0, stream>>>(x2, sq, idx);
  wprep_bf_kernel<<<32, 256, 0, stream>>>(w3, wn3, wd3, 128, 64);
  edgeconv_mfma<64,128><<<gridEC, 256, 0, stream>>>(x2T, idx, wn3, wd3, g3, b3, x3T);
  transpose2d_kernel<<<dim3(4,64,BATCH), 256, 0, stream>>>(x3T, x3, NPTS, 128);
  // layer 4 (C=128 -> 256, bf16 MFMA)
  sqnorm_kernel<<<64, 256, 0, stream>>>(x3, sq, 128);
  knn_kernel<128><<<gridKNN, 256, 0, stream>>>(x3, sq, idx);
  wprep_bf_kernel<<<128, 256, 0, stream>>>(w4, wn4, wd4, 256, 128);
  edgeconv_mfma<128,256><<<gridEC, 256, 0, stream>>>(x3T, idx, wn4, wd4, g4, b4, x4T);
  // conv5 (split-bf16 MFMA, LDS-staged) + global max over n
  xcat_kernel<<<(BATCH*NPTS*128)/256, 256, 0, stream>>>(x1T, x2T, x3T, x4T, xcat_hi, xcat_lo);
  bfsplit_kernel<<<512, 256, 0, stream>>>(w5, w5hi, w5lo, 1024*512/4);
  zero_kernel<<<32, 256, 0, stream>>>(out5, BATCH*1024);
  conv5_v3<<<dim3(BATCH*NPTS/128, 16), 256, 0, stream>>>(xcat_hi, xcat_lo, w5hi, w5lo, g5, b5, out5);
  // FC head (wave-per-output, coalesced)
  fc_wave_kernel<<<(BATCH*512*64)/256, 256, 0, stream>>>(out5, fw1, g6, b6, h6, 1024, 512);
  fc_wave_kernel<<<(BATCH*256*64)/256, 256, 0, stream>>>(h6, fw2, g7, b7, h7, 512, 256);
  fc_wave_kernel<<<(BATCH*40*64 + 255)/256, 256, 0, stream>>>(h7, fw3, nullptr, nullptr, (float*)d_out, 256, 40);
}

// Round 17
// 845.932 us; speedup vs baseline: 1.6864x; 1.0256x over previous
//
#include <hip/hip_runtime.h>
#include <hip/hip_bf16.h>
#include <math.h>

#define BATCH 8
#define NPTS  2048
#define KNN   20
#define NEG_INF (-3.402823466e38f)

static __device__ __forceinline__ float bn_scale(float g){ return g * rsqrtf(1.0f + 1e-5f); }

// bf16 round-to-nearest-even
static __device__ __forceinline__ unsigned short bf16r(float f){
  unsigned int u = __float_as_uint(f);
  unsigned int r = (u + 0x7fffu + ((u >> 16) & 1u)) >> 16;
  return (unsigned short)r;
}
static __device__ __forceinline__ float bf2f(unsigned short h){
  return __uint_as_float((unsigned int)h << 16);
}
// ordered-int encode/decode for float max via atomicMax(uint)
static __device__ __forceinline__ unsigned int fenc(float f){
  unsigned int u = __float_as_uint(f);
  return (u & 0x80000000u) ? ~u : (u | 0x80000000u);
}
static __device__ __forceinline__ float fdec(unsigned int e){
  return __uint_as_float((e & 0x80000000u) ? (e & 0x7fffffffu) : ~e);
}

using bfrag = __attribute__((ext_vector_type(8))) short;  // 8 bf16 (4 VGPRs)
using f32x4 = __attribute__((ext_vector_type(4))) float;  // 4 fp32 acc
using f32x2 = __attribute__((ext_vector_type(2))) float;  // packed pair -> v_pk_fma_f32

// ---- DPP-based wave argmax (lexicographic value desc, idx asc); winner in lane 63 ----
template<int CTRL>
static __device__ __forceinline__ void dpp_amax(float &bv, int &bi){
  int ov_i = __builtin_amdgcn_update_dpp(__float_as_int(NEG_INF), __float_as_int(bv),
                                         CTRL, 0xf, 0xf, false);
  int oi   = __builtin_amdgcn_update_dpp(0x7fffffff, bi, CTRL, 0xf, 0xf, false);
  float ov = __int_as_float(ov_i);
  if (ov > bv || (ov == bv && oi < bi)){ bv = ov; bi = oi; }
}
static __device__ __forceinline__ int wave_argmax_idx(float bv, int bi){
  dpp_amax<0x111>(bv, bi);   // row_shr:1
  dpp_amax<0x112>(bv, bi);   // row_shr:2
  dpp_amax<0x114>(bv, bi);   // row_shr:4
  dpp_amax<0x118>(bv, bi);   // row_shr:8
  dpp_amax<0x142>(bv, bi);   // row_bcast:15
  dpp_amax<0x143>(bv, bi);   // row_bcast:31
  return __builtin_amdgcn_readlane(bi, 63);
}
// ---- DPP wave sum (identity 0.0 injected); total broadcast from lane 63 ----
template<int CTRL>
static __device__ __forceinline__ float dpp_fadd(float v){
  int ov = __builtin_amdgcn_update_dpp(0, __float_as_int(v), CTRL, 0xf, 0xf, false);
  return v + __int_as_float(ov);
}
static __device__ __forceinline__ float wave_sum(float v){
  v = dpp_fadd<0x111>(v); v = dpp_fadd<0x112>(v);
  v = dpp_fadd<0x114>(v); v = dpp_fadd<0x118>(v);
  v = dpp_fadd<0x142>(v); v = dpp_fadd<0x143>(v);
  return __int_as_float(__builtin_amdgcn_readlane(__float_as_int(v), 63));
}

// ---------------- squared norms per point (reads channel-major [C][N]) ----------------
__global__ void sqnorm_kernel(const float* __restrict__ X, float* __restrict__ sq, int C){
  int i = blockIdx.x*blockDim.x + threadIdx.x;
  if (i >= BATCH*NPTS) return;
  int b = i / NPTS, n = i - b*NPTS;
  const float* xb = X + (size_t)b*C*NPTS + n;
  float s = 0.f;
  for (int c=0;c<C;++c){ float v = xb[(size_t)c*NPTS]; s += v*v; }
  sq[i] = s;
}

// ---------------- kNN v10: v8 + packed-f32 distance math (v_pk_fma_f32) ----------------
// acc as f32x2[8][4]: one packed FMA covers 2 MACs -> half the VALU issue slots in the
// distance phase. Per-lane IEEE arithmetic identical to scalar (same order) -> bit-exact.
template<int C>
__global__ __launch_bounds__(256, 2) void knn_kernel(const float* __restrict__ X,
                                                     const float* __restrict__ sq,
                                                     int* __restrict__ idxout){
  const int b = blockIdx.y;
  const int n0 = blockIdx.x * 8;
  const int t = threadIdx.x;
  __shared__ __align__(16) float dist[4][NPTS];
  __shared__ float ctrs[C][8];
  __shared__ float sqn[8];
  const float* xb = X + (size_t)b*C*NPTS;
  for (int i=t; i<C*8; i+=256){
    int c = i >> 3, p = i & 7;
    ctrs[c][p] = xb[(size_t)c*NPTS + n0 + p];
  }
  if (t < 8) sqn[t] = sq[b*NPTS + n0 + t];
  __syncthreads();

  const int m0 = t * 8;
  f32x2 acc2[8][4];
  #pragma unroll
  for (int i=0;i<8;++i)
    #pragma unroll
    for (int j=0;j<4;++j) acc2[i][j] = (f32x2){0.f, 0.f};
  for (int c=0;c<C;++c){
    const float4 xa = *(const float4*)&xb[(size_t)c*NPTS + m0];
    const float4 xc = *(const float4*)&xb[(size_t)c*NPTS + m0 + 4];
    const f32x2 xm2[4] = {(f32x2){xa.x,xa.y}, (f32x2){xa.z,xa.w},
                          (f32x2){xc.x,xc.y}, (f32x2){xc.z,xc.w}};
    #pragma unroll
    for (int i=0;i<8;++i){
      const float cv = ctrs[c][i];
      const f32x2 cv2 = (f32x2){cv, cv};
      #pragma unroll
      for (int j=0;j<4;++j) acc2[i][j] += cv2*xm2[j];   // v_pk_fma_f32
    }
  }
  {
    const float4 sa = *(const float4*)&sq[b*NPTS + m0];
    const float4 sb = *(const float4*)&sq[b*NPTS + m0 + 4];
    const f32x2 sm2[4] = {(f32x2){sa.x,sa.y}, (f32x2){sa.z,sa.w},
                          (f32x2){sb.x,sb.y}, (f32x2){sb.z,sb.w}};
    #pragma unroll
    for (int i=0;i<8;++i){
      const float si = sqn[i];
      const f32x2 si2 = (f32x2){si, si};
      #pragma unroll
      for (int j=0;j<4;++j) acc2[i][j] = (f32x2){2.f,2.f}*acc2[i][j] - si2 - sm2[j];
    }
  }

  const int wv = t >> 6, lane = t & 63;
  #pragma unroll
  for (int rep=0; rep<2; ++rep){
    #pragma unroll
    for (int i=0;i<4;++i){
      const int r = rep*4 + i;
      *(float4*)&dist[i][m0]   = make_float4(acc2[r][0].x, acc2[r][0].y, acc2[r][1].x, acc2[r][1].y);
      *(float4*)&dist[i][m0+4] = make_float4(acc2[r][2].x, acc2[r][2].y, acc2[r][3].x, acc2[r][3].y);
    }
    __syncthreads();
    // initial scan: per-lane sorted top-4 (value desc, idx asc) in registers
    float s0=NEG_INF,s1=NEG_INF,s2=NEG_INF,s3=NEG_INF;
    int   i0=0x7fffffff,i1=0x7fffffff,i2=0x7fffffff,i3=0x7fffffff;
    #pragma unroll
    for (int j=0;j<32;++j){
      const float v = dist[wv][lane + 64*j];
      const int   m = lane + 64*j;
      const bool b0 = v > s0, b1 = v > s1, b2 = v > s2, b3 = v > s3;  // strict: stable ties
      const float n0 = b0 ? v : s0;            const int q0 = b0 ? m : i0;
      const float n1 = b0 ? s0 : (b1 ? v : s1); const int q1 = b0 ? i0 : (b1 ? m : i1);
      const float n2 = b1 ? s1 : (b2 ? v : s2); const int q2 = b1 ? i1 : (b2 ? m : i2);
      const float n3 = b2 ? s2 : (b3 ? v : s3); const int q3 = b2 ? i2 : (b3 ? m : i3);
      s0=n0;s1=n1;s2=n2;s3=n3; i0=q0;i1=q1;i2=q2;i3=q3;
    }
    int rem = 4;
    int* row = idxout + ((size_t)b*NPTS + n0 + rep*4 + wv)*KNN;
    for (int sel=0; sel<KNN; ++sel){
      const int widx = wave_argmax_idx(s0, i0);   // DPP reduction over queue heads
      if (lane == 0) row[sel] = widx;
      if ((widx & 63) == lane){
        const float lastv = s0; const int lasti = i0;
        s0=s1;i0=i1; s1=s2;i1=i2; s2=s3;i2=i3;
        rem--;
        if (rem == 0){
          float nv = NEG_INF; int ni = 0x7fffffff;
          #pragma unroll
          for (int j=0;j<32;++j){
            const float vv = dist[wv][lane + 64*j];
            const int   mi = lane + 64*j;
            const bool ok = (vv < lastv) || (vv == lastv && mi > lasti);
            if (ok && vv > nv){ nv = vv; ni = mi; }
          }
          s0 = nv; i0 = ni; rem = 1;
        }
      }
    }
    __syncthreads();
  }
}

// ---------------- fp32 weight prep (layer 1 only): wnT[c][o], wdT[c][o] ----------------
__global__ void wprep_kernel(const float* __restrict__ w, float* __restrict__ wnT,
                             float* __restrict__ wdT, int O, int C){
  int i = blockIdx.x*blockDim.x + threadIdx.x;
  if (i >= O*C) return;
  int c = i / O, o = i - c*O;
  float a = w[(size_t)o*2*C + c];
  wnT[(size_t)c*O + o] = a;
  wdT[(size_t)c*O + o] = w[(size_t)o*2*C + C + c] - a;
}

// ---------------- bf16 weight prep (layers 2-4): wn[o][c], wd[o][c] (k contiguous) -----
__global__ void wprep_bf_kernel(const float* __restrict__ w, unsigned short* __restrict__ wn,
                                unsigned short* __restrict__ wd, int O, int C){
  int i = blockIdx.x*blockDim.x + threadIdx.x;
  if (i >= O*C) return;
  int o = i / C, c = i - o*C;
  float a = w[(size_t)o*2*C + c];
  float d = w[(size_t)o*2*C + C + c] - a;
  wn[(size_t)o*C + c] = bf16r(a);
  wd[(size_t)o*C + c] = bf16r(d);
}

// ---------------- split-bf16 weight convert (conv5): hi = bf16(w), lo = bf16(w-hi) ------
__global__ void bfsplit_kernel(const float* __restrict__ in, unsigned short* __restrict__ hi,
                               unsigned short* __restrict__ lo, int nq){
  int i = blockIdx.x*blockDim.x + threadIdx.x;
  if (i >= nq) return;
  float4 v = *(const float4*)&in[(size_t)i*4];
  unsigned short h0=bf16r(v.x), h1=bf16r(v.y), h2=bf16r(v.z), h3=bf16r(v.w);
  unsigned short l0=bf16r(v.x-bf2f(h0)), l1=bf16r(v.y-bf2f(h1)),
                 l2=bf16r(v.z-bf2f(h2)), l3=bf16r(v.w-bf2f(h3));
  *(uint2*)&hi[(size_t)i*4] = make_uint2((unsigned)h0|((unsigned)h1<<16), (unsigned)h2|((unsigned)h3<<16));
  *(uint2*)&lo[(size_t)i*4] = make_uint2((unsigned)l0|((unsigned)l1<<16), (unsigned)l2|((unsigned)l3<<16));
}

// ---------------- xcat: concat x1T..x4T -> split-bf16 [b][n][512] ----------------
__global__ __launch_bounds__(256) void xcat_kernel(const float* __restrict__ x1T,
    const float* __restrict__ x2T, const float* __restrict__ x3T, const float* __restrict__ x4T,
    unsigned short* __restrict__ xhi, unsigned short* __restrict__ xlo){
  int i = blockIdx.x*blockDim.x + threadIdx.x;   // quad index over B*N*128
  if (i >= BATCH*NPTS*128) return;
  int q = i & 127, bn_ = i >> 7;
  int k = q*4;
  const float* src; int kk;
  if (k < 64)      { src = x1T + (size_t)bn_*64;  kk = k; }
  else if (k <128) { src = x2T + (size_t)bn_*64;  kk = k-64; }
  else if (k <256) { src = x3T + (size_t)bn_*128; kk = k-128; }
  else             { src = x4T + (size_t)bn_*256; kk = k-256; }
  float4 v = *(const float4*)&src[kk];
  unsigned short h0=bf16r(v.x), h1=bf16r(v.y), h2=bf16r(v.z), h3=bf16r(v.w);
  unsigned short l0=bf16r(v.x-bf2f(h0)), l1=bf16r(v.y-bf2f(h1)),
                 l2=bf16r(v.z-bf2f(h2)), l3=bf16r(v.w-bf2f(h3));
  *(uint2*)&xhi[(size_t)i*4] = make_uint2((unsigned)h0|((unsigned)h1<<16), (unsigned)h2|((unsigned)h3<<16));
  *(uint2*)&xlo[(size_t)i*4] = make_uint2((unsigned)l0|((unsigned)l1<<16), (unsigned)l2|((unsigned)l3<<16));
}

// ---------------- generic tiled transpose: in[R][Cc] -> out[Cc][R], per z-slice ----------------
__global__ __launch_bounds__(256) void transpose2d_kernel(const float* __restrict__ in,
    float* __restrict__ out, int R, int Cc){
  __shared__ float tile[32][33];
  const size_t boff = (size_t)blockIdx.z * (size_t)R * Cc;
  const int c0 = blockIdx.x*32, r0 = blockIdx.y*32;
  const int tx = threadIdx.x & 31, ty = threadIdx.x >> 5;
  #pragma unroll
  for (int j=0;j<4;++j){
    int r = ty*4 + j;
    tile[r][tx] = in[boff + (size_t)(r0+r)*Cc + c0 + tx];
  }
  __syncthreads();
  #pragma unroll
  for (int j=0;j<4;++j){
    int r = ty*4 + j;
    out[boff + (size_t)(c0+r)*R + r0 + tx] = tile[tx][r];
  }
}

// ---------------- x -> xT0 [N][3] ----------------
__global__ void xt0_kernel(const float* __restrict__ x, float* __restrict__ xT0){
  int i = blockIdx.x*blockDim.x + threadIdx.x;
  if (i >= BATCH*NPTS) return;
  int b = i / NPTS, n = i - b*NPTS;
  const float* xb = x + (size_t)b*3*NPTS;
  float v0 = xb[n], v1 = xb[NPTS + n], v2 = xb[2*NPTS + n];
  float* o = xT0 + ((size_t)b*NPTS + n)*3;
  o[0]=v0; o[1]=v1; o[2]=v2;
}

// ---------------- edge conv layer 1 (C=3, fp32): 4 points per block ----------------
__global__ __launch_bounds__(256) void edgeconv1_kernel(const float* __restrict__ xT0,
    const int* __restrict__ idx, const float* __restrict__ wnT, const float* __restrict__ wdT,
    const float* __restrict__ g, const float* __restrict__ bb, float* __restrict__ outT){
  const int b = blockIdx.y, n0 = blockIdx.x*4, t = threadIdx.x;
  __shared__ float nbr[4][KNN][3];
  __shared__ float ctr[4][3];
  __shared__ int   idxs[4][KNN];
  const float* xb = xT0 + (size_t)b*NPTS*3;
  if (t < 4*KNN) idxs[t/KNN][t%KNN] = idx[((size_t)b*NPTS + n0 + t/KNN)*KNN + (t%KNN)];
  if (t >= 128 && t < 140){ int i = t-128; ctr[i/3][i%3] = xb[(size_t)(n0 + i/3)*3 + i%3]; }
  __syncthreads();
  for (int i=t; i<4*KNN*3; i+=256){
    int p = i/(KNN*3), r = i - p*(KNN*3), k = r/3, c = r - k*3;
    nbr[p][k][c] = xb[(size_t)idxs[p][k]*3 + c];
  }
  __syncthreads();
  const int p = t >> 6, o = t & 63;
  const float wn0 = wnT[o], wn1 = wnT[64+o], wn2 = wnT[128+o];
  const float cst = ctr[p][0]*wdT[o] + ctr[p][1]*wdT[64+o] + ctr[p][2]*wdT[128+o];
  float best = NEG_INF;
  #pragma unroll
  for (int k=0;k<KNN;++k){
    float a = nbr[p][k][0]*wn0 + nbr[p][k][1]*wn1 + nbr[p][k][2]*wn2;
    best = fmaxf(best, a);
  }
  float vv = (best + cst) * bn_scale(g[o]) + bb[o];
  outT[((size_t)b*NPTS + n0 + p)*64 + o] = fmaxf(vv, 0.f);
}

// ---------------- edge conv MFMA (bf16): block = 4 points ----------------
template<int C, int O>
__global__ __launch_bounds__(256) void edgeconv_mfma(const float* __restrict__ xT,
    const int* __restrict__ idx,
    const unsigned short* __restrict__ wn_bf, const unsigned short* __restrict__ wd_bf,
    const float* __restrict__ g, const float* __restrict__ bb, float* __restrict__ outT){
  constexpr int ROWS = 112;        // 7 m-tiles of 16
  constexpr int CP   = C + 8;      // padded row (bf16): 16B-aligned stride, conflict-free b128
  constexpr int KS   = C / 32;     // k-steps per tile
  constexpr int NTW  = O / 64;     // n-tiles per wave (O/16 tiles over 4 waves)
  __shared__ __align__(16) unsigned short A[ROWS][CP];
  __shared__ unsigned int res[4][O];
  __shared__ float cst_s[4][O];
  __shared__ int idxs[4][KNN];
  const int b = blockIdx.y, n0 = blockIdx.x*4, t = threadIdx.x;
  const float* xTb = xT + (size_t)b*NPTS*C;
  if (t < 4*KNN) idxs[t/KNN][t%KNN] = idx[((size_t)b*NPTS + n0 + t/KNN)*KNN + (t%KNN)];
  for (int i=t; i<4*O; i+=256) res[i/O][i & (O-1)] = 0u;   // 0 < fenc(any finite)
  __syncthreads();
  for (int i=t; i<ROWS*(C/4); i+=256){
    int r = i/(C/4), c4 = i - r*(C/4);
    float4 v = make_float4(0.f,0.f,0.f,0.f);
    if (r < 96){
      int p = r/24, kk = r - p*24;
      int src = idxs[p][kk < KNN ? kk : 0];        // pad rows duplicate nbr 0 (max-neutral)
      v = *(const float4*)&xTb[(size_t)src*C + c4*4];
    } else if (r < 100){
      v = *(const float4*)&xTb[(size_t)(n0 + (r-96))*C + c4*4];
    }
    unsigned int lo = (unsigned int)bf16r(v.x) | ((unsigned int)bf16r(v.y) << 16);
    unsigned int hi = (unsigned int)bf16r(v.z) | ((unsigned int)bf16r(v.w) << 16);
    *(uint2*)&A[r][c4*4] = make_uint2(lo, hi);
  }
  __syncthreads();

  const int wv = t >> 6, l = t & 63;
  const int lane15 = l & 15, quad = l >> 4;
  bfrag Bn[NTW][KS];
  #pragma unroll
  for (int nt=0; nt<NTW; ++nt){
    const int col = (wv*NTW + nt)*16 + lane15;
    #pragma unroll
    for (int s=0; s<KS; ++s)
      Bn[nt][s] = *(const bfrag*)&wn_bf[(size_t)col*C + s*32 + quad*8];
  }
  #pragma unroll
  for (int mt=0; mt<7; ++mt){
    bfrag Af[KS];
    #pragma unroll
    for (int s=0; s<KS; ++s)
      Af[s] = *(const bfrag*)&A[mt*16 + lane15][s*32 + quad*8];
    if (mt < 6){
      const int rbase = mt*16 + quad*4;
      const int p = rbase / 24;
      #pragma unroll
      for (int nt=0; nt<NTW; ++nt){
        f32x4 acc = {0.f,0.f,0.f,0.f};
        #pragma unroll
        for (int s=0; s<KS; ++s)
          acc = __builtin_amdgcn_mfma_f32_16x16x32_bf16(Af[s], Bn[nt][s], acc, 0, 0, 0);
        float m = fmaxf(fmaxf(acc[0], acc[1]), fmaxf(acc[2], acc[3]));
        const int col = (wv*NTW + nt)*16 + lane15;
        atomicMax(&res[p][col], fenc(m));
      }
    } else {
      #pragma unroll
      for (int nt=0; nt<NTW; ++nt){
        const int col = (wv*NTW + nt)*16 + lane15;
        f32x4 acc = {0.f,0.f,0.f,0.f};
        #pragma unroll
        for (int s=0; s<KS; ++s){
          bfrag Bd = *(const bfrag*)&wd_bf[(size_t)col*C + s*32 + quad*8];
          acc = __builtin_amdgcn_mfma_f32_16x16x32_bf16(Af[s], Bd, acc, 0, 0, 0);
        }
        if (quad == 0){
          #pragma unroll
          for (int r=0;r<4;++r) cst_s[r][col] = acc[r];
        }
      }
    }
  }
  __syncthreads();
  for (int i=t; i<4*O; i+=256){
    int p = i/O, o = i - p*O;
    float mx = fdec(res[p][o]);
    float vv = (mx + cst_s[p][o]) * bn_scale(g[o]) + bb[o];
    outT[((size_t)b*NPTS + n0 + p)*O + o] = fmaxf(vv, 0.f);
  }
}

// ---------------- conv5 v3: LDS-staged split-bf16 MFMA GEMM + max over n ----------------
__global__ __launch_bounds__(256) void conv5_v3(const unsigned short* __restrict__ xhi,
    const unsigned short* __restrict__ xlo, const unsigned short* __restrict__ whi,
    const unsigned short* __restrict__ wlo, const float* __restrict__ g,
    const float* __restrict__ bb, float* __restrict__ out5){
  __shared__ __align__(16) unsigned short Ah_s[128*32];
  __shared__ __align__(16) unsigned short Al_s[128*32];
  __shared__ __align__(16) unsigned short Bh_s[64*32];
  __shared__ __align__(16) unsigned short Bl_s[64*32];
  const int t = threadIdx.x;
  const int row0 = blockIdx.x*128, o0 = blockIdx.y*64;
  const int b = row0 / NPTS;   // 128 | NPTS, so a block never straddles batches
  const int wv = t >> 6, l = t & 63, lane15 = l & 15, quad = l >> 4;
  const int ar = t >> 2, ac = (t & 3)*8;
  const unsigned short* gAh0 = xhi + (size_t)(row0 + ar)*512 + ac;
  const unsigned short* gAh1 = xhi + (size_t)(row0 + 64 + ar)*512 + ac;
  const unsigned short* gAl0 = xlo + (size_t)(row0 + ar)*512 + ac;
  const unsigned short* gAl1 = xlo + (size_t)(row0 + 64 + ar)*512 + ac;
  const unsigned short* gBh  = whi + (size_t)(o0 + ar)*512 + ac;
  const unsigned short* gBl  = wlo + (size_t)(o0 + ar)*512 + ac;

  uint4 pf0 = *(const uint4*)gAh0;
  uint4 pf1 = *(const uint4*)gAh1;
  uint4 pf2 = *(const uint4*)gAl0;
  uint4 pf3 = *(const uint4*)gAl1;
  uint4 pf4 = *(const uint4*)gBh;
  uint4 pf5 = *(const uint4*)gBl;

  f32x4 acc[2][4];
  #pragma unroll
  for (int mt=0;mt<2;++mt)
    #pragma unroll
    for (int nt=0;nt<4;++nt) acc[mt][nt] = (f32x4){0.f,0.f,0.f,0.f};

  for (int ks=0; ks<16; ++ks){
    *(uint4*)&Ah_s[t*8]        = pf0;
    *(uint4*)&Ah_s[2048 + t*8] = pf1;
    *(uint4*)&Al_s[t*8]        = pf2;
    *(uint4*)&Al_s[2048 + t*8] = pf3;
    *(uint4*)&Bh_s[t*8]        = pf4;
    *(uint4*)&Bl_s[t*8]        = pf5;
    __syncthreads();
    if (ks < 15){
      const int koff = (ks+1)*32;
      pf0 = *(const uint4*)(gAh0 + koff);
      pf1 = *(const uint4*)(gAh1 + koff);
      pf2 = *(const uint4*)(gAl0 + koff);
      pf3 = *(const uint4*)(gAl1 + koff);
      pf4 = *(const uint4*)(gBh  + koff);
      pf5 = *(const uint4*)(gBl  + koff);
    }
    bfrag Afh[2], Afl[2], Bfh[4], Bfl[4];
    #pragma unroll
    for (int mt=0;mt<2;++mt){
      const int m = wv*32 + mt*16 + lane15;
      Afh[mt] = *(const bfrag*)&Ah_s[m*32 + quad*8];
      Afl[mt] = *(const bfrag*)&Al_s[m*32 + quad*8];
    }
    #pragma unroll
    for (int nt=0;nt<4;++nt){
      const int oc = nt*16 + lane15;
      Bfh[nt] = *(const bfrag*)&Bh_s[oc*32 + quad*8];
      Bfl[nt] = *(const bfrag*)&Bl_s[oc*32 + quad*8];
    }
    #pragma unroll
    for (int mt=0;mt<2;++mt)
      #pragma unroll
      for (int nt=0;nt<4;++nt){
        acc[mt][nt] = __builtin_amdgcn_mfma_f32_16x16x32_bf16(Afh[mt], Bfh[nt], acc[mt][nt], 0, 0, 0);
        acc[mt][nt] = __builtin_amdgcn_mfma_f32_16x16x32_bf16(Afl[mt], Bfh[nt], acc[mt][nt], 0, 0, 0);
        acc[mt][nt] = __builtin_amdgcn_mfma_f32_16x16x32_bf16(Afh[mt], Bfl[nt], acc[mt][nt], 0, 0, 0);
      }
    __syncthreads();
  }
  #pragma unroll
  for (int nt=0;nt<4;++nt){
    float m = NEG_INF;
    #pragma unroll
    for (int mt=0;mt<2;++mt)
      #pragma unroll
      for (int r=0;r<4;++r) m = fmaxf(m, acc[mt][nt][r]);
    m = fmaxf(m, __shfl_xor(m, 16, 64));
    m = fmaxf(m, __shfl_xor(m, 32, 64));
    if (quad == 0){
      const int o = o0 + nt*16 + lane15;
      float vv = fmaxf(m * bn_scale(g[o]) + bb[o], 0.f);
      atomicMax((int*)&out5[(size_t)b*1024 + o], __float_as_int(vv));
    }
  }
}

__global__ void zero_kernel(float* __restrict__ p, int nfloats){
  int i = blockIdx.x*blockDim.x + threadIdx.x;
  if (i < nfloats) p[i] = 0.f;
}

// ---------------- FC layers: one wave per (b,o), coalesced lane-strided reads ----------
__global__ __launch_bounds__(256) void fc_wave_kernel(const float* __restrict__ in,
    const float* __restrict__ w, const float* __restrict__ g, const float* __restrict__ bb,
    float* __restrict__ out, int IN, int O){
  const int wid = (blockIdx.x*256 + threadIdx.x) >> 6;
  const int lane = threadIdx.x & 63;
  if (wid >= BATCH*O) return;
  const int b = wid / O, o = wid - b*O;
  const float* inb = in + (size_t)b*IN;
  const float* wo  = w + (size_t)o*IN;
  float s = 0.f;
  for (int c = lane; c < IN; c += 64) s += inb[c]*wo[c];   // coalesced across the wave
  s = wave_sum(s);
  if (lane == 0){
    if (g){ s = s*bn_scale(g[o]) + bb[o]; s = fmaxf(s, 0.f); }
    out[wid] = s;
  }
}

extern "C" void kernel_launch(void* const* d_in, const int* in_sizes, int n_in,
                              void* d_out, int out_size, void* d_ws, size_t ws_size,
                              hipStream_t stream){
  const float* x   = (const float*)d_in[0];
  const float* w1  = (const float*)d_in[1];
  const float* w2  = (const float*)d_in[2];
  const float* w3  = (const float*)d_in[3];
  const float* w4  = (const float*)d_in[4];
  const float* w5  = (const float*)d_in[5];
  const float* fw1 = (const float*)d_in[6];
  const float* fw2 = (const float*)d_in[7];
  const float* fw3 = (const float*)d_in[8];
  const float* g1 = (const float*)d_in[9];  const float* b1 = (const float*)d_in[10];
  const float* g2 = (const float*)d_in[11]; const float* b2 = (const float*)d_in[12];
  const float* g3 = (const float*)d_in[13]; const float* b3 = (const float*)d_in[14];
  const float* g4 = (const float*)d_in[15]; const float* b4 = (const float*)d_in[16];
  const float* g5 = (const float*)d_in[17]; const float* b5 = (const float*)d_in[18];
  const float* g6 = (const float*)d_in[19]; const float* b6 = (const float*)d_in[20];
  const float* g7 = (const float*)d_in[21]; const float* b7 = (const float*)d_in[22];

  float* ws = (float*)d_ws;
  size_t off = 0;
  // x1..x3 channel-major; this 4.19M-float region is later reused as xcat_lo
  float* x1  = ws + off; off += (size_t)BATCH*64*NPTS;
  float* x2  = ws + off; off += (size_t)BATCH*64*NPTS;
  float* x3  = ws + off; off += (size_t)BATCH*128*NPTS;
  unsigned short* xcat_lo = (unsigned short*)x1;           // alias: x1..x3 dead before xcat runs
  unsigned short* xcat_hi = (unsigned short*)(ws + off); off += (size_t)BATCH*256*NPTS; // = B*N*512 bf16
  float* x1T = ws + off; off += (size_t)BATCH*64*NPTS;
  float* x2T = ws + off; off += (size_t)BATCH*64*NPTS;
  float* x3T = ws + off; off += (size_t)BATCH*128*NPTS;
  float* x4T = ws + off; off += (size_t)BATCH*256*NPTS;
  float* xT0 = ws + off; off += (size_t)BATCH*3*NPTS;
  float* sq  = ws + off; off += (size_t)BATCH*NPTS;
  int*  idx  = (int*)(ws + off); off += (size_t)BATCH*NPTS*KNN;
  float* out5 = ws + off; off += BATCH*1024;
  float* h6 = ws + off;   off += BATCH*512;
  float* h7 = ws + off;   off += BATCH*256;
  float* wnT1 = ws + off; off += 3*64;
  float* wdT1 = ws + off; off += 3*64;
  unsigned short* wn2 = (unsigned short*)(ws + off); off += 64*64/2;
  unsigned short* wd2 = (unsigned short*)(ws + off); off += 64*64/2;
  unsigned short* wn3 = (unsigned short*)(ws + off); off += 128*64/2;
  unsigned short* wd3 = (unsigned short*)(ws + off); off += 128*64/2;
  unsigned short* wn4 = (unsigned short*)(ws + off); off += 256*128/2;
  unsigned short* wd4 = (unsigned short*)(ws + off); off += 256*128/2;
  unsigned short* w5hi = (unsigned short*)(ws + off); off += 1024*512/2;
  unsigned short* w5lo = (unsigned short*)(ws + off); off += 1024*512/2;

  dim3 gridKNN(NPTS/8, BATCH);
  dim3 gridEC(NPTS/4, BATCH);

  // layer 1 (C=3 -> 64, fp32)
  xt0_kernel<<<64, 256, 0, stream>>>(x, xT0);
  sqnorm_kernel<<<64, 256, 0, stream>>>(x, sq, 3);
  knn_kernel<3><<<gridKNN, 256, 0, stream>>>(x, sq, idx);
  wprep_kernel<<<1, 256, 0, stream>>>(w1, wnT1, wdT1, 64, 3);
  edgeconv1_kernel<<<gridEC, 256, 0, stream>>>(xT0, idx, wnT1, wdT1, g1, b1, x1T);
  transpose2d_kernel<<<dim3(2,64,BATCH), 256, 0, stream>>>(x1T, x1, NPTS, 64);
  // layer 2 (C=64 -> 64, bf16 MFMA)
  sqnorm_kernel<<<64, 256, 0, stream>>>(x1, sq, 64);
  knn_kernel<64><<<gridKNN, 256, 0, stream>>>(x1, sq, idx);
  wprep_bf_kernel<<<16, 256, 0, stream>>>(w2, wn2, wd2, 64, 64);
  edgeconv_mfma<64,64><<<gridEC, 256, 0, stream>>>(x1T, idx, wn2, wd2, g2, b2, x2T);
  transpose2d_kernel<<<dim3(2,64,BATCH), 256, 0, stream>>>(x2T, x2, NPTS, 64);
  // layer 3 (C=64 -> 128, bf16 MFMA)
  sqnorm_kernel<<<64, 256, 0, stream>>>(x2, sq, 64);
  knn_kernel<64><<<gridKNN, 256, 0, stream>>>(x2, sq, idx);
  wprep_bf_kernel<<<32, 256, 0, stream>>>(w3, wn3, wd3, 128, 64);
  edgeconv_mfma<64,128><<<gridEC, 256, 0, stream>>>(x2T, idx, wn3, wd3, g3, b3, x3T);
  transpose2d_kernel<<<dim3(4,64,BATCH), 256, 0, stream>>>(x3T, x3, NPTS, 128);
  // layer 4 (C=128 -> 256, bf16 MFMA)
  sqnorm_kernel<<<64, 256, 0, stream>>>(x3, sq, 128);
  knn_kernel<128><<<gridKNN, 256, 0, stream>>>(x3, sq, idx);
  wprep_bf_kernel<<<128, 256, 0, stream>>>(w4, wn4, wd4, 256, 128);
  edgeconv_mfma<128,256><<<gridEC, 256, 0, stream>>>(x3T, idx, wn4, wd4, g4, b4, x4T);
  // conv5 (split-bf16 MFMA, LDS-staged) + global max over n
  xcat_kernel<<<(BATCH*NPTS*128)/256, 256, 0, stream>>>(x1T, x2T, x3T, x4T, xcat_hi, xcat_lo);
  bfsplit_kernel<<<512, 256, 0, stream>>>(w5, w5hi, w5lo, 1024*512/4);
  zero_kernel<<<32, 256, 0, stream>>>(out5, BATCH*1024);
  conv5_v3<<<dim3(BATCH*NPTS/128, 16), 256, 0, stream>>>(xcat_hi, xcat_lo, w5hi, w5lo, g5, b5, out5);
  // FC head (wave-per-output, coalesced)
  fc_wave_kernel<<<(BATCH*512*64)/256, 256, 0, stream>>>(out5, fw1, g6, b6, h6, 1024, 512);
  fc_wave_kernel<<<(BATCH*256*64)/256, 256, 0, stream>>>(h6, fw2, g7, b7, h7, 512, 256);
  fc_wave_kernel<<<(BATCH*40*64 + 255)/256, 256, 0, stream>>>(h7, fw3, nullptr, nullptr, (float*)d_out, 256, 40);
}